// Round 12
// baseline (464.759 us; speedup 1.0000x reference)
//
#include <hip/hip_runtime.h>
#include <hip/hip_bf16.h>

// ---------- types ----------
typedef __attribute__((ext_vector_type(8)))  __bf16 bf16x8;
typedef __attribute__((ext_vector_type(4)))  float  f32x4;
typedef __attribute__((ext_vector_type(16))) float  f32x16;

static __device__ __forceinline__ unsigned short f2bf(float x) {
    unsigned int u = __float_as_uint(x);
    unsigned int r = (u + 0x7FFFu + ((u >> 16) & 1u)) >> 16;
    return (unsigned short)r;
}
static __device__ __forceinline__ float bf2f(unsigned short u) {
    return __uint_as_float(((unsigned int)u) << 16);
}

// 2^x via v_exp_f32 (CDNA VALU has HW interlocks; no nop needed)
static __device__ __forceinline__ float fast_exp2(float x) {
    float r;
    asm("v_exp_f32 %0, %1" : "=v"(r) : "v"(x));
    return r;
}
// packed f32x2 -> bf16x2 (u32); lo <- a, hi <- b
static __device__ __forceinline__ unsigned int cvt_pk_bf16(float a, float b) {
    unsigned int r;
    asm("v_cvt_pk_bf16_f32 %0, %1, %2" : "=v"(r) : "v"(a), "v"(b));
    return r;
}

// async global->LDS, 16B per lane; lds base wave-uniform (lane*16 auto-offset)
static __device__ __forceinline__ void gload_lds16(const ushort* g, ushort* l) {
    __builtin_amdgcn_global_load_lds((const __attribute__((address_space(1))) void*)g,
                                     (__attribute__((address_space(3))) void*)l, 16, 0, 0);
}

// raw barrier + scheduling/memory fence (no vmcnt drain, unlike __syncthreads)
static __device__ __forceinline__ void barrier_fence() {
    __builtin_amdgcn_s_barrier();
    __builtin_amdgcn_sched_barrier(0);
    asm volatile("" ::: "memory");
}

// T1: XCD-aware chunked remap (requires nwg % 8 == 0; all grids here comply)
static __device__ __forceinline__ int xcd_swz(int id, int nwg) {
    return (id & 7) * (nwg >> 3) + (id >> 3);
}

// ---------- elementwise cast f32 -> bf16 ----------
__global__ __launch_bounds__(256) void cast_bf16_kernel(const float* __restrict__ in,
                                                        ushort* __restrict__ out, int n4) {
    int i = blockIdx.x * 256 + threadIdx.x;
    if (i < n4) {
        float4 v = reinterpret_cast<const float4*>(in)[i];
        ushort4 o;
        o.x = f2bf(v.x); o.y = f2bf(v.y); o.z = f2bf(v.z); o.w = f2bf(v.w);
        reinterpret_cast<ushort4*>(out)[i] = o;
    }
}

// ---------- transpose + cast: in[K][N] f32 -> out[N][K] bf16 ----------
__global__ __launch_bounds__(256) void transpose_cast_kernel(const float* __restrict__ in,
                                                             ushort* __restrict__ out,
                                                             int K, int N) {
    __shared__ float tile[32][33];
    const int tx = threadIdx.x;
    const int ty = threadIdx.y;
    const int n0 = blockIdx.x * 32;
    const int k0 = blockIdx.y * 32;
    for (int i = ty; i < 32; i += 8)
        tile[i][tx] = in[(size_t)(k0 + i) * N + n0 + tx];
    __syncthreads();
    for (int i = ty; i < 32; i += 8)
        out[(size_t)(n0 + i) * K + k0 + tx] = f2bf(tile[tx][i]);
}

// three 1024x1024 transposes (Wq,Wk,Wv) in one launch; z picks the source
__global__ __launch_bounds__(256) void transpose_cast3_kernel(const float* __restrict__ w0,
                                                              const float* __restrict__ w1,
                                                              const float* __restrict__ w2,
                                                              ushort* __restrict__ out) {
    __shared__ float tile[32][33];
    const int tx = threadIdx.x;
    const int ty = threadIdx.y;
    const int n0 = blockIdx.x * 32;
    const int k0 = blockIdx.y * 32;
    const int z  = blockIdx.z;
    const float* in = (z == 0) ? w0 : (z == 1 ? w1 : w2);
    ushort* o = out + (size_t)z * 1024 * 1024;
    for (int i = ty; i < 32; i += 8)
        tile[i][tx] = in[(size_t)(k0 + i) * 1024 + n0 + tx];
    __syncthreads();
    for (int i = ty; i < 32; i += 8)
        o[(size_t)(n0 + i) * 1024 + k0 + tx] = f2bf(tile[tx][i]);
}

// ============================================================================
// gemm_p3 (proven round-8/11 structure): 128x128, BK=32, 256 thr, 3 LDS bufs,
// counted vmcnt(4), 1 barrier/tile. Used for QKV (grid 1536 -> 3 blocks/CU).
// ============================================================================
template<int RELU, int OUTBF, int QKV, int RES>
__global__ __launch_bounds__(256) void gemm_p3(const ushort* __restrict__ A,
                                               const ushort* __restrict__ Bt,
                                               const float* __restrict__ b0,
                                               const float* __restrict__ b1_,
                                               const float* __restrict__ b2_,
                                               const void* __restrict__ xres,
                                               void* __restrict__ Cp,
                                               int M, int N, int K) {
    __shared__ ushort As[3][4096];
    __shared__ ushort Bs[3][4096];
    const int tid  = threadIdx.x;
    const int lane = tid & 63;
    const int w    = tid >> 6;
    const int wr   = w >> 1, wc = w & 1;
    const int nwg = gridDim.x * gridDim.y;
    int wid = xcd_swz(blockIdx.y * gridDim.x + blockIdx.x, nwg);
    const int bx = wid % gridDim.x;
    const int by = wid / gridDim.x;
    const int m0 = by * 128;
    const int n0 = bx * 128;
    const int lr = lane & 15;
    const int lg = lane >> 4;
    const int xc = (lg ^ ((lr >> 1) & 3)) * 8;

    const int r0 = w * 32 + (lane >> 2);
    const int c8 = ((lane & 3) ^ ((lane >> 3) & 3)) * 8;
    const ushort* gA0 = A  + (size_t)(m0 + r0)      * K + c8;
    const ushort* gA1 = A  + (size_t)(m0 + r0 + 16) * K + c8;
    const ushort* gB0 = Bt + (size_t)(n0 + r0)      * K + c8;
    const ushort* gB1 = Bt + (size_t)(n0 + r0 + 16) * K + c8;
    const int wb = w * 1024;

    f32x4 acc[4][4];
    const f32x4 z = {0.f, 0.f, 0.f, 0.f};
#pragma unroll
    for (int i = 0; i < 4; i++)
#pragma unroll
        for (int j = 0; j < 4; j++) acc[i][j] = z;

    const int nt = K >> 5;

#pragma unroll
    for (int t = 0; t < 2; ++t) {
        const int kn = t * 32;
        gload_lds16(gA0 + kn, &As[t][wb]);
        gload_lds16(gA1 + kn, &As[t][wb + 512]);
        gload_lds16(gB0 + kn, &Bs[t][wb]);
        gload_lds16(gB1 + kn, &Bs[t][wb + 512]);
    }

    int cur = 0;
    for (int t = 0; t < nt; ++t) {
        if (t + 1 < nt) asm volatile("s_waitcnt vmcnt(4)" ::: "memory");
        else            asm volatile("s_waitcnt vmcnt(0)" ::: "memory");
        barrier_fence();

        if (t + 2 < nt) {
            const int bi = (cur + 2 >= 3) ? cur - 1 : cur + 2;
            const int kn = (t + 2) * 32;
            gload_lds16(gA0 + kn, &As[bi][wb]);
            gload_lds16(gA1 + kn, &As[bi][wb + 512]);
            gload_lds16(gB0 + kn, &Bs[bi][wb]);
            gload_lds16(gB1 + kn, &Bs[bi][wb + 512]);
        }

        const ushort* Asb = As[cur];
        const ushort* Bsb = Bs[cur];
        bf16x8 af[4], bfr[4];
#pragma unroll
        for (int i = 0; i < 4; i++)
            af[i] = *reinterpret_cast<const bf16x8*>(&Asb[(wr * 64 + i * 16 + lr) * 32 + xc]);
#pragma unroll
        for (int j = 0; j < 4; j++)
            bfr[j] = *reinterpret_cast<const bf16x8*>(&Bsb[(wc * 64 + j * 16 + lr) * 32 + xc]);
#pragma unroll
        for (int i = 0; i < 4; i++)
#pragma unroll
            for (int j = 0; j < 4; j++)
                acc[i][j] = __builtin_amdgcn_mfma_f32_16x16x32_bf16(af[i], bfr[j], acc[i][j], 0, 0, 0);

        cur = (cur == 2) ? 0 : cur + 1;
    }

    const float* bias;
    float qscale = 1.0f;
    if (QKV) {
        bias = (n0 < 1024) ? b0 : (n0 < 2048 ? b1_ : b2_);
        if (n0 < 1024) qscale = 0.18033688f;
    } else {
        bias = b0;
    }
    const int nb = QKV ? (n0 & 1023) : n0;
    const int rbase = (lane >> 4) * 4;
#pragma unroll
    for (int i = 0; i < 4; i++) {
#pragma unroll
        for (int j = 0; j < 4; j++) {
            const int cloc = wc * 64 + j * 16 + lr;
            const float bv = bias[nb + cloc];
#pragma unroll
            for (int r = 0; r < 4; r++) {
                const int row = m0 + wr * 64 + i * 16 + rbase + r;
                float v = acc[i][j][r] + bv;
                if (RES == 1) v += ((const float*)xres)[(size_t)row * N + n0 + cloc];
                if (RES == 2) v += bf2f(((const ushort*)xres)[(size_t)row * N + n0 + cloc]);
                if (RELU) v = v > 0.f ? v : 0.f;
                if (QKV)  v *= qscale;
                if (OUTBF) ((ushort*)Cp)[(size_t)row * N + n0 + cloc] = f2bf(v);
                else       ((float*)Cp)[(size_t)row * N + n0 + cloc] = v;
            }
        }
    }
}

// ============================================================================
// gemm_4p (m201-style phase choreography): BM=256, BN=128, BK=64.
// 512 threads = 8 waves (4M x 2N), per-wave 64x64 out (acc 4x4).
// LDS: 2 dbuf x (A 256x64 = 32 KB + B 128x64 = 16 KB) = 96 KB -> 1 block/CU.
// Staging in HALF-tiles (A-half 128 rows: 2 gloads; B-half 64 rows: 1) = 3
// gloads/half, issued at phases 0 and 2 for tile t+1 while computing t.
// Counted wait: at p0 outstanding FIFO = [t.h0(3), t.h1(3), t+1.h0(3)] ->
// vmcnt(3) certifies tile t (this wave); the barrier extends to all waves.
// WAR: stage writes buf cur^1, last read in t-1 p2/p3, closed by t-1 p3's
// end barrier (reads complete before each wave's MFMA which precedes it).
// 4 phases/tile, 8 MFMA each; ds_read || MFMA overlap across waves within a
// phase (no barrier between a wave's reads and its MFMAs).
// Swizzle: rows are 128B; LDS chunk c holds global octet c ^ (row&7); write
// side pre-swizzles the global source column, gload dest linear (rule 21).
// ds_read bank: byte = row*128 + c*16 -> bank = 4c mod 32; 64 lanes spread
// all 8 chunk slots evenly -> conflict-free.
// ============================================================================
template<int RELU, int OUTBF, int RES>
__global__ __launch_bounds__(512, 1) void gemm_4p(const ushort* __restrict__ A,
                                                  const ushort* __restrict__ Bt,
                                                  const float* __restrict__ bias,
                                                  const void* __restrict__ xres,
                                                  void* __restrict__ Cp,
                                                  int M, int N, int K) {
    __shared__ ushort As[2][16384];   // [256][64]
    __shared__ ushort Bs[2][8192];    // [128][64]
    const int tid  = threadIdx.x;
    const int lane = tid & 63;
    const int w    = tid >> 6;        // 0..7
    const int wr   = w >> 1;          // 0..3
    const int wc   = w & 1;           // 0..1
    const int nwg  = gridDim.x * gridDim.y;
    int wid = xcd_swz(blockIdx.y * gridDim.x + blockIdx.x, nwg);
    const int bx = wid % gridDim.x;
    const int by = wid / gridDim.x;
    const int m0 = by * 256;
    const int n0 = bx * 128;
    const int lr = lane & 15;
    const int lg = lane >> 4;         // k-octet 0..3

    // fragment LDS element offsets: row*64 + ((kh*4+lg) ^ (row&7))*8, row&7 = lr&7
    int offA[4][2], offB[4][2];
#pragma unroll
    for (int i = 0; i < 4; i++) {
        const int row = wr * 64 + i * 16 + lr;
#pragma unroll
        for (int kh = 0; kh < 2; kh++)
            offA[i][kh] = row * 64 + (((kh * 4 + lg) ^ (lr & 7)) << 3);
    }
#pragma unroll
    for (int j = 0; j < 4; j++) {
        const int row = wc * 64 + j * 16 + lr;
#pragma unroll
        for (int kh = 0; kh < 2; kh++)
            offB[j][kh] = row * 64 + (((kh * 4 + lg) ^ (lr & 7)) << 3);
    }

    // staging: per thread, source chunk pre-swizzled by row&7 == lane>>3
    const int srcc = ((lane & 7) ^ (lane >> 3)) * 8;
    // A-half h, load l: row = h*128 + l*64 + w*8 + (lane>>3); lds elem base (h*8192+l*4096+w*512)
    const ushort* gA[2][2];
    int ldsA[2][2];
#pragma unroll
    for (int h = 0; h < 2; h++)
#pragma unroll
        for (int l = 0; l < 2; l++) {
            const int row = h * 128 + l * 64 + w * 8 + (lane >> 3);
            gA[h][l]  = A + (size_t)(m0 + row) * K + srcc;
            ldsA[h][l] = h * 8192 + l * 4096 + w * 512;
        }
    // B-half h: row = h*64 + w*8 + (lane>>3); lds elem base h*4096 + w*512
    const ushort* gB[2];
    int ldsB[2];
#pragma unroll
    for (int h = 0; h < 2; h++) {
        const int row = h * 64 + w * 8 + (lane >> 3);
        gB[h]  = Bt + (size_t)(n0 + row) * K + srcc;
        ldsB[h] = h * 4096 + w * 512;
    }

    f32x4 acc[4][4];
    const f32x4 z = {0.f, 0.f, 0.f, 0.f};
#pragma unroll
    for (int i = 0; i < 4; i++)
#pragma unroll
        for (int j = 0; j < 4; j++) acc[i][j] = z;

    const int nt = K >> 6;

    // prologue: stage tile 0, both halves (6 loads)
#pragma unroll
    for (int h = 0; h < 2; h++) {
        gload_lds16(gA[h][0], &As[0][ldsA[h][0]]);
        gload_lds16(gA[h][1], &As[0][ldsA[h][1]]);
        gload_lds16(gB[h],    &Bs[0][ldsB[h]]);
    }

    int cur = 0;
    for (int t = 0; t < nt; ++t) {
        const int kn = (t + 1) << 6;
        // ---- phase 0: stage t+1 half0; certify tile t; kh=0, i=0..1
        if (t + 1 < nt) {
            gload_lds16(gA[0][0] + kn, &As[cur ^ 1][ldsA[0][0]]);
            gload_lds16(gA[0][1] + kn, &As[cur ^ 1][ldsA[0][1]]);
            gload_lds16(gB[0]    + kn, &Bs[cur ^ 1][ldsB[0]]);
            asm volatile("s_waitcnt vmcnt(3)" ::: "memory");
        } else {
            asm volatile("s_waitcnt vmcnt(0)" ::: "memory");
        }
        barrier_fence();
        {
            const ushort* Asb = As[cur];
            const ushort* Bsb = Bs[cur];
            bf16x8 b0[4], a0, a1;
#pragma unroll
            for (int j = 0; j < 4; j++)
                b0[j] = *reinterpret_cast<const bf16x8*>(&Bsb[offB[j][0]]);
            a0 = *reinterpret_cast<const bf16x8*>(&Asb[offA[0][0]]);
            a1 = *reinterpret_cast<const bf16x8*>(&Asb[offA[1][0]]);
            __builtin_amdgcn_s_setprio(1);
#pragma unroll
            for (int j = 0; j < 4; j++) {
                acc[0][j] = __builtin_amdgcn_mfma_f32_16x16x32_bf16(a0, b0[j], acc[0][j], 0, 0, 0);
                acc[1][j] = __builtin_amdgcn_mfma_f32_16x16x32_bf16(a1, b0[j], acc[1][j], 0, 0, 0);
            }
            __builtin_amdgcn_s_setprio(0);
            barrier_fence();
            // ---- phase 1: kh=0, i=2..3
            a0 = *reinterpret_cast<const bf16x8*>(&Asb[offA[2][0]]);
            a1 = *reinterpret_cast<const bf16x8*>(&Asb[offA[3][0]]);
            __builtin_amdgcn_s_setprio(1);
#pragma unroll
            for (int j = 0; j < 4; j++) {
                acc[2][j] = __builtin_amdgcn_mfma_f32_16x16x32_bf16(a0, b0[j], acc[2][j], 0, 0, 0);
                acc[3][j] = __builtin_amdgcn_mfma_f32_16x16x32_bf16(a1, b0[j], acc[3][j], 0, 0, 0);
            }
            __builtin_amdgcn_s_setprio(0);
            barrier_fence();
            // ---- phase 2: stage t+1 half1; kh=1, i=0..1
            if (t + 1 < nt) {
                gload_lds16(gA[1][0] + kn, &As[cur ^ 1][ldsA[1][0]]);
                gload_lds16(gA[1][1] + kn, &As[cur ^ 1][ldsA[1][1]]);
                gload_lds16(gB[1]    + kn, &Bs[cur ^ 1][ldsB[1]]);
            }
#pragma unroll
            for (int j = 0; j < 4; j++)
                b0[j] = *reinterpret_cast<const bf16x8*>(&Bsb[offB[j][1]]);
            a0 = *reinterpret_cast<const bf16x8*>(&Asb[offA[0][1]]);
            a1 = *reinterpret_cast<const bf16x8*>(&Asb[offA[1][1]]);
            __builtin_amdgcn_s_setprio(1);
#pragma unroll
            for (int j = 0; j < 4; j++) {
                acc[0][j] = __builtin_amdgcn_mfma_f32_16x16x32_bf16(a0, b0[j], acc[0][j], 0, 0, 0);
                acc[1][j] = __builtin_amdgcn_mfma_f32_16x16x32_bf16(a1, b0[j], acc[1][j], 0, 0, 0);
            }
            __builtin_amdgcn_s_setprio(0);
            barrier_fence();
            // ---- phase 3: kh=1, i=2..3
            a0 = *reinterpret_cast<const bf16x8*>(&Asb[offA[2][1]]);
            a1 = *reinterpret_cast<const bf16x8*>(&Asb[offA[3][1]]);
            __builtin_amdgcn_s_setprio(1);
#pragma unroll
            for (int j = 0; j < 4; j++) {
                acc[2][j] = __builtin_amdgcn_mfma_f32_16x16x32_bf16(a0, b0[j], acc[2][j], 0, 0, 0);
                acc[3][j] = __builtin_amdgcn_mfma_f32_16x16x32_bf16(a1, b0[j], acc[3][j], 0, 0, 0);
            }
            __builtin_amdgcn_s_setprio(0);
            barrier_fence();   // closes tile t's reads -> next p0 stage is WAR-safe
        }
        cur ^= 1;
    }

    // epilogue
    const int rbase = (lane >> 4) * 4;
#pragma unroll
    for (int i = 0; i < 4; i++) {
#pragma unroll
        for (int j = 0; j < 4; j++) {
            const int cloc = wc * 64 + j * 16 + lr;
            const float bv = bias[n0 + cloc];
#pragma unroll
            for (int r = 0; r < 4; r++) {
                const int row = m0 + wr * 64 + i * 16 + rbase + r;
                float v = acc[i][j][r] + bv;
                if (RES == 1) v += ((const float*)xres)[(size_t)row * N + n0 + cloc];
                if (RES == 2) v += bf2f(((const ushort*)xres)[(size_t)row * N + n0 + cloc]);
                if (RELU) v = v > 0.f ? v : 0.f;
                if (OUTBF) ((ushort*)Cp)[(size_t)row * N + n0 + cloc] = f2bf(v);
                else       ((float*)Cp)[(size_t)row * N + n0 + cloc] = v;
            }
        }
    }
}

// ---------- flash attention, 32x32 swapped-QK^T, in-register P (T12) ----------
#define ASWZ(row, col) ((row) * 64 + ((col) ^ ((((row) ^ ((row) >> 3)) & 7) << 3)))

__global__ __launch_bounds__(256, 3) void attn_kernel(const ushort* __restrict__ QKV,
                                                      ushort* __restrict__ O) {
    __shared__ ushort Ks[2][4096];
    __shared__ ushort Vt[2][4096];
    const int tid  = threadIdx.x;
    const int lane = tid & 63;
    const int w    = tid >> 6;
    const int l31  = lane & 31;
    const int hi   = lane >> 5;

    int blk = xcd_swz(blockIdx.x, gridDim.x);
    const int qb = blk & 15;
    const int h  = (blk >> 4) & 15;
    const int b  = blk >> 8;
    const int s0 = qb * 128 + w * 32;
    const size_t rowb   = (size_t)b * 2048;
    const size_t base_q = rowb * 3072 + (size_t)h * 64;
    const size_t base_k = base_q + 1024;
    const size_t base_v = base_q + 2048;
    const size_t base_o = rowb * 1024 + (size_t)h * 64;

    bf16x8 qf[4];
#pragma unroll
    for (int ks = 0; ks < 4; ks++)
        qf[ks] = *reinterpret_cast<const bf16x8*>(
            &QKV[base_q + (size_t)(s0 + l31) * 3072 + ks * 16 + 8 * hi]);

    int off8[2][4];
#pragma unroll
    for (int sub = 0; sub < 2; sub++)
#pragma unroll
        for (int ks = 0; ks < 4; ks++)
            off8[sub][ks] = ASWZ(sub * 32 + l31, ks * 16 + 8 * hi);

    const int tS2 = tid >> 3;
    const int ccS = tid & 7;
    int voff[8];
#pragma unroll
    for (int jj = 0; jj < 8; jj++)
        voff[jj] = ASWZ(ccS * 8 + jj, 2 * tS2);
    const int tk1 = tS2 + 32;
    const int sz0 = (tS2 ^ (tS2 >> 3)) & 7;
    const int sz1 = (tk1 ^ (tk1 >> 3)) & 7;
    const ushort* pK0 = QKV + base_k + (size_t)tS2 * 3072 + (ccS ^ sz0) * 8;
    const ushort* pK1 = QKV + base_k + (size_t)tk1 * 3072 + (ccS ^ sz1) * 8;
    const ushort* pV0 = QKV + base_v + (size_t)(2 * tS2)     * 3072 + ccS * 8;
    const ushort* pV1 = QKV + base_v + (size_t)(2 * tS2 + 1) * 3072 + ccS * 8;
    const size_t step = (size_t)64 * 3072;

    gload_lds16(pK0, &Ks[0][w * 512]);
    gload_lds16(pK1, &Ks[0][2048 + w * 512]);
    {
        int4 v0 = *reinterpret_cast<const int4*>(pV0);
        int4 v1 = *reinterpret_cast<const int4*>(pV1);
        const ushort* vs0 = reinterpret_cast<const ushort*>(&v0);
        const ushort* vs1 = reinterpret_cast<const ushort*>(&v1);
#pragma unroll
        for (int jj = 0; jj < 8; jj++)
            *reinterpret_cast<unsigned*>(&Vt[0][voff[jj]]) =
                (unsigned)vs0[jj] | ((unsigned)vs1[jj] << 16);
    }
    pK0 += step; pK1 += step; pV0 += step; pV1 += step;
    __syncthreads();

    f32x16 oacc0, oacc1;
    for (int i = 0; i < 16; i++) { oacc0[i] = 0.f; oacc1[i] = 0.f; }
    float lacc = 0.f;
    int cur = 0;

    for (int it = 0; it < 32; ++it) {
        int4 nv0, nv1;
        if (it < 31) {
            gload_lds16(pK0, &Ks[cur ^ 1][w * 512]);
            gload_lds16(pK1, &Ks[cur ^ 1][2048 + w * 512]);
            nv0 = *reinterpret_cast<const int4*>(pV0);
            nv1 = *reinterpret_cast<const int4*>(pV1);
            pK0 += step; pK1 += step; pV0 += step; pV1 += step;
        }

        f32x16 sa0, sa1;
        for (int i = 0; i < 16; i++) { sa0[i] = 0.f; sa1[i] = 0.f; }
        __builtin_amdgcn_s_setprio(1);
#pragma unroll
        for (int ks = 0; ks < 4; ks++) {
            bf16x8 k0 = *reinterpret_cast<const bf16x8*>(&Ks[cur][off8[0][ks]]);
            sa0 = __builtin_amdgcn_mfma_f32_32x32x16_bf16(k0, qf[ks], sa0, 0, 0, 0);
        }
#pragma unroll
        for (int ks = 0; ks < 4; ks++) {
            bf16x8 k1 = *reinterpret_cast<const bf16x8*>(&Ks[cur][off8[1][ks]]);
            sa1 = __builtin_amdgcn_mfma_f32_32x32x16_bf16(k1, qf[ks], sa1, 0, 0, 0);
        }
        __builtin_amdgcn_s_setprio(0);

        unsigned pk0[8], pk1[8];
#pragma unroll
        for (int i = 0; i < 8; i++) {
            float plo = fast_exp2(sa0[2 * i]);
            float phi = fast_exp2(sa0[2 * i + 1]);
            lacc += plo + phi;
            pk0[i] = cvt_pk_bf16(plo, phi);
        }
#pragma unroll
        for (int i = 0; i < 8; i++) {
            float plo = fast_exp2(sa1[2 * i]);
            float phi = fast_exp2(sa1[2 * i + 1]);
            lacc += plo + phi;
            pk1[i] = cvt_pk_bf16(plo, phi);
        }

        __builtin_amdgcn_s_setprio(1);
#pragma unroll
        for (int ks = 0; ks < 4; ks++) {
            const int bi = 4 * (ks & 1);
            unsigned a, bb, c, d;
            if (ks < 2) { a = pk0[bi]; bb = pk0[bi + 1]; c = pk0[bi + 2]; d = pk0[bi + 3]; }
            else        { a = pk1[bi]; bb = pk1[bi + 1]; c = pk1[bi + 2]; d = pk1[bi + 3]; }
            asm("v_permlane32_swap_b32 %0, %1" : "+v"(a), "+v"(c));
            asm("v_permlane32_swap_b32 %0, %1" : "+v"(bb), "+v"(d));
            union { unsigned u[4]; bf16x8 v; } fr;
            fr.u[0] = a; fr.u[1] = bb; fr.u[2] = c; fr.u[3] = d;
            bf16x8 v0 = *reinterpret_cast<const bf16x8*>(&Vt[cur][off8[0][ks]]);
            oacc0 = __builtin_amdgcn_mfma_f32_32x32x16_bf16(fr.v, v0, oacc0, 0, 0, 0);
            bf16x8 v1 = *reinterpret_cast<const bf16x8*>(&Vt[cur][off8[1][ks]]);
            oacc1 = __builtin_amdgcn_mfma_f32_32x32x16_bf16(fr.v, v1, oacc1, 0, 0, 0);
        }
        __builtin_amdgcn_s_setprio(0);

        if (it < 31) {
            const ushort* vs0 = reinterpret_cast<const ushort*>(&nv0);
            const ushort* vs1 = reinterpret_cast<const ushort*>(&nv1);
#pragma unroll
            for (int jj = 0; jj < 8; jj++)
                *reinterpret_cast<unsigned*>(&Vt[cur ^ 1][voff[jj]]) =
                    (unsigned)vs0[jj] | ((unsigned)vs1[jj] << 16);
        }
        __syncthreads();
        cur ^= 1;
    }

    const float ltot = lacc + __shfl_xor(lacc, 32);
    const float inv  = 1.f / ltot;
#pragma unroll
    for (int r = 0; r < 16; r++) {
        const int qloc = (r & 3) + 8 * (r >> 2) + 4 * hi;
        const float invq = __shfl(inv, qloc);
        const size_t rowoff = base_o + (size_t)(s0 + qloc) * 1024 + l31;
        O[rowoff]      = f2bf(oacc0[r] * invq);
        O[rowoff + 32] = f2bf(oacc1[r] * invq);
    }
}

// ---------- single-input layernorm ----------
template<int OUTBF>
__global__ __launch_bounds__(256) void ln_one(const ushort* __restrict__ zin,
                                              const float* __restrict__ g,
                                              const float* __restrict__ be,
                                              void* __restrict__ out) {
    const int row = blockIdx.x;
    const int tid = threadIdx.x;
    const ushort4 zv = reinterpret_cast<const ushort4*>(zin + (size_t)row * 1024)[tid];
    float v[4] = {bf2f(zv.x), bf2f(zv.y), bf2f(zv.z), bf2f(zv.w)};
    float s  = v[0] + v[1] + v[2] + v[3];
    float s2 = v[0]*v[0] + v[1]*v[1] + v[2]*v[2] + v[3]*v[3];
    for (int off = 32; off; off >>= 1) { s += __shfl_down(s, off); s2 += __shfl_down(s2, off); }
    __shared__ float red[8];
    const int w = tid >> 6, lane = tid & 63;
    if (lane == 0) { red[w] = s; red[4 + w] = s2; }
    __syncthreads();
    if (tid == 0) {
        const float ts  = red[0] + red[1] + red[2] + red[3];
        const float ts2 = red[4] + red[5] + red[6] + red[7];
        const float mu  = ts * (1.f / 1024.f);
        const float var = ts2 * (1.f / 1024.f) - mu * mu;
        red[0] = mu;
        red[1] = rsqrtf(var + 1e-5f);
    }
    __syncthreads();
    const float mu = red[0], rs = red[1];
    const float4 gv = reinterpret_cast<const float4*>(g)[tid];
    const float4 bv = reinterpret_cast<const float4*>(be)[tid];
    float o0 = (v[0] - mu) * rs * gv.x + bv.x;
    float o1 = (v[1] - mu) * rs * gv.y + bv.y;
    float o2 = (v[2] - mu) * rs * gv.z + bv.z;
    float o3 = (v[3] - mu) * rs * gv.w + bv.w;
    if (OUTBF) {
        ushort4 ob;
        ob.x = f2bf(o0); ob.y = f2bf(o1); ob.z = f2bf(o2); ob.w = f2bf(o3);
        reinterpret_cast<ushort4*>((ushort*)out + (size_t)row * 1024)[tid] = ob;
    } else {
        float4 of;
        of.x = o0; of.y = o1; of.z = o2; of.w = o3;
        reinterpret_cast<float4*>((float*)out + (size_t)row * 1024)[tid] = of;
    }
}

// ---------- launch ----------
extern "C" void kernel_launch(void* const* d_in, const int* in_sizes, int n_in,
                              void* d_out, int out_size, void* d_ws, size_t ws_size,
                              hipStream_t stream) {
    const float* x  = (const float*)d_in[0];
    const float* Wq = (const float*)d_in[1];  const float* bq = (const float*)d_in[2];
    const float* Wk = (const float*)d_in[3];  const float* bk = (const float*)d_in[4];
    const float* Wv = (const float*)d_in[5];  const float* bv = (const float*)d_in[6];
    const float* Wo = (const float*)d_in[7];  const float* bo = (const float*)d_in[8];
    const float* W1 = (const float*)d_in[9];  const float* b1 = (const float*)d_in[10];
    const float* W2 = (const float*)d_in[11]; const float* b2 = (const float*)d_in[12];
    const float* g1 = (const float*)d_in[13]; const float* be1 = (const float*)d_in[14];
    const float* g2 = (const float*)d_in[15]; const float* be2 = (const float*)d_in[16];

    char* ws = (char*)d_ws;
    const size_t MBy = (size_t)1 << 20;
    ushort* xb    = (ushort*)(ws + 0 * MBy);     // 16 MB  [8192][1024] bf16
    ushort* wqkvT = (ushort*)(ws + 16 * MBy);    // 6 MB   [3072][1024]
    ushort* woT   = (ushort*)(ws + 22 * MBy);    // 2 MB
    ushort* w1T   = (ushort*)(ws + 24 * MBy);    // 8 MB   [4096][1024]
    ushort* w2T   = (ushort*)(ws + 32 * MBy);    // 8 MB   [1024][4096]
    ushort* QKVb  = (ushort*)(ws + 40 * MBy);    // 48 MB  [8192][3072]
    ushort* AOb   = (ushort*)(ws + 88 * MBy);    // 16 MB
    ushort* h1    = (ushort*)(ws + 40 * MBy);    // 64 MB (aliases QKVb+AOb, both dead by FFN1)
    ushort* z1b   = (ushort*)(ws + 104 * MBy);   // 16 MB  x + attn_out (bf16)
    ushort* z2b   = (ushort*)(ws + 104 * MBy);   // aliases z1b (dead after LN1)
    ushort* x2b   = (ushort*)(ws + 120 * MBy);   // 16 MB
    (void)ws_size; (void)n_in; (void)in_sizes; (void)out_size;

    const int M = 8192;

    cast_bf16_kernel<<<(M * 1024 / 4 + 255) / 256, 256, 0, stream>>>(x, xb, M * 1024 / 4);
    dim3 tb(32, 8);
    transpose_cast3_kernel<<<dim3(32, 32, 3), tb, 0, stream>>>(Wq, Wk, Wv, wqkvT);
    transpose_cast_kernel<<<dim3(32, 32),  tb, 0, stream>>>(Wo, woT, 1024, 1024);
    transpose_cast_kernel<<<dim3(128, 32), tb, 0, stream>>>(W1, w1T, 1024, 4096);
    transpose_cast_kernel<<<dim3(32, 128), tb, 0, stream>>>(W2, w2T, 4096, 1024);

    // QKV projection (proven p3 structure; 1536 blocks -> 3/CU)
    gemm_p3<0, 1, 1, 0><<<dim3(24, 64), 256, 0, stream>>>(xb, wqkvT, bq, bk, bv, nullptr,
                                                          QKVb, M, 3072, 1024);

    attn_kernel<<<1024, 256, 0, stream>>>(QKVb, AOb);

    // Wo + fused residual (x, f32) -> z1 (bf16); 4p: grid 8x32 = 256 = 1/CU
    gemm_4p<0, 1, 1><<<dim3(8, 32), 512, 0, stream>>>(AOb, woT, bo, x, z1b, M, 1024, 1024);

    ln_one<1><<<M, 256, 0, stream>>>(z1b, g1, be1, x2b);

    // FFN1 (ReLU); 4p: grid 32x32 = 1024 -> 4 clean rounds
    gemm_4p<1, 1, 0><<<dim3(32, 32), 512, 0, stream>>>(x2b, w1T, b1, nullptr, h1,
                                                       M, 4096, 1024);
    // FFN2 + fused residual (x2b); 4p: grid 8x32 = 256 = 1/CU, nt = 64
    gemm_4p<0, 1, 2><<<dim3(8, 32), 512, 0, stream>>>(h1, w2T, b2, x2b, z2b,
                                                      M, 1024, 4096);

    ln_one<0><<<M, 256, 0, stream>>>(z2b, g2, be2, (float*)d_out);
}

// Round 13
// 419.764 us; speedup vs baseline: 1.1072x; 1.1072x over previous
//
#include <hip/hip_runtime.h>
#include <hip/hip_bf16.h>

// ---------- types ----------
typedef __attribute__((ext_vector_type(8)))  __bf16 bf16x8;
typedef __attribute__((ext_vector_type(4)))  float  f32x4;
typedef __attribute__((ext_vector_type(16))) float  f32x16;

static __device__ __forceinline__ unsigned short f2bf(float x) {
    unsigned int u = __float_as_uint(x);
    unsigned int r = (u + 0x7FFFu + ((u >> 16) & 1u)) >> 16;
    return (unsigned short)r;
}
static __device__ __forceinline__ float bf2f(unsigned short u) {
    return __uint_as_float(((unsigned int)u) << 16);
}

// 2^x via v_exp_f32 (CDNA VALU has HW interlocks; no nop needed)
static __device__ __forceinline__ float fast_exp2(float x) {
    float r;
    asm("v_exp_f32 %0, %1" : "=v"(r) : "v"(x));
    return r;
}
// packed f32x2 -> bf16x2 (u32); lo <- a, hi <- b
static __device__ __forceinline__ unsigned int cvt_pk_bf16(float a, float b) {
    unsigned int r;
    asm("v_cvt_pk_bf16_f32 %0, %1, %2" : "=v"(r) : "v"(a), "v"(b));
    return r;
}

// async global->LDS, 16B per lane; lds base wave-uniform (lane*16 auto-offset)
static __device__ __forceinline__ void gload_lds16(const ushort* g, ushort* l) {
    __builtin_amdgcn_global_load_lds((const __attribute__((address_space(1))) void*)g,
                                     (__attribute__((address_space(3))) void*)l, 16, 0, 0);
}

// raw barrier + scheduling/memory fence (no vmcnt drain, unlike __syncthreads)
static __device__ __forceinline__ void barrier_fence() {
    __builtin_amdgcn_s_barrier();
    __builtin_amdgcn_sched_barrier(0);
    asm volatile("" ::: "memory");
}

// T1: XCD-aware chunked remap (requires nwg % 8 == 0; all grids here comply)
static __device__ __forceinline__ int xcd_swz(int id, int nwg) {
    return (id & 7) * (nwg >> 3) + (id >> 3);
}

// ---------- elementwise cast f32 -> bf16 ----------
__global__ __launch_bounds__(256) void cast_bf16_kernel(const float* __restrict__ in,
                                                        ushort* __restrict__ out, int n4) {
    int i = blockIdx.x * 256 + threadIdx.x;
    if (i < n4) {
        float4 v = reinterpret_cast<const float4*>(in)[i];
        ushort4 o;
        o.x = f2bf(v.x); o.y = f2bf(v.y); o.z = f2bf(v.z); o.w = f2bf(v.w);
        reinterpret_cast<ushort4*>(out)[i] = o;
    }
}

// ---------- transpose + cast: in[K][N] f32 -> out[N][K] bf16 ----------
__global__ __launch_bounds__(256) void transpose_cast_kernel(const float* __restrict__ in,
                                                             ushort* __restrict__ out,
                                                             int K, int N) {
    __shared__ float tile[32][33];
    const int tx = threadIdx.x;
    const int ty = threadIdx.y;
    const int n0 = blockIdx.x * 32;
    const int k0 = blockIdx.y * 32;
    for (int i = ty; i < 32; i += 8)
        tile[i][tx] = in[(size_t)(k0 + i) * N + n0 + tx];
    __syncthreads();
    for (int i = ty; i < 32; i += 8)
        out[(size_t)(n0 + i) * K + k0 + tx] = f2bf(tile[tx][i]);
}

// three 1024x1024 transposes (Wq,Wk,Wv) in one launch; z picks the source
__global__ __launch_bounds__(256) void transpose_cast3_kernel(const float* __restrict__ w0,
                                                              const float* __restrict__ w1,
                                                              const float* __restrict__ w2,
                                                              ushort* __restrict__ out) {
    __shared__ float tile[32][33];
    const int tx = threadIdx.x;
    const int ty = threadIdx.y;
    const int n0 = blockIdx.x * 32;
    const int k0 = blockIdx.y * 32;
    const int z  = blockIdx.z;
    const float* in = (z == 0) ? w0 : (z == 1 ? w1 : w2);
    ushort* o = out + (size_t)z * 1024 * 1024;
    for (int i = ty; i < 32; i += 8)
        tile[i][tx] = in[(size_t)(k0 + i) * 1024 + n0 + tx];
    __syncthreads();
    for (int i = ty; i < 32; i += 8)
        o[(size_t)(n0 + i) * 1024 + k0 + tx] = f2bf(tile[tx][i]);
}

// ============================================================================
// gemm_p3 (proven round-8/11 structure): 128x128, BK=32, 256 thr, 3 LDS bufs,
// counted vmcnt(4), 1 barrier/tile. For QKV (1536 blk) and FFN1 (2048 blk).
// ============================================================================
template<int RELU, int OUTBF, int QKV, int RES>
__global__ __launch_bounds__(256) void gemm_p3(const ushort* __restrict__ A,
                                               const ushort* __restrict__ Bt,
                                               const float* __restrict__ b0,
                                               const float* __restrict__ b1_,
                                               const float* __restrict__ b2_,
                                               const void* __restrict__ xres,
                                               void* __restrict__ Cp,
                                               int M, int N, int K) {
    __shared__ ushort As[3][4096];
    __shared__ ushort Bs[3][4096];
    const int tid  = threadIdx.x;
    const int lane = tid & 63;
    const int w    = tid >> 6;
    const int wr   = w >> 1, wc = w & 1;
    const int nwg = gridDim.x * gridDim.y;
    int wid = xcd_swz(blockIdx.y * gridDim.x + blockIdx.x, nwg);
    const int bx = wid % gridDim.x;
    const int by = wid / gridDim.x;
    const int m0 = by * 128;
    const int n0 = bx * 128;
    const int lr = lane & 15;
    const int lg = lane >> 4;
    const int xc = (lg ^ ((lr >> 1) & 3)) * 8;

    const int r0 = w * 32 + (lane >> 2);
    const int c8 = ((lane & 3) ^ ((lane >> 3) & 3)) * 8;
    const ushort* gA0 = A  + (size_t)(m0 + r0)      * K + c8;
    const ushort* gA1 = A  + (size_t)(m0 + r0 + 16) * K + c8;
    const ushort* gB0 = Bt + (size_t)(n0 + r0)      * K + c8;
    const ushort* gB1 = Bt + (size_t)(n0 + r0 + 16) * K + c8;
    const int wb = w * 1024;

    f32x4 acc[4][4];
    const f32x4 z = {0.f, 0.f, 0.f, 0.f};
#pragma unroll
    for (int i = 0; i < 4; i++)
#pragma unroll
        for (int j = 0; j < 4; j++) acc[i][j] = z;

    const int nt = K >> 5;

#pragma unroll
    for (int t = 0; t < 2; ++t) {
        const int kn = t * 32;
        gload_lds16(gA0 + kn, &As[t][wb]);
        gload_lds16(gA1 + kn, &As[t][wb + 512]);
        gload_lds16(gB0 + kn, &Bs[t][wb]);
        gload_lds16(gB1 + kn, &Bs[t][wb + 512]);
    }

    int cur = 0;
    for (int t = 0; t < nt; ++t) {
        if (t + 1 < nt) asm volatile("s_waitcnt vmcnt(4)" ::: "memory");
        else            asm volatile("s_waitcnt vmcnt(0)" ::: "memory");
        barrier_fence();

        if (t + 2 < nt) {
            const int bi = (cur + 2 >= 3) ? cur - 1 : cur + 2;
            const int kn = (t + 2) * 32;
            gload_lds16(gA0 + kn, &As[bi][wb]);
            gload_lds16(gA1 + kn, &As[bi][wb + 512]);
            gload_lds16(gB0 + kn, &Bs[bi][wb]);
            gload_lds16(gB1 + kn, &Bs[bi][wb + 512]);
        }

        const ushort* Asb = As[cur];
        const ushort* Bsb = Bs[cur];
        bf16x8 af[4], bfr[4];
#pragma unroll
        for (int i = 0; i < 4; i++)
            af[i] = *reinterpret_cast<const bf16x8*>(&Asb[(wr * 64 + i * 16 + lr) * 32 + xc]);
#pragma unroll
        for (int j = 0; j < 4; j++)
            bfr[j] = *reinterpret_cast<const bf16x8*>(&Bsb[(wc * 64 + j * 16 + lr) * 32 + xc]);
#pragma unroll
        for (int i = 0; i < 4; i++)
#pragma unroll
            for (int j = 0; j < 4; j++)
                acc[i][j] = __builtin_amdgcn_mfma_f32_16x16x32_bf16(af[i], bfr[j], acc[i][j], 0, 0, 0);

        cur = (cur == 2) ? 0 : cur + 1;
    }

    const float* bias;
    float qscale = 1.0f;
    if (QKV) {
        bias = (n0 < 1024) ? b0 : (n0 < 2048 ? b1_ : b2_);
        if (n0 < 1024) qscale = 0.18033688f;
    } else {
        bias = b0;
    }
    const int nb = QKV ? (n0 & 1023) : n0;
    const int rbase = (lane >> 4) * 4;
#pragma unroll
    for (int i = 0; i < 4; i++) {
#pragma unroll
        for (int j = 0; j < 4; j++) {
            const int cloc = wc * 64 + j * 16 + lr;
            const float bv = bias[nb + cloc];
#pragma unroll
            for (int r = 0; r < 4; r++) {
                const int row = m0 + wr * 64 + i * 16 + rbase + r;
                float v = acc[i][j][r] + bv;
                if (RES == 1) v += ((const float*)xres)[(size_t)row * N + n0 + cloc];
                if (RES == 2) v += bf2f(((const ushort*)xres)[(size_t)row * N + n0 + cloc]);
                if (RELU) v = v > 0.f ? v : 0.f;
                if (QKV)  v *= qscale;
                if (OUTBF) ((ushort*)Cp)[(size_t)row * N + n0 + cloc] = f2bf(v);
                else       ((float*)Cp)[(size_t)row * N + n0 + cloc] = v;
            }
        }
    }
}

// ============================================================================
// gemm_n64: same p3 pipeline at BM=128 x BN=64 (for N=1024 GEMMs: Wo, FFN2).
// Grid doubles to 1024 blocks -> 4 blocks/CU (LDS 3x12KB = 36KB caps at 4).
// 4 waves (2Mx2N), per-wave 64x32 out (acc[4][2]). 3 gloads/thread/tile
// (2 A + 1 B) -> vmcnt(3). Swizzle identical algebra to gemm_p3:
// staging rows give s(row) = (lane>>3)&3 for both A (r0=w*32+lane>>2) and
// B (rB=tid>>2, since (w*64 offsets) % 4 == 0); reads give s = (lr>>1)&3.
// ============================================================================
template<int RELU, int OUTBF, int RES>
__global__ __launch_bounds__(256) void gemm_n64(const ushort* __restrict__ A,
                                                const ushort* __restrict__ Bt,
                                                const float* __restrict__ bias,
                                                const void* __restrict__ xres,
                                                void* __restrict__ Cp,
                                                int M, int N, int K) {
    __shared__ ushort As[3][4096];   // [128][32]
    __shared__ ushort Bs[3][2048];   // [64][32]
    const int tid  = threadIdx.x;
    const int lane = tid & 63;
    const int w    = tid >> 6;
    const int wr   = w >> 1, wc = w & 1;
    const int nwg = gridDim.x * gridDim.y;
    int wid = xcd_swz(blockIdx.y * gridDim.x + blockIdx.x, nwg);
    const int bx = wid % gridDim.x;
    const int by = wid / gridDim.x;
    const int m0 = by * 128;
    const int n0 = bx * 64;
    const int lr = lane & 15;
    const int lg = lane >> 4;
    const int xc = (lg ^ ((lr >> 1) & 3)) * 8;

    const int r0 = w * 32 + (lane >> 2);
    const int c8 = ((lane & 3) ^ ((lane >> 3) & 3)) * 8;
    const ushort* gA0 = A  + (size_t)(m0 + r0)      * K + c8;
    const ushort* gA1 = A  + (size_t)(m0 + r0 + 16) * K + c8;
    const ushort* gB0 = Bt + (size_t)(n0 + (tid >> 2)) * K + c8;   // rB = tid>>2 (0..63)
    const int wb  = w * 1024;
    const int wbB = w * 512;

    f32x4 acc[4][2];
    const f32x4 z = {0.f, 0.f, 0.f, 0.f};
#pragma unroll
    for (int i = 0; i < 4; i++)
#pragma unroll
        for (int j = 0; j < 2; j++) acc[i][j] = z;

    const int nt = K >> 5;

#pragma unroll
    for (int t = 0; t < 2; ++t) {
        const int kn = t * 32;
        gload_lds16(gA0 + kn, &As[t][wb]);
        gload_lds16(gA1 + kn, &As[t][wb + 512]);
        gload_lds16(gB0 + kn, &Bs[t][wbB]);
    }

    int cur = 0;
    for (int t = 0; t < nt; ++t) {
        if (t + 1 < nt) asm volatile("s_waitcnt vmcnt(3)" ::: "memory");
        else            asm volatile("s_waitcnt vmcnt(0)" ::: "memory");
        barrier_fence();

        if (t + 2 < nt) {
            const int bi = (cur + 2 >= 3) ? cur - 1 : cur + 2;
            const int kn = (t + 2) * 32;
            gload_lds16(gA0 + kn, &As[bi][wb]);
            gload_lds16(gA1 + kn, &As[bi][wb + 512]);
            gload_lds16(gB0 + kn, &Bs[bi][wbB]);
        }

        const ushort* Asb = As[cur];
        const ushort* Bsb = Bs[cur];
        bf16x8 af[4], bfr[2];
#pragma unroll
        for (int i = 0; i < 4; i++)
            af[i] = *reinterpret_cast<const bf16x8*>(&Asb[(wr * 64 + i * 16 + lr) * 32 + xc]);
#pragma unroll
        for (int j = 0; j < 2; j++)
            bfr[j] = *reinterpret_cast<const bf16x8*>(&Bsb[(wc * 32 + j * 16 + lr) * 32 + xc]);
#pragma unroll
        for (int i = 0; i < 4; i++)
#pragma unroll
            for (int j = 0; j < 2; j++)
                acc[i][j] = __builtin_amdgcn_mfma_f32_16x16x32_bf16(af[i], bfr[j], acc[i][j], 0, 0, 0);

        cur = (cur == 2) ? 0 : cur + 1;
    }

    const int rbase = (lane >> 4) * 4;
#pragma unroll
    for (int i = 0; i < 4; i++) {
#pragma unroll
        for (int j = 0; j < 2; j++) {
            const int cloc = wc * 32 + j * 16 + lr;
            const float bv = bias[n0 + cloc];
#pragma unroll
            for (int r = 0; r < 4; r++) {
                const int row = m0 + wr * 64 + i * 16 + rbase + r;
                float v = acc[i][j][r] + bv;
                if (RES == 1) v += ((const float*)xres)[(size_t)row * N + n0 + cloc];
                if (RES == 2) v += bf2f(((const ushort*)xres)[(size_t)row * N + n0 + cloc]);
                if (RELU) v = v > 0.f ? v : 0.f;
                if (OUTBF) ((ushort*)Cp)[(size_t)row * N + n0 + cloc] = f2bf(v);
                else       ((float*)Cp)[(size_t)row * N + n0 + cloc] = v;
            }
        }
    }
}

// ---------- flash attention, 32x32 swapped-QK^T, in-register P (T12) ----------
#define ASWZ(row, col) ((row) * 64 + ((col) ^ ((((row) ^ ((row) >> 3)) & 7) << 3)))

__global__ __launch_bounds__(256, 3) void attn_kernel(const ushort* __restrict__ QKV,
                                                      ushort* __restrict__ O) {
    __shared__ ushort Ks[2][4096];
    __shared__ ushort Vt[2][4096];
    const int tid  = threadIdx.x;
    const int lane = tid & 63;
    const int w    = tid >> 6;
    const int l31  = lane & 31;
    const int hi   = lane >> 5;

    int blk = xcd_swz(blockIdx.x, gridDim.x);
    const int qb = blk & 15;
    const int h  = (blk >> 4) & 15;
    const int b  = blk >> 8;
    const int s0 = qb * 128 + w * 32;
    const size_t rowb   = (size_t)b * 2048;
    const size_t base_q = rowb * 3072 + (size_t)h * 64;
    const size_t base_k = base_q + 1024;
    const size_t base_v = base_q + 2048;
    const size_t base_o = rowb * 1024 + (size_t)h * 64;

    bf16x8 qf[4];
#pragma unroll
    for (int ks = 0; ks < 4; ks++)
        qf[ks] = *reinterpret_cast<const bf16x8*>(
            &QKV[base_q + (size_t)(s0 + l31) * 3072 + ks * 16 + 8 * hi]);

    int off8[2][4];
#pragma unroll
    for (int sub = 0; sub < 2; sub++)
#pragma unroll
        for (int ks = 0; ks < 4; ks++)
            off8[sub][ks] = ASWZ(sub * 32 + l31, ks * 16 + 8 * hi);

    const int tS2 = tid >> 3;
    const int ccS = tid & 7;
    int voff[8];
#pragma unroll
    for (int jj = 0; jj < 8; jj++)
        voff[jj] = ASWZ(ccS * 8 + jj, 2 * tS2);
    const int tk1 = tS2 + 32;
    const int sz0 = (tS2 ^ (tS2 >> 3)) & 7;
    const int sz1 = (tk1 ^ (tk1 >> 3)) & 7;
    const ushort* pK0 = QKV + base_k + (size_t)tS2 * 3072 + (ccS ^ sz0) * 8;
    const ushort* pK1 = QKV + base_k + (size_t)tk1 * 3072 + (ccS ^ sz1) * 8;
    const ushort* pV0 = QKV + base_v + (size_t)(2 * tS2)     * 3072 + ccS * 8;
    const ushort* pV1 = QKV + base_v + (size_t)(2 * tS2 + 1) * 3072 + ccS * 8;
    const size_t step = (size_t)64 * 3072;

    gload_lds16(pK0, &Ks[0][w * 512]);
    gload_lds16(pK1, &Ks[0][2048 + w * 512]);
    {
        int4 v0 = *reinterpret_cast<const int4*>(pV0);
        int4 v1 = *reinterpret_cast<const int4*>(pV1);
        const ushort* vs0 = reinterpret_cast<const ushort*>(&v0);
        const ushort* vs1 = reinterpret_cast<const ushort*>(&v1);
#pragma unroll
        for (int jj = 0; jj < 8; jj++)
            *reinterpret_cast<unsigned*>(&Vt[0][voff[jj]]) =
                (unsigned)vs0[jj] | ((unsigned)vs1[jj] << 16);
    }
    pK0 += step; pK1 += step; pV0 += step; pV1 += step;
    __syncthreads();

    f32x16 oacc0, oacc1;
    for (int i = 0; i < 16; i++) { oacc0[i] = 0.f; oacc1[i] = 0.f; }
    float lacc = 0.f;
    int cur = 0;

    for (int it = 0; it < 32; ++it) {
        int4 nv0, nv1;
        if (it < 31) {
            gload_lds16(pK0, &Ks[cur ^ 1][w * 512]);
            gload_lds16(pK1, &Ks[cur ^ 1][2048 + w * 512]);
            nv0 = *reinterpret_cast<const int4*>(pV0);
            nv1 = *reinterpret_cast<const int4*>(pV1);
            pK0 += step; pK1 += step; pV0 += step; pV1 += step;
        }

        f32x16 sa0, sa1;
        for (int i = 0; i < 16; i++) { sa0[i] = 0.f; sa1[i] = 0.f; }
        __builtin_amdgcn_s_setprio(1);
#pragma unroll
        for (int ks = 0; ks < 4; ks++) {
            bf16x8 k0 = *reinterpret_cast<const bf16x8*>(&Ks[cur][off8[0][ks]]);
            sa0 = __builtin_amdgcn_mfma_f32_32x32x16_bf16(k0, qf[ks], sa0, 0, 0, 0);
        }
#pragma unroll
        for (int ks = 0; ks < 4; ks++) {
            bf16x8 k1 = *reinterpret_cast<const bf16x8*>(&Ks[cur][off8[1][ks]]);
            sa1 = __builtin_amdgcn_mfma_f32_32x32x16_bf16(k1, qf[ks], sa1, 0, 0, 0);
        }
        __builtin_amdgcn_s_setprio(0);

        unsigned pk0[8], pk1[8];
#pragma unroll
        for (int i = 0; i < 8; i++) {
            float plo = fast_exp2(sa0[2 * i]);
            float phi = fast_exp2(sa0[2 * i + 1]);
            lacc += plo + phi;
            pk0[i] = cvt_pk_bf16(plo, phi);
        }
#pragma unroll
        for (int i = 0; i < 8; i++) {
            float plo = fast_exp2(sa1[2 * i]);
            float phi = fast_exp2(sa1[2 * i + 1]);
            lacc += plo + phi;
            pk1[i] = cvt_pk_bf16(plo, phi);
        }

        __builtin_amdgcn_s_setprio(1);
#pragma unroll
        for (int ks = 0; ks < 4; ks++) {
            const int bi = 4 * (ks & 1);
            unsigned a, bb, c, d;
            if (ks < 2) { a = pk0[bi]; bb = pk0[bi + 1]; c = pk0[bi + 2]; d = pk0[bi + 3]; }
            else        { a = pk1[bi]; bb = pk1[bi + 1]; c = pk1[bi + 2]; d = pk1[bi + 3]; }
            asm("v_permlane32_swap_b32 %0, %1" : "+v"(a), "+v"(c));
            asm("v_permlane32_swap_b32 %0, %1" : "+v"(bb), "+v"(d));
            union { unsigned u[4]; bf16x8 v; } fr;
            fr.u[0] = a; fr.u[1] = bb; fr.u[2] = c; fr.u[3] = d;
            bf16x8 v0 = *reinterpret_cast<const bf16x8*>(&Vt[cur][off8[0][ks]]);
            oacc0 = __builtin_amdgcn_mfma_f32_32x32x16_bf16(fr.v, v0, oacc0, 0, 0, 0);
            bf16x8 v1 = *reinterpret_cast<const bf16x8*>(&Vt[cur][off8[1][ks]]);
            oacc1 = __builtin_amdgcn_mfma_f32_32x32x16_bf16(fr.v, v1, oacc1, 0, 0, 0);
        }
        __builtin_amdgcn_s_setprio(0);

        if (it < 31) {
            const ushort* vs0 = reinterpret_cast<const ushort*>(&nv0);
            const ushort* vs1 = reinterpret_cast<const ushort*>(&nv1);
#pragma unroll
            for (int jj = 0; jj < 8; jj++)
                *reinterpret_cast<unsigned*>(&Vt[cur ^ 1][voff[jj]]) =
                    (unsigned)vs0[jj] | ((unsigned)vs1[jj] << 16);
        }
        __syncthreads();
        cur ^= 1;
    }

    const float ltot = lacc + __shfl_xor(lacc, 32);
    const float inv  = 1.f / ltot;
#pragma unroll
    for (int r = 0; r < 16; r++) {
        const int qloc = (r & 3) + 8 * (r >> 2) + 4 * hi;
        const float invq = __shfl(inv, qloc);
        const size_t rowoff = base_o + (size_t)(s0 + qloc) * 1024 + l31;
        O[rowoff]      = f2bf(oacc0[r] * invq);
        O[rowoff + 32] = f2bf(oacc1[r] * invq);
    }
}

// ---------- single-input layernorm ----------
template<int OUTBF>
__global__ __launch_bounds__(256) void ln_one(const ushort* __restrict__ zin,
                                              const float* __restrict__ g,
                                              const float* __restrict__ be,
                                              void* __restrict__ out) {
    const int row = blockIdx.x;
    const int tid = threadIdx.x;
    const ushort4 zv = reinterpret_cast<const ushort4*>(zin + (size_t)row * 1024)[tid];
    float v[4] = {bf2f(zv.x), bf2f(zv.y), bf2f(zv.z), bf2f(zv.w)};
    float s  = v[0] + v[1] + v[2] + v[3];
    float s2 = v[0]*v[0] + v[1]*v[1] + v[2]*v[2] + v[3]*v[3];
    for (int off = 32; off; off >>= 1) { s += __shfl_down(s, off); s2 += __shfl_down(s2, off); }
    __shared__ float red[8];
    const int w = tid >> 6, lane = tid & 63;
    if (lane == 0) { red[w] = s; red[4 + w] = s2; }
    __syncthreads();
    if (tid == 0) {
        const float ts  = red[0] + red[1] + red[2] + red[3];
        const float ts2 = red[4] + red[5] + red[6] + red[7];
        const float mu  = ts * (1.f / 1024.f);
        const float var = ts2 * (1.f / 1024.f) - mu * mu;
        red[0] = mu;
        red[1] = rsqrtf(var + 1e-5f);
    }
    __syncthreads();
    const float mu = red[0], rs = red[1];
    const float4 gv = reinterpret_cast<const float4*>(g)[tid];
    const float4 bv = reinterpret_cast<const float4*>(be)[tid];
    float o0 = (v[0] - mu) * rs * gv.x + bv.x;
    float o1 = (v[1] - mu) * rs * gv.y + bv.y;
    float o2 = (v[2] - mu) * rs * gv.z + bv.z;
    float o3 = (v[3] - mu) * rs * gv.w + bv.w;
    if (OUTBF) {
        ushort4 ob;
        ob.x = f2bf(o0); ob.y = f2bf(o1); ob.z = f2bf(o2); ob.w = f2bf(o3);
        reinterpret_cast<ushort4*>((ushort*)out + (size_t)row * 1024)[tid] = ob;
    } else {
        float4 of;
        of.x = o0; of.y = o1; of.z = o2; of.w = o3;
        reinterpret_cast<float4*>((float*)out + (size_t)row * 1024)[tid] = of;
    }
}

// ---------- launch ----------
extern "C" void kernel_launch(void* const* d_in, const int* in_sizes, int n_in,
                              void* d_out, int out_size, void* d_ws, size_t ws_size,
                              hipStream_t stream) {
    const float* x  = (const float*)d_in[0];
    const float* Wq = (const float*)d_in[1];  const float* bq = (const float*)d_in[2];
    const float* Wk = (const float*)d_in[3];  const float* bk = (const float*)d_in[4];
    const float* Wv = (const float*)d_in[5];  const float* bv = (const float*)d_in[6];
    const float* Wo = (const float*)d_in[7];  const float* bo = (const float*)d_in[8];
    const float* W1 = (const float*)d_in[9];  const float* b1 = (const float*)d_in[10];
    const float* W2 = (const float*)d_in[11]; const float* b2 = (const float*)d_in[12];
    const float* g1 = (const float*)d_in[13]; const float* be1 = (const float*)d_in[14];
    const float* g2 = (const float*)d_in[15]; const float* be2 = (const float*)d_in[16];

    char* ws = (char*)d_ws;
    const size_t MBy = (size_t)1 << 20;
    ushort* xb    = (ushort*)(ws + 0 * MBy);     // 16 MB  [8192][1024] bf16
    ushort* wqkvT = (ushort*)(ws + 16 * MBy);    // 6 MB   [3072][1024]
    ushort* woT   = (ushort*)(ws + 22 * MBy);    // 2 MB
    ushort* w1T   = (ushort*)(ws + 24 * MBy);    // 8 MB   [4096][1024]
    ushort* w2T   = (ushort*)(ws + 32 * MBy);    // 8 MB   [1024][4096]
    ushort* QKVb  = (ushort*)(ws + 40 * MBy);    // 48 MB  [8192][3072]
    ushort* AOb   = (ushort*)(ws + 88 * MBy);    // 16 MB
    ushort* h1    = (ushort*)(ws + 40 * MBy);    // 64 MB (aliases QKVb+AOb, both dead by FFN1)
    ushort* z1b   = (ushort*)(ws + 104 * MBy);   // 16 MB  x + attn_out (bf16)
    ushort* z2b   = (ushort*)(ws + 104 * MBy);   // aliases z1b (dead after LN1)
    ushort* x2b   = (ushort*)(ws + 120 * MBy);   // 16 MB
    (void)ws_size; (void)n_in; (void)in_sizes; (void)out_size;

    const int M = 8192;

    cast_bf16_kernel<<<(M * 1024 / 4 + 255) / 256, 256, 0, stream>>>(x, xb, M * 1024 / 4);
    dim3 tb(32, 8);
    transpose_cast3_kernel<<<dim3(32, 32, 3), tb, 0, stream>>>(Wq, Wk, Wv, wqkvT);
    transpose_cast_kernel<<<dim3(32, 32),  tb, 0, stream>>>(Wo, woT, 1024, 1024);
    transpose_cast_kernel<<<dim3(128, 32), tb, 0, stream>>>(W1, w1T, 1024, 4096);
    transpose_cast_kernel<<<dim3(32, 128), tb, 0, stream>>>(W2, w2T, 4096, 1024);

    // QKV projection (p3; 1536 blocks -> 3/CU)
    gemm_p3<0, 1, 1, 0><<<dim3(24, 64), 256, 0, stream>>>(xb, wqkvT, bq, bk, bv, nullptr,
                                                          QKVb, M, 3072, 1024);

    attn_kernel<<<1024, 256, 0, stream>>>(QKVb, AOb);

    // Wo + fused residual (x, f32) -> z1 (bf16); n64: 16x64 = 1024 blocks -> 4/CU
    gemm_n64<0, 1, 1><<<dim3(16, 64), 256, 0, stream>>>(AOb, woT, bo, x, z1b,
                                                        M, 1024, 1024);

    ln_one<1><<<M, 256, 0, stream>>>(z1b, g1, be1, x2b);

    // FFN1 (p3; 2048 blocks -> 3/CU)
    gemm_p3<1, 1, 0, 0><<<dim3(32, 64), 256, 0, stream>>>(x2b, w1T, b1, nullptr, nullptr,
                                                          nullptr, h1, M, 4096, 1024);
    // FFN2 + fused residual; n64: 1024 blocks -> 4/CU, nt = 128
    gemm_n64<0, 1, 2><<<dim3(16, 64), 256, 0, stream>>>(h1, w2T, b2, x2b, z2b,
                                                        M, 1024, 4096);

    ln_one<0><<<M, 256, 0, stream>>>(z2b, g2, be2, (float*)d_out);
}

// Round 14
// 419.649 us; speedup vs baseline: 1.1075x; 1.0003x over previous
//
#include <hip/hip_runtime.h>
#include <hip/hip_bf16.h>

// ---------- types ----------
typedef __attribute__((ext_vector_type(8)))  __bf16 bf16x8;
typedef __attribute__((ext_vector_type(4)))  float  f32x4;
typedef __attribute__((ext_vector_type(16))) float  f32x16;

static __device__ __forceinline__ unsigned short f2bf(float x) {
    unsigned int u = __float_as_uint(x);
    unsigned int r = (u + 0x7FFFu + ((u >> 16) & 1u)) >> 16;
    return (unsigned short)r;
}
static __device__ __forceinline__ float bf2f(unsigned short u) {
    return __uint_as_float(((unsigned int)u) << 16);
}

// 2^x via v_exp_f32 (CDNA VALU has HW interlocks; no nop needed)
static __device__ __forceinline__ float fast_exp2(float x) {
    float r;
    asm("v_exp_f32 %0, %1" : "=v"(r) : "v"(x));
    return r;
}
// packed f32x2 -> bf16x2 (u32); lo <- a, hi <- b
static __device__ __forceinline__ unsigned int cvt_pk_bf16(float a, float b) {
    unsigned int r;
    asm("v_cvt_pk_bf16_f32 %0, %1, %2" : "=v"(r) : "v"(a), "v"(b));
    return r;
}

// async global->LDS, 16B per lane; lds base wave-uniform (lane*16 auto-offset)
static __device__ __forceinline__ void gload_lds16(const ushort* g, ushort* l) {
    __builtin_amdgcn_global_load_lds((const __attribute__((address_space(1))) void*)g,
                                     (__attribute__((address_space(3))) void*)l, 16, 0, 0);
}

// raw barrier + scheduling/memory fence (no vmcnt drain, unlike __syncthreads)
static __device__ __forceinline__ void barrier_fence() {
    __builtin_amdgcn_s_barrier();
    __builtin_amdgcn_sched_barrier(0);
    asm volatile("" ::: "memory");
}

// T1: XCD-aware chunked remap (requires nwg % 8 == 0; all grids here comply)
static __device__ __forceinline__ int xcd_swz(int id, int nwg) {
    return (id & 7) * (nwg >> 3) + (id >> 3);
}

// ---------- elementwise cast f32 -> bf16 ----------
__global__ __launch_bounds__(256) void cast_bf16_kernel(const float* __restrict__ in,
                                                        ushort* __restrict__ out, int n4) {
    int i = blockIdx.x * 256 + threadIdx.x;
    if (i < n4) {
        float4 v = reinterpret_cast<const float4*>(in)[i];
        ushort4 o;
        o.x = f2bf(v.x); o.y = f2bf(v.y); o.z = f2bf(v.z); o.w = f2bf(v.w);
        reinterpret_cast<ushort4*>(out)[i] = o;
    }
}

// ---------- transpose + cast: in[K][N] f32 -> out[N][K] bf16 ----------
__global__ __launch_bounds__(256) void transpose_cast_kernel(const float* __restrict__ in,
                                                             ushort* __restrict__ out,
                                                             int K, int N) {
    __shared__ float tile[32][33];
    const int tx = threadIdx.x;
    const int ty = threadIdx.y;
    const int n0 = blockIdx.x * 32;
    const int k0 = blockIdx.y * 32;
    for (int i = ty; i < 32; i += 8)
        tile[i][tx] = in[(size_t)(k0 + i) * N + n0 + tx];
    __syncthreads();
    for (int i = ty; i < 32; i += 8)
        out[(size_t)(n0 + i) * K + k0 + tx] = f2bf(tile[tx][i]);
}

// three 1024x1024 transposes (Wq,Wk,Wv) in one launch; z picks the source
__global__ __launch_bounds__(256) void transpose_cast3_kernel(const float* __restrict__ w0,
                                                              const float* __restrict__ w1,
                                                              const float* __restrict__ w2,
                                                              ushort* __restrict__ out) {
    __shared__ float tile[32][33];
    const int tx = threadIdx.x;
    const int ty = threadIdx.y;
    const int n0 = blockIdx.x * 32;
    const int k0 = blockIdx.y * 32;
    const int z  = blockIdx.z;
    const float* in = (z == 0) ? w0 : (z == 1 ? w1 : w2);
    ushort* o = out + (size_t)z * 1024 * 1024;
    for (int i = ty; i < 32; i += 8)
        tile[i][tx] = in[(size_t)(k0 + i) * 1024 + n0 + tx];
    __syncthreads();
    for (int i = ty; i < 32; i += 8)
        o[(size_t)(n0 + i) * 1024 + k0 + tx] = f2bf(tile[tx][i]);
}

// ============================================================================
// gemm_p3 (proven round-8/11 structure): 128x128, BK=32, 256 thr, 3 LDS bufs,
// counted vmcnt(4), 1 barrier/tile, both-sides chunk swizzle.
// ============================================================================
template<int RELU, int OUTBF, int QKV, int RES>
__global__ __launch_bounds__(256) void gemm_p3(const ushort* __restrict__ A,
                                               const ushort* __restrict__ Bt,
                                               const float* __restrict__ b0,
                                               const float* __restrict__ b1_,
                                               const float* __restrict__ b2_,
                                               const void* __restrict__ xres,
                                               void* __restrict__ Cp,
                                               int M, int N, int K) {
    __shared__ ushort As[3][4096];
    __shared__ ushort Bs[3][4096];
    const int tid  = threadIdx.x;
    const int lane = tid & 63;
    const int w    = tid >> 6;
    const int wr   = w >> 1, wc = w & 1;
    const int nwg = gridDim.x * gridDim.y;
    int wid = xcd_swz(blockIdx.y * gridDim.x + blockIdx.x, nwg);
    const int bx = wid % gridDim.x;
    const int by = wid / gridDim.x;
    const int m0 = by * 128;
    const int n0 = bx * 128;
    const int lr = lane & 15;
    const int lg = lane >> 4;
    const int xc = (lg ^ ((lr >> 1) & 3)) * 8;

    const int r0 = w * 32 + (lane >> 2);
    const int c8 = ((lane & 3) ^ ((lane >> 3) & 3)) * 8;
    const ushort* gA0 = A  + (size_t)(m0 + r0)      * K + c8;
    const ushort* gA1 = A  + (size_t)(m0 + r0 + 16) * K + c8;
    const ushort* gB0 = Bt + (size_t)(n0 + r0)      * K + c8;
    const ushort* gB1 = Bt + (size_t)(n0 + r0 + 16) * K + c8;
    const int wb = w * 1024;

    f32x4 acc[4][4];
    const f32x4 z = {0.f, 0.f, 0.f, 0.f};
#pragma unroll
    for (int i = 0; i < 4; i++)
#pragma unroll
        for (int j = 0; j < 4; j++) acc[i][j] = z;

    const int nt = K >> 5;

#pragma unroll
    for (int t = 0; t < 2; ++t) {
        const int kn = t * 32;
        gload_lds16(gA0 + kn, &As[t][wb]);
        gload_lds16(gA1 + kn, &As[t][wb + 512]);
        gload_lds16(gB0 + kn, &Bs[t][wb]);
        gload_lds16(gB1 + kn, &Bs[t][wb + 512]);
    }

    int cur = 0;
    for (int t = 0; t < nt; ++t) {
        if (t + 1 < nt) asm volatile("s_waitcnt vmcnt(4)" ::: "memory");
        else            asm volatile("s_waitcnt vmcnt(0)" ::: "memory");
        barrier_fence();

        if (t + 2 < nt) {
            const int bi = (cur + 2 >= 3) ? cur - 1 : cur + 2;
            const int kn = (t + 2) * 32;
            gload_lds16(gA0 + kn, &As[bi][wb]);
            gload_lds16(gA1 + kn, &As[bi][wb + 512]);
            gload_lds16(gB0 + kn, &Bs[bi][wb]);
            gload_lds16(gB1 + kn, &Bs[bi][wb + 512]);
        }

        const ushort* Asb = As[cur];
        const ushort* Bsb = Bs[cur];
        bf16x8 af[4], bfr[4];
#pragma unroll
        for (int i = 0; i < 4; i++)
            af[i] = *reinterpret_cast<const bf16x8*>(&Asb[(wr * 64 + i * 16 + lr) * 32 + xc]);
#pragma unroll
        for (int j = 0; j < 4; j++)
            bfr[j] = *reinterpret_cast<const bf16x8*>(&Bsb[(wc * 64 + j * 16 + lr) * 32 + xc]);
#pragma unroll
        for (int i = 0; i < 4; i++)
#pragma unroll
            for (int j = 0; j < 4; j++)
                acc[i][j] = __builtin_amdgcn_mfma_f32_16x16x32_bf16(af[i], bfr[j], acc[i][j], 0, 0, 0);

        cur = (cur == 2) ? 0 : cur + 1;
    }

    const float* bias;
    float qscale = 1.0f;
    if (QKV) {
        bias = (n0 < 1024) ? b0 : (n0 < 2048 ? b1_ : b2_);
        if (n0 < 1024) qscale = 0.18033688f;
    } else {
        bias = b0;
    }
    const int nb = QKV ? (n0 & 1023) : n0;
    const int rbase = (lane >> 4) * 4;
#pragma unroll
    for (int i = 0; i < 4; i++) {
#pragma unroll
        for (int j = 0; j < 4; j++) {
            const int cloc = wc * 64 + j * 16 + lr;
            const float bv = bias[nb + cloc];
#pragma unroll
            for (int r = 0; r < 4; r++) {
                const int row = m0 + wr * 64 + i * 16 + rbase + r;
                float v = acc[i][j][r] + bv;
                if (RES == 1) v += ((const float*)xres)[(size_t)row * N + n0 + cloc];
                if (RES == 2) v += bf2f(((const ushort*)xres)[(size_t)row * N + n0 + cloc]);
                if (RELU) v = v > 0.f ? v : 0.f;
                if (QKV)  v *= qscale;
                if (OUTBF) ((ushort*)Cp)[(size_t)row * N + n0 + cloc] = f2bf(v);
                else       ((float*)Cp)[(size_t)row * N + n0 + cloc] = v;
            }
        }
    }
}

// ============================================================================
// gemm_sk: split-K=2 variant of gemm_p3 for FFN2 (M=8192, N=1024, K=4096,
// ld=4096). Grid (8,128) = 1024 blocks: by&63 -> m-tile, by>>6 -> K-half.
// Each block computes K=2048 into bf16 partial P[sk][M][N] (no bias/res);
// the ln2_reduce kernel sums partials + bias + residual + LN.
// ============================================================================
__global__ __launch_bounds__(256) void gemm_sk(const ushort* __restrict__ A,
                                               const ushort* __restrict__ Bt,
                                               ushort* __restrict__ P,
                                               int M, int N, int ld, int Khalf) {
    __shared__ ushort As[3][4096];
    __shared__ ushort Bs[3][4096];
    const int tid  = threadIdx.x;
    const int lane = tid & 63;
    const int w    = tid >> 6;
    const int wr   = w >> 1, wc = w & 1;
    const int nwg = gridDim.x * gridDim.y;
    int wid = xcd_swz(blockIdx.y * gridDim.x + blockIdx.x, nwg);
    const int bx  = wid % gridDim.x;
    const int byz = wid / gridDim.x;          // 0..127
    const int m0  = (byz & 63) * 128;
    const int sk  = byz >> 6;                 // K-half
    const int koff = sk * Khalf;
    const int n0  = bx * 128;
    const int lr = lane & 15;
    const int lg = lane >> 4;
    const int xc = (lg ^ ((lr >> 1) & 3)) * 8;

    const int r0 = w * 32 + (lane >> 2);
    const int c8 = ((lane & 3) ^ ((lane >> 3) & 3)) * 8;
    const ushort* gA0 = A  + (size_t)(m0 + r0)      * ld + koff + c8;
    const ushort* gA1 = A  + (size_t)(m0 + r0 + 16) * ld + koff + c8;
    const ushort* gB0 = Bt + (size_t)(n0 + r0)      * ld + koff + c8;
    const ushort* gB1 = Bt + (size_t)(n0 + r0 + 16) * ld + koff + c8;
    const int wb = w * 1024;

    f32x4 acc[4][4];
    const f32x4 z = {0.f, 0.f, 0.f, 0.f};
#pragma unroll
    for (int i = 0; i < 4; i++)
#pragma unroll
        for (int j = 0; j < 4; j++) acc[i][j] = z;

    const int nt = Khalf >> 5;

#pragma unroll
    for (int t = 0; t < 2; ++t) {
        const int kn = t * 32;
        gload_lds16(gA0 + kn, &As[t][wb]);
        gload_lds16(gA1 + kn, &As[t][wb + 512]);
        gload_lds16(gB0 + kn, &Bs[t][wb]);
        gload_lds16(gB1 + kn, &Bs[t][wb + 512]);
    }

    int cur = 0;
    for (int t = 0; t < nt; ++t) {
        if (t + 1 < nt) asm volatile("s_waitcnt vmcnt(4)" ::: "memory");
        else            asm volatile("s_waitcnt vmcnt(0)" ::: "memory");
        barrier_fence();

        if (t + 2 < nt) {
            const int bi = (cur + 2 >= 3) ? cur - 1 : cur + 2;
            const int kn = (t + 2) * 32;
            gload_lds16(gA0 + kn, &As[bi][wb]);
            gload_lds16(gA1 + kn, &As[bi][wb + 512]);
            gload_lds16(gB0 + kn, &Bs[bi][wb]);
            gload_lds16(gB1 + kn, &Bs[bi][wb + 512]);
        }

        const ushort* Asb = As[cur];
        const ushort* Bsb = Bs[cur];
        bf16x8 af[4], bfr[4];
#pragma unroll
        for (int i = 0; i < 4; i++)
            af[i] = *reinterpret_cast<const bf16x8*>(&Asb[(wr * 64 + i * 16 + lr) * 32 + xc]);
#pragma unroll
        for (int j = 0; j < 4; j++)
            bfr[j] = *reinterpret_cast<const bf16x8*>(&Bsb[(wc * 64 + j * 16 + lr) * 32 + xc]);
#pragma unroll
        for (int i = 0; i < 4; i++)
#pragma unroll
            for (int j = 0; j < 4; j++)
                acc[i][j] = __builtin_amdgcn_mfma_f32_16x16x32_bf16(af[i], bfr[j], acc[i][j], 0, 0, 0);

        cur = (cur == 2) ? 0 : cur + 1;
    }

    ushort* Pp = P + (size_t)sk * M * N;
    const int rbase = (lane >> 4) * 4;
#pragma unroll
    for (int i = 0; i < 4; i++) {
#pragma unroll
        for (int j = 0; j < 4; j++) {
            const int cloc = wc * 64 + j * 16 + lr;
#pragma unroll
            for (int r = 0; r < 4; r++) {
                const int row = m0 + wr * 64 + i * 16 + rbase + r;
                Pp[(size_t)row * N + n0 + cloc] = f2bf(acc[i][j][r]);
            }
        }
    }
}

// ---------- flash attention, 32x32 swapped-QK^T, in-register P (T12) ----------
#define ASWZ(row, col) ((row) * 64 + ((col) ^ ((((row) ^ ((row) >> 3)) & 7) << 3)))

__global__ __launch_bounds__(256, 4) void attn_kernel(const ushort* __restrict__ QKV,
                                                      ushort* __restrict__ O) {
    __shared__ ushort Ks[2][4096];
    __shared__ ushort Vt[2][4096];
    const int tid  = threadIdx.x;
    const int lane = tid & 63;
    const int w    = tid >> 6;
    const int l31  = lane & 31;
    const int hi   = lane >> 5;

    int blk = xcd_swz(blockIdx.x, gridDim.x);
    const int qb = blk & 15;
    const int h  = (blk >> 4) & 15;
    const int b  = blk >> 8;
    const int s0 = qb * 128 + w * 32;
    const size_t rowb   = (size_t)b * 2048;
    const size_t base_q = rowb * 3072 + (size_t)h * 64;
    const size_t base_k = base_q + 1024;
    const size_t base_v = base_q + 2048;
    const size_t base_o = rowb * 1024 + (size_t)h * 64;

    bf16x8 qf[4];
#pragma unroll
    for (int ks = 0; ks < 4; ks++)
        qf[ks] = *reinterpret_cast<const bf16x8*>(
            &QKV[base_q + (size_t)(s0 + l31) * 3072 + ks * 16 + 8 * hi]);

    int off8[2][4];
#pragma unroll
    for (int sub = 0; sub < 2; sub++)
#pragma unroll
        for (int ks = 0; ks < 4; ks++)
            off8[sub][ks] = ASWZ(sub * 32 + l31, ks * 16 + 8 * hi);

    const int tS2 = tid >> 3;
    const int ccS = tid & 7;
    int voff[8];
#pragma unroll
    for (int jj = 0; jj < 8; jj++)
        voff[jj] = ASWZ(ccS * 8 + jj, 2 * tS2);
    const int tk1 = tS2 + 32;
    const int sz0 = (tS2 ^ (tS2 >> 3)) & 7;
    const int sz1 = (tk1 ^ (tk1 >> 3)) & 7;
    const ushort* pK0 = QKV + base_k + (size_t)tS2 * 3072 + (ccS ^ sz0) * 8;
    const ushort* pK1 = QKV + base_k + (size_t)tk1 * 3072 + (ccS ^ sz1) * 8;
    const ushort* pV0 = QKV + base_v + (size_t)(2 * tS2)     * 3072 + ccS * 8;
    const ushort* pV1 = QKV + base_v + (size_t)(2 * tS2 + 1) * 3072 + ccS * 8;
    const size_t step = (size_t)64 * 3072;

    gload_lds16(pK0, &Ks[0][w * 512]);
    gload_lds16(pK1, &Ks[0][2048 + w * 512]);
    {
        int4 v0 = *reinterpret_cast<const int4*>(pV0);
        int4 v1 = *reinterpret_cast<const int4*>(pV1);
        const ushort* vs0 = reinterpret_cast<const ushort*>(&v0);
        const ushort* vs1 = reinterpret_cast<const ushort*>(&v1);
#pragma unroll
        for (int jj = 0; jj < 8; jj++)
            *reinterpret_cast<unsigned*>(&Vt[0][voff[jj]]) =
                (unsigned)vs0[jj] | ((unsigned)vs1[jj] << 16);
    }
    pK0 += step; pK1 += step; pV0 += step; pV1 += step;
    __syncthreads();

    f32x16 oacc0, oacc1;
    for (int i = 0; i < 16; i++) { oacc0[i] = 0.f; oacc1[i] = 0.f; }
    float lacc = 0.f;
    int cur = 0;

    for (int it = 0; it < 32; ++it) {
        int4 nv0, nv1;
        if (it < 31) {
            gload_lds16(pK0, &Ks[cur ^ 1][w * 512]);
            gload_lds16(pK1, &Ks[cur ^ 1][2048 + w * 512]);
            nv0 = *reinterpret_cast<const int4*>(pV0);
            nv1 = *reinterpret_cast<const int4*>(pV1);
            pK0 += step; pK1 += step; pV0 += step; pV1 += step;
        }

        f32x16 sa0, sa1;
        for (int i = 0; i < 16; i++) { sa0[i] = 0.f; sa1[i] = 0.f; }
        __builtin_amdgcn_s_setprio(1);
#pragma unroll
        for (int ks = 0; ks < 4; ks++) {
            bf16x8 k0 = *reinterpret_cast<const bf16x8*>(&Ks[cur][off8[0][ks]]);
            sa0 = __builtin_amdgcn_mfma_f32_32x32x16_bf16(k0, qf[ks], sa0, 0, 0, 0);
        }
#pragma unroll
        for (int ks = 0; ks < 4; ks++) {
            bf16x8 k1 = *reinterpret_cast<const bf16x8*>(&Ks[cur][off8[1][ks]]);
            sa1 = __builtin_amdgcn_mfma_f32_32x32x16_bf16(k1, qf[ks], sa1, 0, 0, 0);
        }
        __builtin_amdgcn_s_setprio(0);

        unsigned pk0[8], pk1[8];
#pragma unroll
        for (int i = 0; i < 8; i++) {
            float plo = fast_exp2(sa0[2 * i]);
            float phi = fast_exp2(sa0[2 * i + 1]);
            lacc += plo + phi;
            pk0[i] = cvt_pk_bf16(plo, phi);
        }
#pragma unroll
        for (int i = 0; i < 8; i++) {
            float plo = fast_exp2(sa1[2 * i]);
            float phi = fast_exp2(sa1[2 * i + 1]);
            lacc += plo + phi;
            pk1[i] = cvt_pk_bf16(plo, phi);
        }

        __builtin_amdgcn_s_setprio(1);
#pragma unroll
        for (int ks = 0; ks < 4; ks++) {
            const int bi = 4 * (ks & 1);
            unsigned a, bb, c, d;
            if (ks < 2) { a = pk0[bi]; bb = pk0[bi + 1]; c = pk0[bi + 2]; d = pk0[bi + 3]; }
            else        { a = pk1[bi]; bb = pk1[bi + 1]; c = pk1[bi + 2]; d = pk1[bi + 3]; }
            asm("v_permlane32_swap_b32 %0, %1" : "+v"(a), "+v"(c));
            asm("v_permlane32_swap_b32 %0, %1" : "+v"(bb), "+v"(d));
            union { unsigned u[4]; bf16x8 v; } fr;
            fr.u[0] = a; fr.u[1] = bb; fr.u[2] = c; fr.u[3] = d;
            bf16x8 v0 = *reinterpret_cast<const bf16x8*>(&Vt[cur][off8[0][ks]]);
            oacc0 = __builtin_amdgcn_mfma_f32_32x32x16_bf16(fr.v, v0, oacc0, 0, 0, 0);
            bf16x8 v1 = *reinterpret_cast<const bf16x8*>(&Vt[cur][off8[1][ks]]);
            oacc1 = __builtin_amdgcn_mfma_f32_32x32x16_bf16(fr.v, v1, oacc1, 0, 0, 0);
        }
        __builtin_amdgcn_s_setprio(0);

        if (it < 31) {
            const ushort* vs0 = reinterpret_cast<const ushort*>(&nv0);
            const ushort* vs1 = reinterpret_cast<const ushort*>(&nv1);
#pragma unroll
            for (int jj = 0; jj < 8; jj++)
                *reinterpret_cast<unsigned*>(&Vt[cur ^ 1][voff[jj]]) =
                    (unsigned)vs0[jj] | ((unsigned)vs1[jj] << 16);
        }
        __syncthreads();
        cur ^= 1;
    }

    const float ltot = lacc + __shfl_xor(lacc, 32);
    const float inv  = 1.f / ltot;
#pragma unroll
    for (int r = 0; r < 16; r++) {
        const int qloc = (r & 3) + 8 * (r >> 2) + 4 * hi;
        const float invq = __shfl(inv, qloc);
        const size_t rowoff = base_o + (size_t)(s0 + qloc) * 1024 + l31;
        O[rowoff]      = f2bf(oacc0[r] * invq);
        O[rowoff + 32] = f2bf(oacc1[r] * invq);
    }
}

// ---------- single-input layernorm (LN1) ----------
__global__ __launch_bounds__(256) void ln_one_b(const ushort* __restrict__ zin,
                                                const float* __restrict__ g,
                                                const float* __restrict__ be,
                                                ushort* __restrict__ out) {
    const int row = blockIdx.x;
    const int tid = threadIdx.x;
    const ushort4 zv = reinterpret_cast<const ushort4*>(zin + (size_t)row * 1024)[tid];
    float v[4] = {bf2f(zv.x), bf2f(zv.y), bf2f(zv.z), bf2f(zv.w)};
    float s  = v[0] + v[1] + v[2] + v[3];
    float s2 = v[0]*v[0] + v[1]*v[1] + v[2]*v[2] + v[3]*v[3];
    for (int off = 32; off; off >>= 1) { s += __shfl_down(s, off); s2 += __shfl_down(s2, off); }
    __shared__ float red[8];
    const int w = tid >> 6, lane = tid & 63;
    if (lane == 0) { red[w] = s; red[4 + w] = s2; }
    __syncthreads();
    if (tid == 0) {
        const float ts  = red[0] + red[1] + red[2] + red[3];
        const float ts2 = red[4] + red[5] + red[6] + red[7];
        const float mu  = ts * (1.f / 1024.f);
        const float var = ts2 * (1.f / 1024.f) - mu * mu;
        red[0] = mu;
        red[1] = rsqrtf(var + 1e-5f);
    }
    __syncthreads();
    const float mu = red[0], rs = red[1];
    const float4 gv = reinterpret_cast<const float4*>(g)[tid];
    const float4 bv = reinterpret_cast<const float4*>(be)[tid];
    ushort4 ob;
    ob.x = f2bf((v[0] - mu) * rs * gv.x + bv.x);
    ob.y = f2bf((v[1] - mu) * rs * gv.y + bv.y);
    ob.z = f2bf((v[2] - mu) * rs * gv.z + bv.z);
    ob.w = f2bf((v[3] - mu) * rs * gv.w + bv.w);
    reinterpret_cast<ushort4*>(out + (size_t)row * 1024)[tid] = ob;
}

// ---------- LN2 fused with split-K reduction: z = x2 + p0 + p1 + b2, LN -> f32 ----------
__global__ __launch_bounds__(256) void ln2_reduce(const ushort* __restrict__ x2,
                                                  const ushort* __restrict__ p0,
                                                  const ushort* __restrict__ p1,
                                                  const float* __restrict__ b2,
                                                  const float* __restrict__ g,
                                                  const float* __restrict__ be,
                                                  float* __restrict__ out) {
    const int row = blockIdx.x;
    const int tid = threadIdx.x;
    const size_t off = (size_t)row * 1024;
    const ushort4 xv = reinterpret_cast<const ushort4*>(x2 + off)[tid];
    const ushort4 q0 = reinterpret_cast<const ushort4*>(p0 + off)[tid];
    const ushort4 q1 = reinterpret_cast<const ushort4*>(p1 + off)[tid];
    const float4 bb = reinterpret_cast<const float4*>(b2)[tid];
    float v[4];
    v[0] = bf2f(xv.x) + bf2f(q0.x) + bf2f(q1.x) + bb.x;
    v[1] = bf2f(xv.y) + bf2f(q0.y) + bf2f(q1.y) + bb.y;
    v[2] = bf2f(xv.z) + bf2f(q0.z) + bf2f(q1.z) + bb.z;
    v[3] = bf2f(xv.w) + bf2f(q0.w) + bf2f(q1.w) + bb.w;
    float s  = v[0] + v[1] + v[2] + v[3];
    float s2 = v[0]*v[0] + v[1]*v[1] + v[2]*v[2] + v[3]*v[3];
    for (int o = 32; o; o >>= 1) { s += __shfl_down(s, o); s2 += __shfl_down(s2, o); }
    __shared__ float red[8];
    const int w = tid >> 6, lane = tid & 63;
    if (lane == 0) { red[w] = s; red[4 + w] = s2; }
    __syncthreads();
    if (tid == 0) {
        const float ts  = red[0] + red[1] + red[2] + red[3];
        const float ts2 = red[4] + red[5] + red[6] + red[7];
        const float mu  = ts * (1.f / 1024.f);
        const float var = ts2 * (1.f / 1024.f) - mu * mu;
        red[0] = mu;
        red[1] = rsqrtf(var + 1e-5f);
    }
    __syncthreads();
    const float mu = red[0], rs = red[1];
    const float4 gv = reinterpret_cast<const float4*>(g)[tid];
    const float4 bv = reinterpret_cast<const float4*>(be)[tid];
    float4 of;
    of.x = (v[0] - mu) * rs * gv.x + bv.x;
    of.y = (v[1] - mu) * rs * gv.y + bv.y;
    of.z = (v[2] - mu) * rs * gv.z + bv.z;
    of.w = (v[3] - mu) * rs * gv.w + bv.w;
    reinterpret_cast<float4*>(out + off)[tid] = of;
}

// ---------- launch ----------
extern "C" void kernel_launch(void* const* d_in, const int* in_sizes, int n_in,
                              void* d_out, int out_size, void* d_ws, size_t ws_size,
                              hipStream_t stream) {
    const float* x  = (const float*)d_in[0];
    const float* Wq = (const float*)d_in[1];  const float* bq = (const float*)d_in[2];
    const float* Wk = (const float*)d_in[3];  const float* bk = (const float*)d_in[4];
    const float* Wv = (const float*)d_in[5];  const float* bv = (const float*)d_in[6];
    const float* Wo = (const float*)d_in[7];  const float* bo = (const float*)d_in[8];
    const float* W1 = (const float*)d_in[9];  const float* b1 = (const float*)d_in[10];
    const float* W2 = (const float*)d_in[11]; const float* b2 = (const float*)d_in[12];
    const float* g1 = (const float*)d_in[13]; const float* be1 = (const float*)d_in[14];
    const float* g2 = (const float*)d_in[15]; const float* be2 = (const float*)d_in[16];

    char* ws = (char*)d_ws;
    const size_t MBy = (size_t)1 << 20;
    ushort* xb    = (ushort*)(ws + 0 * MBy);     // 16 MB  [8192][1024] bf16
    ushort* wqkvT = (ushort*)(ws + 16 * MBy);    // 6 MB   [3072][1024]
    ushort* woT   = (ushort*)(ws + 22 * MBy);    // 2 MB
    ushort* w1T   = (ushort*)(ws + 24 * MBy);    // 8 MB   [4096][1024]
    ushort* w2T   = (ushort*)(ws + 32 * MBy);    // 8 MB   [1024][4096]
    ushort* QKVb  = (ushort*)(ws + 40 * MBy);    // 48 MB  [8192][3072]
    ushort* AOb   = (ushort*)(ws + 88 * MBy);    // 16 MB
    ushort* h1    = (ushort*)(ws + 40 * MBy);    // 64 MB (aliases QKVb+AOb, both dead by FFN1)
    ushort* z1b   = (ushort*)(ws + 104 * MBy);   // 16 MB  x + attn_out (bf16)
    ushort* x2b   = (ushort*)(ws + 120 * MBy);   // 16 MB
    ushort* psk   = (ushort*)(ws + 136 * MBy);   // 32 MB  [2][8192][1024] bf16 split-K partials
    (void)ws_size; (void)n_in; (void)in_sizes; (void)out_size;

    const int M = 8192;

    cast_bf16_kernel<<<(M * 1024 / 4 + 255) / 256, 256, 0, stream>>>(x, xb, M * 1024 / 4);
    dim3 tb(32, 8);
    transpose_cast3_kernel<<<dim3(32, 32, 3), tb, 0, stream>>>(Wq, Wk, Wv, wqkvT);
    transpose_cast_kernel<<<dim3(32, 32),  tb, 0, stream>>>(Wo, woT, 1024, 1024);
    transpose_cast_kernel<<<dim3(128, 32), tb, 0, stream>>>(W1, w1T, 1024, 4096);
    transpose_cast_kernel<<<dim3(32, 128), tb, 0, stream>>>(W2, w2T, 4096, 1024);

    // QKV projection (p3; 1536 blocks -> 3/CU)
    gemm_p3<0, 1, 1, 0><<<dim3(24, 64), 256, 0, stream>>>(xb, wqkvT, bq, bk, bv, nullptr,
                                                          QKVb, M, 3072, 1024);

    attn_kernel<<<1024, 256, 0, stream>>>(QKVb, AOb);

    // Wo + fused residual (x, f32) -> z1 (bf16)
    gemm_p3<0, 1, 0, 1><<<dim3(8, 64), 256, 0, stream>>>(AOb, woT, bo, nullptr, nullptr, x,
                                                         z1b, M, 1024, 1024);

    ln_one_b<<<M, 256, 0, stream>>>(z1b, g1, be1, x2b);

    // FFN1 (p3; 2048 blocks -> 3/CU)
    gemm_p3<1, 1, 0, 0><<<dim3(32, 64), 256, 0, stream>>>(x2b, w1T, b1, nullptr, nullptr,
                                                          nullptr, h1, M, 4096, 1024);

    // FFN2 split-K=2: 1024 blocks (FFN1-like residency), bf16 partials
    gemm_sk<<<dim3(8, 128), 256, 0, stream>>>(h1, w2T, psk, M, 1024, 4096, 2048);

    // fused reduce + residual + bias + LN2 -> d_out (f32)
    ln2_reduce<<<M, 256, 0, stream>>>(x2b, psk, psk + (size_t)M * 1024, b2, g2, be2,
                                      (float*)d_out);
}

// Round 15
// 404.061 us; speedup vs baseline: 1.1502x; 1.0386x over previous
//
#include <hip/hip_runtime.h>
#include <hip/hip_bf16.h>

// ---------- types ----------
typedef __attribute__((ext_vector_type(8)))  __bf16 bf16x8;
typedef __attribute__((ext_vector_type(4)))  float  f32x4;
typedef __attribute__((ext_vector_type(16))) float  f32x16;

static __device__ __forceinline__ unsigned short f2bf(float x) {
    unsigned int u = __float_as_uint(x);
    unsigned int r = (u + 0x7FFFu + ((u >> 16) & 1u)) >> 16;
    return (unsigned short)r;
}
static __device__ __forceinline__ float bf2f(unsigned short u) {
    return __uint_as_float(((unsigned int)u) << 16);
}

// 2^x via v_exp_f32 (CDNA VALU has HW interlocks; no nop needed)
static __device__ __forceinline__ float fast_exp2(float x) {
    float r;
    asm("v_exp_f32 %0, %1" : "=v"(r) : "v"(x));
    return r;
}
// packed f32x2 -> bf16x2 (u32); lo <- a, hi <- b
static __device__ __forceinline__ unsigned int cvt_pk_bf16(float a, float b) {
    unsigned int r;
    asm("v_cvt_pk_bf16_f32 %0, %1, %2" : "=v"(r) : "v"(a), "v"(b));
    return r;
}

// async global->LDS, 16B per lane; lds base wave-uniform (lane*16 auto-offset)
static __device__ __forceinline__ void gload_lds16(const ushort* g, ushort* l) {
    __builtin_amdgcn_global_load_lds((const __attribute__((address_space(1))) void*)g,
                                     (__attribute__((address_space(3))) void*)l, 16, 0, 0);
}

// raw barrier + scheduling/memory fence (no vmcnt drain, unlike __syncthreads)
static __device__ __forceinline__ void barrier_fence() {
    __builtin_amdgcn_s_barrier();
    __builtin_amdgcn_sched_barrier(0);
    asm volatile("" ::: "memory");
}

// T1: XCD-aware chunked remap (requires nwg % 8 == 0; all grids here comply)
static __device__ __forceinline__ int xcd_swz(int id, int nwg) {
    return (id & 7) * (nwg >> 3) + (id >> 3);
}

// ---------- elementwise cast f32 -> bf16 ----------
__global__ __launch_bounds__(256) void cast_bf16_kernel(const float* __restrict__ in,
                                                        ushort* __restrict__ out, int n4) {
    int i = blockIdx.x * 256 + threadIdx.x;
    if (i < n4) {
        float4 v = reinterpret_cast<const float4*>(in)[i];
        ushort4 o;
        o.x = f2bf(v.x); o.y = f2bf(v.y); o.z = f2bf(v.z); o.w = f2bf(v.w);
        reinterpret_cast<ushort4*>(out)[i] = o;
    }
}

// ---------- transpose + cast: in[K][N] f32 -> out[N][K] bf16 ----------
__global__ __launch_bounds__(256) void transpose_cast_kernel(const float* __restrict__ in,
                                                             ushort* __restrict__ out,
                                                             int K, int N) {
    __shared__ float tile[32][33];
    const int tx = threadIdx.x;
    const int ty = threadIdx.y;
    const int n0 = blockIdx.x * 32;
    const int k0 = blockIdx.y * 32;
    for (int i = ty; i < 32; i += 8)
        tile[i][tx] = in[(size_t)(k0 + i) * N + n0 + tx];
    __syncthreads();
    for (int i = ty; i < 32; i += 8)
        out[(size_t)(n0 + i) * K + k0 + tx] = f2bf(tile[tx][i]);
}

// three 1024x1024 transposes (Wq,Wk,Wv) in one launch; z picks the source
__global__ __launch_bounds__(256) void transpose_cast3_kernel(const float* __restrict__ w0,
                                                              const float* __restrict__ w1,
                                                              const float* __restrict__ w2,
                                                              ushort* __restrict__ out) {
    __shared__ float tile[32][33];
    const int tx = threadIdx.x;
    const int ty = threadIdx.y;
    const int n0 = blockIdx.x * 32;
    const int k0 = blockIdx.y * 32;
    const int z  = blockIdx.z;
    const float* in = (z == 0) ? w0 : (z == 1 ? w1 : w2);
    ushort* o = out + (size_t)z * 1024 * 1024;
    for (int i = ty; i < 32; i += 8)
        tile[i][tx] = in[(size_t)(k0 + i) * 1024 + n0 + tx];
    __syncthreads();
    for (int i = ty; i < 32; i += 8)
        o[(size_t)(n0 + i) * 1024 + k0 + tx] = f2bf(tile[tx][i]);
}

// ============================================================================
// GEMM, 128x128 tile, BK=32, 256 threads (4 waves, 2x2 of 64x64).
// 3 LDS buffers, counted-vmcnt pipeline (round-8 structure, measured best):
//   iter t: s_waitcnt vmcnt(4) ; s_barrier ; issue tile t+2 ; compute tile t.
// T2 bank-conflict swizzle (round-11): chunk ^= (row>>1)&3, both sides.
// RES: 0 none, 1 add f32 residual, 2 add bf16 residual in epilogue.
// ============================================================================
template<int RELU, int OUTBF, int QKV, int RES>
__global__ __launch_bounds__(256) void gemm_p3(const ushort* __restrict__ A,
                                               const ushort* __restrict__ Bt,
                                               const float* __restrict__ b0,
                                               const float* __restrict__ b1_,
                                               const float* __restrict__ b2_,
                                               const void* __restrict__ xres,
                                               void* __restrict__ Cp,
                                               int M, int N, int K) {
    __shared__ ushort As[3][4096];
    __shared__ ushort Bs[3][4096];
    const int tid  = threadIdx.x;
    const int lane = tid & 63;
    const int w    = tid >> 6;
    const int wr   = w >> 1, wc = w & 1;
    const int nwg = gridDim.x * gridDim.y;
    int wid = xcd_swz(blockIdx.y * gridDim.x + blockIdx.x, nwg);
    const int bx = wid % gridDim.x;
    const int by = wid / gridDim.x;
    const int m0 = by * 128;
    const int n0 = bx * 128;
    const int lr = lane & 15;
    const int lg = lane >> 4;
    const int xc = (lg ^ ((lr >> 1) & 3)) * 8;

    const int r0 = w * 32 + (lane >> 2);
    const int c8 = ((lane & 3) ^ ((lane >> 3) & 3)) * 8;
    const ushort* gA0 = A  + (size_t)(m0 + r0)      * K + c8;
    const ushort* gA1 = A  + (size_t)(m0 + r0 + 16) * K + c8;
    const ushort* gB0 = Bt + (size_t)(n0 + r0)      * K + c8;
    const ushort* gB1 = Bt + (size_t)(n0 + r0 + 16) * K + c8;
    const int wb = w * 1024;

    f32x4 acc[4][4];
    const f32x4 z = {0.f, 0.f, 0.f, 0.f};
#pragma unroll
    for (int i = 0; i < 4; i++)
#pragma unroll
        for (int j = 0; j < 4; j++) acc[i][j] = z;

    const int nt = K >> 5;

#pragma unroll
    for (int t = 0; t < 2; ++t) {
        const int kn = t * 32;
        gload_lds16(gA0 + kn, &As[t][wb]);
        gload_lds16(gA1 + kn, &As[t][wb + 512]);
        gload_lds16(gB0 + kn, &Bs[t][wb]);
        gload_lds16(gB1 + kn, &Bs[t][wb + 512]);
    }

    int cur = 0;
    for (int t = 0; t < nt; ++t) {
        if (t + 1 < nt) asm volatile("s_waitcnt vmcnt(4)" ::: "memory");
        else            asm volatile("s_waitcnt vmcnt(0)" ::: "memory");
        barrier_fence();

        if (t + 2 < nt) {
            const int bi = (cur + 2 >= 3) ? cur - 1 : cur + 2;
            const int kn = (t + 2) * 32;
            gload_lds16(gA0 + kn, &As[bi][wb]);
            gload_lds16(gA1 + kn, &As[bi][wb + 512]);
            gload_lds16(gB0 + kn, &Bs[bi][wb]);
            gload_lds16(gB1 + kn, &Bs[bi][wb + 512]);
        }

        const ushort* Asb = As[cur];
        const ushort* Bsb = Bs[cur];
        bf16x8 af[4], bfr[4];
#pragma unroll
        for (int i = 0; i < 4; i++)
            af[i] = *reinterpret_cast<const bf16x8*>(&Asb[(wr * 64 + i * 16 + lr) * 32 + xc]);
#pragma unroll
        for (int j = 0; j < 4; j++)
            bfr[j] = *reinterpret_cast<const bf16x8*>(&Bsb[(wc * 64 + j * 16 + lr) * 32 + xc]);
#pragma unroll
        for (int i = 0; i < 4; i++)
#pragma unroll
            for (int j = 0; j < 4; j++)
                acc[i][j] = __builtin_amdgcn_mfma_f32_16x16x32_bf16(af[i], bfr[j], acc[i][j], 0, 0, 0);

        cur = (cur == 2) ? 0 : cur + 1;
    }

    const float* bias;
    float qscale = 1.0f;
    if (QKV) {
        bias = (n0 < 1024) ? b0 : (n0 < 2048 ? b1_ : b2_);
        if (n0 < 1024) qscale = 0.18033688f;   // 0.125*log2(e) folded into Q
    } else {
        bias = b0;
    }
    const int nb = QKV ? (n0 & 1023) : n0;
    const int rbase = (lane >> 4) * 4;
#pragma unroll
    for (int i = 0; i < 4; i++) {
#pragma unroll
        for (int j = 0; j < 4; j++) {
            const int cloc = wc * 64 + j * 16 + lr;
            const float bv = bias[nb + cloc];
#pragma unroll
            for (int r = 0; r < 4; r++) {
                const int row = m0 + wr * 64 + i * 16 + rbase + r;
                float v = acc[i][j][r] + bv;
                if (RES == 1) v += ((const float*)xres)[(size_t)row * N + n0 + cloc];
                if (RES == 2) v += bf2f(((const ushort*)xres)[(size_t)row * N + n0 + cloc]);
                if (RELU) v = v > 0.f ? v : 0.f;
                if (QKV)  v *= qscale;
                if (OUTBF) ((ushort*)Cp)[(size_t)row * N + n0 + cloc] = f2bf(v);
                else       ((float*)Cp)[(size_t)row * N + n0 + cloc] = v;
            }
        }
    }
}

// ---------- flash attention, 32x32 swapped-QK^T, in-register P (T12) ----------
#define ASWZ(row, col) ((row) * 64 + ((col) ^ ((((row) ^ ((row) >> 3)) & 7) << 3)))

__global__ __launch_bounds__(256, 3) void attn_kernel(const ushort* __restrict__ QKV,
                                                      ushort* __restrict__ O) {
    __shared__ ushort Ks[2][4096];
    __shared__ ushort Vt[2][4096];
    const int tid  = threadIdx.x;
    const int lane = tid & 63;
    const int w    = tid >> 6;
    const int l31  = lane & 31;
    const int hi   = lane >> 5;

    int blk = xcd_swz(blockIdx.x, gridDim.x);
    const int qb = blk & 15;
    const int h  = (blk >> 4) & 15;
    const int b  = blk >> 8;
    const int s0 = qb * 128 + w * 32;
    const size_t rowb   = (size_t)b * 2048;
    const size_t base_q = rowb * 3072 + (size_t)h * 64;
    const size_t base_k = base_q + 1024;
    const size_t base_v = base_q + 2048;
    const size_t base_o = rowb * 1024 + (size_t)h * 64;

    bf16x8 qf[4];
#pragma unroll
    for (int ks = 0; ks < 4; ks++)
        qf[ks] = *reinterpret_cast<const bf16x8*>(
            &QKV[base_q + (size_t)(s0 + l31) * 3072 + ks * 16 + 8 * hi]);

    int off8[2][4];
#pragma unroll
    for (int sub = 0; sub < 2; sub++)
#pragma unroll
        for (int ks = 0; ks < 4; ks++)
            off8[sub][ks] = ASWZ(sub * 32 + l31, ks * 16 + 8 * hi);

    // staging geometry: K rows tS2 and tS2+32; V row-pair 2*tS2, 2*tS2+1
    const int tS2 = tid >> 3;
    const int ccS = tid & 7;
    int voff[8];
#pragma unroll
    for (int jj = 0; jj < 8; jj++)
        voff[jj] = ASWZ(ccS * 8 + jj, 2 * tS2);
    const int tk1 = tS2 + 32;
    const int sz0 = (tS2 ^ (tS2 >> 3)) & 7;
    const int sz1 = (tk1 ^ (tk1 >> 3)) & 7;
    const ushort* pK0 = QKV + base_k + (size_t)tS2 * 3072 + (ccS ^ sz0) * 8;
    const ushort* pK1 = QKV + base_k + (size_t)tk1 * 3072 + (ccS ^ sz1) * 8;
    const ushort* pV0 = QKV + base_v + (size_t)(2 * tS2)     * 3072 + ccS * 8;
    const ushort* pV1 = QKV + base_v + (size_t)(2 * tS2 + 1) * 3072 + ccS * 8;
    const size_t step = (size_t)64 * 3072;

    gload_lds16(pK0, &Ks[0][w * 512]);
    gload_lds16(pK1, &Ks[0][2048 + w * 512]);
    {
        int4 v0 = *reinterpret_cast<const int4*>(pV0);
        int4 v1 = *reinterpret_cast<const int4*>(pV1);
        const ushort* vs0 = reinterpret_cast<const ushort*>(&v0);
        const ushort* vs1 = reinterpret_cast<const ushort*>(&v1);
#pragma unroll
        for (int jj = 0; jj < 8; jj++)
            *reinterpret_cast<unsigned*>(&Vt[0][voff[jj]]) =
                (unsigned)vs0[jj] | ((unsigned)vs1[jj] << 16);
    }
    pK0 += step; pK1 += step; pV0 += step; pV1 += step;
    __syncthreads();

    f32x16 oacc0, oacc1;
    for (int i = 0; i < 16; i++) { oacc0[i] = 0.f; oacc1[i] = 0.f; }
    float lacc = 0.f;
    int cur = 0;

    for (int it = 0; it < 32; ++it) {
        int4 nv0, nv1;
        if (it < 31) {
            gload_lds16(pK0, &Ks[cur ^ 1][w * 512]);
            gload_lds16(pK1, &Ks[cur ^ 1][2048 + w * 512]);
            nv0 = *reinterpret_cast<const int4*>(pV0);
            nv1 = *reinterpret_cast<const int4*>(pV1);
            pK0 += step; pK1 += step; pV0 += step; pV1 += step;
        }

        f32x16 sa0, sa1;
        for (int i = 0; i < 16; i++) { sa0[i] = 0.f; sa1[i] = 0.f; }
        __builtin_amdgcn_s_setprio(1);
#pragma unroll
        for (int ks = 0; ks < 4; ks++) {
            bf16x8 k0 = *reinterpret_cast<const bf16x8*>(&Ks[cur][off8[0][ks]]);
            sa0 = __builtin_amdgcn_mfma_f32_32x32x16_bf16(k0, qf[ks], sa0, 0, 0, 0);
        }
#pragma unroll
        for (int ks = 0; ks < 4; ks++) {
            bf16x8 k1 = *reinterpret_cast<const bf16x8*>(&Ks[cur][off8[1][ks]]);
            sa1 = __builtin_amdgcn_mfma_f32_32x32x16_bf16(k1, qf[ks], sa1, 0, 0, 0);
        }
        __builtin_amdgcn_s_setprio(0);

        unsigned pk0[8], pk1[8];
#pragma unroll
        for (int i = 0; i < 8; i++) {
            float plo = fast_exp2(sa0[2 * i]);
            float phi = fast_exp2(sa0[2 * i + 1]);
            lacc += plo + phi;
            pk0[i] = cvt_pk_bf16(plo, phi);
        }
#pragma unroll
        for (int i = 0; i < 8; i++) {
            float plo = fast_exp2(sa1[2 * i]);
            float phi = fast_exp2(sa1[2 * i + 1]);
            lacc += plo + phi;
            pk1[i] = cvt_pk_bf16(plo, phi);
        }

        __builtin_amdgcn_s_setprio(1);
#pragma unroll
        for (int ks = 0; ks < 4; ks++) {
            const int bi = 4 * (ks & 1);
            unsigned a, bb, c, d;
            if (ks < 2) { a = pk0[bi]; bb = pk0[bi + 1]; c = pk0[bi + 2]; d = pk0[bi + 3]; }
            else        { a = pk1[bi]; bb = pk1[bi + 1]; c = pk1[bi + 2]; d = pk1[bi + 3]; }
            asm("v_permlane32_swap_b32 %0, %1" : "+v"(a), "+v"(c));
            asm("v_permlane32_swap_b32 %0, %1" : "+v"(bb), "+v"(d));
            union { unsigned u[4]; bf16x8 v; } fr;
            fr.u[0] = a; fr.u[1] = bb; fr.u[2] = c; fr.u[3] = d;
            bf16x8 v0 = *reinterpret_cast<const bf16x8*>(&Vt[cur][off8[0][ks]]);
            oacc0 = __builtin_amdgcn_mfma_f32_32x32x16_bf16(fr.v, v0, oacc0, 0, 0, 0);
            bf16x8 v1 = *reinterpret_cast<const bf16x8*>(&Vt[cur][off8[1][ks]]);
            oacc1 = __builtin_amdgcn_mfma_f32_32x32x16_bf16(fr.v, v1, oacc1, 0, 0, 0);
        }
        __builtin_amdgcn_s_setprio(0);

        if (it < 31) {
            const ushort* vs0 = reinterpret_cast<const ushort*>(&nv0);
            const ushort* vs1 = reinterpret_cast<const ushort*>(&nv1);
#pragma unroll
            for (int jj = 0; jj < 8; jj++)
                *reinterpret_cast<unsigned*>(&Vt[cur ^ 1][voff[jj]]) =
                    (unsigned)vs0[jj] | ((unsigned)vs1[jj] << 16);
        }
        __syncthreads();
        cur ^= 1;
    }

    const float ltot = lacc + __shfl_xor(lacc, 32);
    const float inv  = 1.f / ltot;
#pragma unroll
    for (int r = 0; r < 16; r++) {
        const int qloc = (r & 3) + 8 * (r >> 2) + 4 * hi;
        const float invq = __shfl(inv, qloc);
        const size_t rowoff = base_o + (size_t)(s0 + qloc) * 1024 + l31;
        O[rowoff]      = f2bf(oacc0[r] * invq);
        O[rowoff + 32] = f2bf(oacc1[r] * invq);
    }
}

// ---------- single-input layernorm (residual already added in GEMM epilogue) ----------
template<int OUTBF>
__global__ __launch_bounds__(256) void ln_one(const ushort* __restrict__ zin,
                                              const float* __restrict__ g,
                                              const float* __restrict__ be,
                                              void* __restrict__ out) {
    const int row = blockIdx.x;
    const int tid = threadIdx.x;
    const ushort4 zv = reinterpret_cast<const ushort4*>(zin + (size_t)row * 1024)[tid];
    float v[4] = {bf2f(zv.x), bf2f(zv.y), bf2f(zv.z), bf2f(zv.w)};
    float s  = v[0] + v[1] + v[2] + v[3];
    float s2 = v[0]*v[0] + v[1]*v[1] + v[2]*v[2] + v[3]*v[3];
    for (int off = 32; off; off >>= 1) { s += __shfl_down(s, off); s2 += __shfl_down(s2, off); }
    __shared__ float red[8];
    const int w = tid >> 6, lane = tid & 63;
    if (lane == 0) { red[w] = s; red[4 + w] = s2; }
    __syncthreads();
    if (tid == 0) {
        const float ts  = red[0] + red[1] + red[2] + red[3];
        const float ts2 = red[4] + red[5] + red[6] + red[7];
        const float mu  = ts * (1.f / 1024.f);
        const float var = ts2 * (1.f / 1024.f) - mu * mu;
        red[0] = mu;
        red[1] = rsqrtf(var + 1e-5f);
    }
    __syncthreads();
    const float mu = red[0], rs = red[1];
    const float4 gv = reinterpret_cast<const float4*>(g)[tid];
    const float4 bv = reinterpret_cast<const float4*>(be)[tid];
    float o0 = (v[0] - mu) * rs * gv.x + bv.x;
    float o1 = (v[1] - mu) * rs * gv.y + bv.y;
    float o2 = (v[2] - mu) * rs * gv.z + bv.z;
    float o3 = (v[3] - mu) * rs * gv.w + bv.w;
    if (OUTBF) {
        ushort4 ob;
        ob.x = f2bf(o0); ob.y = f2bf(o1); ob.z = f2bf(o2); ob.w = f2bf(o3);
        reinterpret_cast<ushort4*>((ushort*)out + (size_t)row * 1024)[tid] = ob;
    } else {
        float4 of;
        of.x = o0; of.y = o1; of.z = o2; of.w = o3;
        reinterpret_cast<float4*>((float*)out + (size_t)row * 1024)[tid] = of;
    }
}

// ---------- launch ----------
extern "C" void kernel_launch(void* const* d_in, const int* in_sizes, int n_in,
                              void* d_out, int out_size, void* d_ws, size_t ws_size,
                              hipStream_t stream) {
    const float* x  = (const float*)d_in[0];
    const float* Wq = (const float*)d_in[1];  const float* bq = (const float*)d_in[2];
    const float* Wk = (const float*)d_in[3];  const float* bk = (const float*)d_in[4];
    const float* Wv = (const float*)d_in[5];  const float* bv = (const float*)d_in[6];
    const float* Wo = (const float*)d_in[7];  const float* bo = (const float*)d_in[8];
    const float* W1 = (const float*)d_in[9];  const float* b1 = (const float*)d_in[10];
    const float* W2 = (const float*)d_in[11]; const float* b2 = (const float*)d_in[12];
    const float* g1 = (const float*)d_in[13]; const float* be1 = (const float*)d_in[14];
    const float* g2 = (const float*)d_in[15]; const float* be2 = (const float*)d_in[16];

    char* ws = (char*)d_ws;
    const size_t MBy = (size_t)1 << 20;
    ushort* xb    = (ushort*)(ws + 0 * MBy);     // 16 MB  [8192][1024] bf16
    ushort* wqkvT = (ushort*)(ws + 16 * MBy);    // 6 MB   [3072][1024]
    ushort* woT   = (ushort*)(ws + 22 * MBy);    // 2 MB
    ushort* w1T   = (ushort*)(ws + 24 * MBy);    // 8 MB   [4096][1024]
    ushort* w2T   = (ushort*)(ws + 32 * MBy);    // 8 MB   [1024][4096]
    ushort* QKVb  = (ushort*)(ws + 40 * MBy);    // 48 MB  [8192][3072]
    ushort* AOb   = (ushort*)(ws + 88 * MBy);    // 16 MB
    ushort* h1    = (ushort*)(ws + 40 * MBy);    // 64 MB (aliases QKVb+AOb, both dead by FFN1)
    ushort* z1b   = (ushort*)(ws + 104 * MBy);   // 16 MB  x + attn_out (bf16)
    ushort* z2b   = (ushort*)(ws + 104 * MBy);   // aliases z1b (dead after LN1)
    ushort* x2b   = (ushort*)(ws + 120 * MBy);   // 16 MB
    (void)ws_size; (void)n_in; (void)in_sizes; (void)out_size;

    const int M = 8192;

    cast_bf16_kernel<<<(M * 1024 / 4 + 255) / 256, 256, 0, stream>>>(x, xb, M * 1024 / 4);
    dim3 tb(32, 8);
    transpose_cast3_kernel<<<dim3(32, 32, 3), tb, 0, stream>>>(Wq, Wk, Wv, wqkvT);
    transpose_cast_kernel<<<dim3(32, 32),  tb, 0, stream>>>(Wo, woT, 1024, 1024);
    transpose_cast_kernel<<<dim3(128, 32), tb, 0, stream>>>(W1, w1T, 1024, 4096);
    transpose_cast_kernel<<<dim3(32, 128), tb, 0, stream>>>(W2, w2T, 4096, 1024);

    // QKV projection (p3; 1536 blocks -> 3/CU)
    gemm_p3<0, 1, 1, 0><<<dim3(24, 64), 256, 0, stream>>>(xb, wqkvT, bq, bk, bv, nullptr,
                                                          QKVb, M, 3072, 1024);

    attn_kernel<<<1024, 256, 0, stream>>>(QKVb, AOb);

    // Wo + fused residual (x, f32) -> z1 = x + attn_out (bf16)
    gemm_p3<0, 1, 0, 1><<<dim3(8, 64), 256, 0, stream>>>(AOb, woT, bo, nullptr, nullptr, x,
                                                         z1b, M, 1024, 1024);

    // LN1 (single input)
    ln_one<1><<<M, 256, 0, stream>>>(z1b, g1, be1, x2b);

    // FFN1
    gemm_p3<1, 1, 0, 0><<<dim3(32, 64), 256, 0, stream>>>(x2b, w1T, b1, nullptr, nullptr,
                                                          nullptr, h1, M, 4096, 1024);
    // FFN2 + fused residual (x2b, bf16) -> z2 = x2 + ffn_out (bf16)
    gemm_p3<0, 1, 0, 2><<<dim3(8, 64), 256, 0, stream>>>(h1, w2T, b2, nullptr, nullptr, x2b,
                                                         z2b, M, 1024, 4096);

    // LN2 -> d_out (f32)
    ln_one<0><<<M, 256, 0, stream>>>(z2b, g2, be2, (float*)d_out);
}

// Round 16
// 397.874 us; speedup vs baseline: 1.1681x; 1.0156x over previous
//
#include <hip/hip_runtime.h>
#include <hip/hip_bf16.h>

// ---------- types ----------
typedef __attribute__((ext_vector_type(8)))  __bf16 bf16x8;
typedef __attribute__((ext_vector_type(4)))  float  f32x4;
typedef __attribute__((ext_vector_type(16))) float  f32x16;

static __device__ __forceinline__ unsigned short f2bf(float x) {
    unsigned int u = __float_as_uint(x);
    unsigned int r = (u + 0x7FFFu + ((u >> 16) & 1u)) >> 16;
    return (unsigned short)r;
}
static __device__ __forceinline__ float bf2f(unsigned short u) {
    return __uint_as_float(((unsigned int)u) << 16);
}

// 2^x via v_exp_f32 (CDNA VALU has HW interlocks; no nop needed)
static __device__ __forceinline__ float fast_exp2(float x) {
    float r;
    asm("v_exp_f32 %0, %1" : "=v"(r) : "v"(x));
    return r;
}
// packed f32x2 -> bf16x2 (u32); lo <- a, hi <- b
static __device__ __forceinline__ unsigned int cvt_pk_bf16(float a, float b) {
    unsigned int r;
    asm("v_cvt_pk_bf16_f32 %0, %1, %2" : "=v"(r) : "v"(a), "v"(b));
    return r;
}

// async global->LDS, 16B per lane; lds base wave-uniform (lane*16 auto-offset)
static __device__ __forceinline__ void gload_lds16(const ushort* g, ushort* l) {
    __builtin_amdgcn_global_load_lds((const __attribute__((address_space(1))) void*)g,
                                     (__attribute__((address_space(3))) void*)l, 16, 0, 0);
}

// raw barrier + scheduling/memory fence (no vmcnt drain, unlike __syncthreads)
static __device__ __forceinline__ void barrier_fence() {
    __builtin_amdgcn_s_barrier();
    __builtin_amdgcn_sched_barrier(0);
    asm volatile("" ::: "memory");
}

// T1: XCD-aware chunked remap (requires nwg % 8 == 0; all grids here comply)
static __device__ __forceinline__ int xcd_swz(int id, int nwg) {
    return (id & 7) * (nwg >> 3) + (id >> 3);
}

// ---------- elementwise cast f32 -> bf16 ----------
__global__ __launch_bounds__(256) void cast_bf16_kernel(const float* __restrict__ in,
                                                        ushort* __restrict__ out, int n4) {
    int i = blockIdx.x * 256 + threadIdx.x;
    if (i < n4) {
        float4 v = reinterpret_cast<const float4*>(in)[i];
        ushort4 o;
        o.x = f2bf(v.x); o.y = f2bf(v.y); o.z = f2bf(v.z); o.w = f2bf(v.w);
        reinterpret_cast<ushort4*>(out)[i] = o;
    }
}

// ---------- transpose + cast: in[K][N] f32 -> out[N][K] bf16 ----------
__global__ __launch_bounds__(256) void transpose_cast_kernel(const float* __restrict__ in,
                                                             ushort* __restrict__ out,
                                                             int K, int N) {
    __shared__ float tile[32][33];
    const int tx = threadIdx.x;
    const int ty = threadIdx.y;
    const int n0 = blockIdx.x * 32;
    const int k0 = blockIdx.y * 32;
    for (int i = ty; i < 32; i += 8)
        tile[i][tx] = in[(size_t)(k0 + i) * N + n0 + tx];
    __syncthreads();
    for (int i = ty; i < 32; i += 8)
        out[(size_t)(n0 + i) * K + k0 + tx] = f2bf(tile[tx][i]);
}

// three 1024x1024 transposes (Wq,Wk,Wv) in one launch; z picks the source
__global__ __launch_bounds__(256) void transpose_cast3_kernel(const float* __restrict__ w0,
                                                              const float* __restrict__ w1,
                                                              const float* __restrict__ w2,
                                                              ushort* __restrict__ out) {
    __shared__ float tile[32][33];
    const int tx = threadIdx.x;
    const int ty = threadIdx.y;
    const int n0 = blockIdx.x * 32;
    const int k0 = blockIdx.y * 32;
    const int z  = blockIdx.z;
    const float* in = (z == 0) ? w0 : (z == 1 ? w1 : w2);
    ushort* o = out + (size_t)z * 1024 * 1024;
    for (int i = ty; i < 32; i += 8)
        tile[i][tx] = in[(size_t)(k0 + i) * 1024 + n0 + tx];
    __syncthreads();
    for (int i = ty; i < 32; i += 8)
        o[(size_t)(n0 + i) * 1024 + k0 + tx] = f2bf(tile[tx][i]);
}

// ============================================================================
// GEMM, 128x128 tile, BK=32, 256 threads (4 waves, 2x2 of 64x64).
// 3 LDS buffers, counted-vmcnt pipeline (round-8 structure, measured best):
//   iter t: s_waitcnt vmcnt(4) ; s_barrier ; issue tile t+2 ; compute tile t.
// T2 bank-conflict swizzle (round-11): chunk ^= (row>>1)&3, both sides.
// RES: 0 none, 1 add f32 residual, 2 add bf16 residual in epilogue.
// ============================================================================
template<int RELU, int OUTBF, int QKV, int RES>
__global__ __launch_bounds__(256) void gemm_p3(const ushort* __restrict__ A,
                                               const ushort* __restrict__ Bt,
                                               const float* __restrict__ b0,
                                               const float* __restrict__ b1_,
                                               const float* __restrict__ b2_,
                                               const void* __restrict__ xres,
                                               void* __restrict__ Cp,
                                               int M, int N, int K) {
    __shared__ ushort As[3][4096];
    __shared__ ushort Bs[3][4096];
    const int tid  = threadIdx.x;
    const int lane = tid & 63;
    const int w    = tid >> 6;
    const int wr   = w >> 1, wc = w & 1;
    const int nwg = gridDim.x * gridDim.y;
    int wid = xcd_swz(blockIdx.y * gridDim.x + blockIdx.x, nwg);
    const int bx = wid % gridDim.x;
    const int by = wid / gridDim.x;
    const int m0 = by * 128;
    const int n0 = bx * 128;
    const int lr = lane & 15;
    const int lg = lane >> 4;
    const int xc = (lg ^ ((lr >> 1) & 3)) * 8;

    const int r0 = w * 32 + (lane >> 2);
    const int c8 = ((lane & 3) ^ ((lane >> 3) & 3)) * 8;
    const ushort* gA0 = A  + (size_t)(m0 + r0)      * K + c8;
    const ushort* gA1 = A  + (size_t)(m0 + r0 + 16) * K + c8;
    const ushort* gB0 = Bt + (size_t)(n0 + r0)      * K + c8;
    const ushort* gB1 = Bt + (size_t)(n0 + r0 + 16) * K + c8;
    const int wb = w * 1024;

    f32x4 acc[4][4];
    const f32x4 z = {0.f, 0.f, 0.f, 0.f};
#pragma unroll
    for (int i = 0; i < 4; i++)
#pragma unroll
        for (int j = 0; j < 4; j++) acc[i][j] = z;

    const int nt = K >> 5;

#pragma unroll
    for (int t = 0; t < 2; ++t) {
        const int kn = t * 32;
        gload_lds16(gA0 + kn, &As[t][wb]);
        gload_lds16(gA1 + kn, &As[t][wb + 512]);
        gload_lds16(gB0 + kn, &Bs[t][wb]);
        gload_lds16(gB1 + kn, &Bs[t][wb + 512]);
    }

    int cur = 0;
    for (int t = 0; t < nt; ++t) {
        if (t + 1 < nt) asm volatile("s_waitcnt vmcnt(4)" ::: "memory");
        else            asm volatile("s_waitcnt vmcnt(0)" ::: "memory");
        barrier_fence();

        if (t + 2 < nt) {
            const int bi = (cur + 2 >= 3) ? cur - 1 : cur + 2;
            const int kn = (t + 2) * 32;
            gload_lds16(gA0 + kn, &As[bi][wb]);
            gload_lds16(gA1 + kn, &As[bi][wb + 512]);
            gload_lds16(gB0 + kn, &Bs[bi][wb]);
            gload_lds16(gB1 + kn, &Bs[bi][wb + 512]);
        }

        const ushort* Asb = As[cur];
        const ushort* Bsb = Bs[cur];
        bf16x8 af[4], bfr[4];
#pragma unroll
        for (int i = 0; i < 4; i++)
            af[i] = *reinterpret_cast<const bf16x8*>(&Asb[(wr * 64 + i * 16 + lr) * 32 + xc]);
#pragma unroll
        for (int j = 0; j < 4; j++)
            bfr[j] = *reinterpret_cast<const bf16x8*>(&Bsb[(wc * 64 + j * 16 + lr) * 32 + xc]);
#pragma unroll
        for (int i = 0; i < 4; i++)
#pragma unroll
            for (int j = 0; j < 4; j++)
                acc[i][j] = __builtin_amdgcn_mfma_f32_16x16x32_bf16(af[i], bfr[j], acc[i][j], 0, 0, 0);

        cur = (cur == 2) ? 0 : cur + 1;
    }

    const float* bias;
    float qscale = 1.0f;
    if (QKV) {
        bias = (n0 < 1024) ? b0 : (n0 < 2048 ? b1_ : b2_);
        if (n0 < 1024) qscale = 0.18033688f;   // 0.125*log2(e) folded into Q
    } else {
        bias = b0;
    }
    const int nb = QKV ? (n0 & 1023) : n0;
    const int rbase = (lane >> 4) * 4;
#pragma unroll
    for (int i = 0; i < 4; i++) {
#pragma unroll
        for (int j = 0; j < 4; j++) {
            const int cloc = wc * 64 + j * 16 + lr;
            const float bv = bias[nb + cloc];
#pragma unroll
            for (int r = 0; r < 4; r++) {
                const int row = m0 + wr * 64 + i * 16 + rbase + r;
                float v = acc[i][j][r] + bv;
                if (RES == 1) v += ((const float*)xres)[(size_t)row * N + n0 + cloc];
                if (RES == 2) v += bf2f(((const ushort*)xres)[(size_t)row * N + n0 + cloc]);
                if (RELU) v = v > 0.f ? v : 0.f;
                if (QKV)  v *= qscale;
                if (OUTBF) ((ushort*)Cp)[(size_t)row * N + n0 + cloc] = f2bf(v);
                else       ((float*)Cp)[(size_t)row * N + n0 + cloc] = v;
            }
        }
    }
}

// ---------- flash attention, 32x32 swapped-QK^T, in-register P (T12) ----------
// 8 waves x 32 q-rows = 256 q-rows per block (grid 512, 2 blocks/CU, 16 waves/CU).
// One 64x64 K/V tile serves 256 q-rows: each thread stages exactly ONE K chunk
// (gload_lds) and ONE V chunk (int4 + 8 ds_write_b16) per tile -> per-CU staging
// traffic halved vs the 128-row block.
#define ASWZ(row, col) ((row) * 64 + ((col) ^ ((((row) ^ ((row) >> 3)) & 7) << 3)))

__global__ __launch_bounds__(512, 4) void attn_kernel(const ushort* __restrict__ QKV,
                                                      ushort* __restrict__ O) {
    __shared__ ushort Ks[2][4096];
    __shared__ ushort Vt[2][4096];
    const int tid  = threadIdx.x;          // 0..511
    const int lane = tid & 63;
    const int w    = tid >> 6;             // 0..7
    const int l31  = lane & 31;
    const int hi   = lane >> 5;

    int blk = xcd_swz(blockIdx.x, gridDim.x);   // 512 blocks
    const int qb = blk & 7;                // q-block of 256 rows
    const int h  = (blk >> 3) & 15;
    const int b  = blk >> 7;
    const int s0 = qb * 256 + w * 32;
    const size_t rowb   = (size_t)b * 2048;
    const size_t base_q = rowb * 3072 + (size_t)h * 64;
    const size_t base_k = base_q + 1024;
    const size_t base_v = base_q + 2048;
    const size_t base_o = rowb * 1024 + (size_t)h * 64;

    bf16x8 qf[4];
#pragma unroll
    for (int ks = 0; ks < 4; ks++)
        qf[ks] = *reinterpret_cast<const bf16x8*>(
            &QKV[base_q + (size_t)(s0 + l31) * 3072 + ks * 16 + 8 * hi]);

    int off8[2][4];
#pragma unroll
    for (int sub = 0; sub < 2; sub++)
#pragma unroll
        for (int ks = 0; ks < 4; ks++)
            off8[sub][ks] = ASWZ(sub * 32 + l31, ks * 16 + 8 * hi);

    // staging: thread <-> one 16B chunk of the 64x64 tile (64 rows x 8 chunks)
    const int tS  = tid >> 3;              // row 0..63
    const int ccS = tid & 7;               // 16B chunk within row
    int voff[8];
#pragma unroll
    for (int jj = 0; jj < 8; jj++)
        voff[jj] = ASWZ(ccS * 8 + jj, tS); // Vt[d][t] scatter (2-way banks, free)
    const int szK = (tS ^ (tS >> 3)) & 7;
    const ushort* pK = QKV + base_k + (size_t)tS * 3072 + (ccS ^ szK) * 8;
    const ushort* pV = QKV + base_v + (size_t)tS * 3072 + ccS * 8;
    const size_t step = (size_t)64 * 3072;

    // prologue: stage tile 0 (1 gload + 1 int4 per thread)
    gload_lds16(pK, &Ks[0][w * 512]);
    {
        int4 v0 = *reinterpret_cast<const int4*>(pV);
        const ushort* vs = reinterpret_cast<const ushort*>(&v0);
#pragma unroll
        for (int jj = 0; jj < 8; jj++) Vt[0][voff[jj]] = vs[jj];
    }
    pK += step; pV += step;
    __syncthreads();

    f32x16 oacc0, oacc1;
    for (int i = 0; i < 16; i++) { oacc0[i] = 0.f; oacc1[i] = 0.f; }
    float lacc = 0.f;
    int cur = 0;

    for (int it = 0; it < 32; ++it) {
        int4 nv;
        if (it < 31) {
            gload_lds16(pK, &Ks[cur ^ 1][w * 512]);
            nv = *reinterpret_cast<const int4*>(pV);
            pK += step; pV += step;
        }

        f32x16 sa0, sa1;
        for (int i = 0; i < 16; i++) { sa0[i] = 0.f; sa1[i] = 0.f; }
        __builtin_amdgcn_s_setprio(1);
#pragma unroll
        for (int ks = 0; ks < 4; ks++) {
            bf16x8 k0 = *reinterpret_cast<const bf16x8*>(&Ks[cur][off8[0][ks]]);
            sa0 = __builtin_amdgcn_mfma_f32_32x32x16_bf16(k0, qf[ks], sa0, 0, 0, 0);
        }
#pragma unroll
        for (int ks = 0; ks < 4; ks++) {
            bf16x8 k1 = *reinterpret_cast<const bf16x8*>(&Ks[cur][off8[1][ks]]);
            sa1 = __builtin_amdgcn_mfma_f32_32x32x16_bf16(k1, qf[ks], sa1, 0, 0, 0);
        }
        __builtin_amdgcn_s_setprio(0);

        unsigned pk0[8], pk1[8];
#pragma unroll
        for (int i = 0; i < 8; i++) {
            float plo = fast_exp2(sa0[2 * i]);
            float phi = fast_exp2(sa0[2 * i + 1]);
            lacc += plo + phi;
            pk0[i] = cvt_pk_bf16(plo, phi);
        }
#pragma unroll
        for (int i = 0; i < 8; i++) {
            float plo = fast_exp2(sa1[2 * i]);
            float phi = fast_exp2(sa1[2 * i + 1]);
            lacc += plo + phi;
            pk1[i] = cvt_pk_bf16(plo, phi);
        }

        __builtin_amdgcn_s_setprio(1);
#pragma unroll
        for (int ks = 0; ks < 4; ks++) {
            const int bi = 4 * (ks & 1);
            unsigned a, bb, c, d;
            if (ks < 2) { a = pk0[bi]; bb = pk0[bi + 1]; c = pk0[bi + 2]; d = pk0[bi + 3]; }
            else        { a = pk1[bi]; bb = pk1[bi + 1]; c = pk1[bi + 2]; d = pk1[bi + 3]; }
            asm("v_permlane32_swap_b32 %0, %1" : "+v"(a), "+v"(c));
            asm("v_permlane32_swap_b32 %0, %1" : "+v"(bb), "+v"(d));
            union { unsigned u[4]; bf16x8 v; } fr;
            fr.u[0] = a; fr.u[1] = bb; fr.u[2] = c; fr.u[3] = d;
            bf16x8 v0 = *reinterpret_cast<const bf16x8*>(&Vt[cur][off8[0][ks]]);
            oacc0 = __builtin_amdgcn_mfma_f32_32x32x16_bf16(fr.v, v0, oacc0, 0, 0, 0);
            bf16x8 v1 = *reinterpret_cast<const bf16x8*>(&Vt[cur][off8[1][ks]]);
            oacc1 = __builtin_amdgcn_mfma_f32_32x32x16_bf16(fr.v, v1, oacc1, 0, 0, 0);
        }
        __builtin_amdgcn_s_setprio(0);

        if (it < 31) {
            const ushort* vs = reinterpret_cast<const ushort*>(&nv);
#pragma unroll
            for (int jj = 0; jj < 8; jj++) Vt[cur ^ 1][voff[jj]] = vs[jj];
        }
        __syncthreads();
        cur ^= 1;
    }

    const float ltot = lacc + __shfl_xor(lacc, 32);
    const float inv  = 1.f / ltot;
#pragma unroll
    for (int r = 0; r < 16; r++) {
        const int qloc = (r & 3) + 8 * (r >> 2) + 4 * hi;
        const float invq = __shfl(inv, qloc);
        const size_t rowoff = base_o + (size_t)(s0 + qloc) * 1024 + l31;
        O[rowoff]      = f2bf(oacc0[r] * invq);
        O[rowoff + 32] = f2bf(oacc1[r] * invq);
    }
}

// ---------- single-input layernorm (residual already added in GEMM epilogue) ----------
template<int OUTBF>
__global__ __launch_bounds__(256) void ln_one(const ushort* __restrict__ zin,
                                              const float* __restrict__ g,
                                              const float* __restrict__ be,
                                              void* __restrict__ out) {
    const int row = blockIdx.x;
    const int tid = threadIdx.x;
    const ushort4 zv = reinterpret_cast<const ushort4*>(zin + (size_t)row * 1024)[tid];
    float v[4] = {bf2f(zv.x), bf2f(zv.y), bf2f(zv.z), bf2f(zv.w)};
    float s  = v[0] + v[1] + v[2] + v[3];
    float s2 = v[0]*v[0] + v[1]*v[1] + v[2]*v[2] + v[3]*v[3];
    for (int off = 32; off; off >>= 1) { s += __shfl_down(s, off); s2 += __shfl_down(s2, off); }
    __shared__ float red[8];
    const int w = tid >> 6, lane = tid & 63;
    if (lane == 0) { red[w] = s; red[4 + w] = s2; }
    __syncthreads();
    if (tid == 0) {
        const float ts  = red[0] + red[1] + red[2] + red[3];
        const float ts2 = red[4] + red[5] + red[6] + red[7];
        const float mu  = ts * (1.f / 1024.f);
        const float var = ts2 * (1.f / 1024.f) - mu * mu;
        red[0] = mu;
        red[1] = rsqrtf(var + 1e-5f);
    }
    __syncthreads();
    const float mu = red[0], rs = red[1];
    const float4 gv = reinterpret_cast<const float4*>(g)[tid];
    const float4 bv = reinterpret_cast<const float4*>(be)[tid];
    float o0 = (v[0] - mu) * rs * gv.x + bv.x;
    float o1 = (v[1] - mu) * rs * gv.y + bv.y;
    float o2 = (v[2] - mu) * rs * gv.z + bv.z;
    float o3 = (v[3] - mu) * rs * gv.w + bv.w;
    if (OUTBF) {
        ushort4 ob;
        ob.x = f2bf(o0); ob.y = f2bf(o1); ob.z = f2bf(o2); ob.w = f2bf(o3);
        reinterpret_cast<ushort4*>((ushort*)out + (size_t)row * 1024)[tid] = ob;
    } else {
        float4 of;
        of.x = o0; of.y = o1; of.z = o2; of.w = o3;
        reinterpret_cast<float4*>((float*)out + (size_t)row * 1024)[tid] = of;
    }
}

// ---------- launch ----------
extern "C" void kernel_launch(void* const* d_in, const int* in_sizes, int n_in,
                              void* d_out, int out_size, void* d_ws, size_t ws_size,
                              hipStream_t stream) {
    const float* x  = (const float*)d_in[0];
    const float* Wq = (const float*)d_in[1];  const float* bq = (const float*)d_in[2];
    const float* Wk = (const float*)d_in[3];  const float* bk = (const float*)d_in[4];
    const float* Wv = (const float*)d_in[5];  const float* bv = (const float*)d_in[6];
    const float* Wo = (const float*)d_in[7];  const float* bo = (const float*)d_in[8];
    const float* W1 = (const float*)d_in[9];  const float* b1 = (const float*)d_in[10];
    const float* W2 = (const float*)d_in[11]; const float* b2 = (const float*)d_in[12];
    const float* g1 = (const float*)d_in[13]; const float* be1 = (const float*)d_in[14];
    const float* g2 = (const float*)d_in[15]; const float* be2 = (const float*)d_in[16];

    char* ws = (char*)d_ws;
    const size_t MBy = (size_t)1 << 20;
    ushort* xb    = (ushort*)(ws + 0 * MBy);     // 16 MB  [8192][1024] bf16
    ushort* wqkvT = (ushort*)(ws + 16 * MBy);    // 6 MB   [3072][1024]
    ushort* woT   = (ushort*)(ws + 22 * MBy);    // 2 MB
    ushort* w1T   = (ushort*)(ws + 24 * MBy);    // 8 MB   [4096][1024]
    ushort* w2T   = (ushort*)(ws + 32 * MBy);    // 8 MB   [1024][4096]
    ushort* QKVb  = (ushort*)(ws + 40 * MBy);    // 48 MB  [8192][3072]
    ushort* AOb   = (ushort*)(ws + 88 * MBy);    // 16 MB
    ushort* h1    = (ushort*)(ws + 40 * MBy);    // 64 MB (aliases QKVb+AOb, both dead by FFN1)
    ushort* z1b   = (ushort*)(ws + 104 * MBy);   // 16 MB  x + attn_out (bf16)
    ushort* z2b   = (ushort*)(ws + 104 * MBy);   // aliases z1b (dead after LN1)
    ushort* x2b   = (ushort*)(ws + 120 * MBy);   // 16 MB
    (void)ws_size; (void)n_in; (void)in_sizes; (void)out_size;

    const int M = 8192;

    cast_bf16_kernel<<<(M * 1024 / 4 + 255) / 256, 256, 0, stream>>>(x, xb, M * 1024 / 4);
    dim3 tb(32, 8);
    transpose_cast3_kernel<<<dim3(32, 32, 3), tb, 0, stream>>>(Wq, Wk, Wv, wqkvT);
    transpose_cast_kernel<<<dim3(32, 32),  tb, 0, stream>>>(Wo, woT, 1024, 1024);
    transpose_cast_kernel<<<dim3(128, 32), tb, 0, stream>>>(W1, w1T, 1024, 4096);
    transpose_cast_kernel<<<dim3(32, 128), tb, 0, stream>>>(W2, w2T, 4096, 1024);

    // QKV projection (p3; 1536 blocks -> 3/CU)
    gemm_p3<0, 1, 1, 0><<<dim3(24, 64), 256, 0, stream>>>(xb, wqkvT, bq, bk, bv, nullptr,
                                                          QKVb, M, 3072, 1024);

    // attention: 512 blocks x 512 threads (256 q-rows per block)
    attn_kernel<<<512, 512, 0, stream>>>(QKVb, AOb);

    // Wo + fused residual (x, f32) -> z1 = x + attn_out (bf16)
    gemm_p3<0, 1, 0, 1><<<dim3(8, 64), 256, 0, stream>>>(AOb, woT, bo, nullptr, nullptr, x,
                                                         z1b, M, 1024, 1024);

    // LN1 (single input)
    ln_one<1><<<M, 256, 0, stream>>>(z1b, g1, be1, x2b);

    // FFN1
    gemm_p3<1, 1, 0, 0><<<dim3(32, 64), 256, 0, stream>>>(x2b, w1T, b1, nullptr, nullptr,
                                                          nullptr, h1, M, 4096, 1024);
    // FFN2 + fused residual (x2b, bf16) -> z2 = x2 + ffn_out (bf16)
    gemm_p3<0, 1, 0, 2><<<dim3(8, 64), 256, 0, stream>>>(h1, w2T, b2, nullptr, nullptr, x2b,
                                                         z2b, M, 1024, 4096);

    // LN2 -> d_out (f32)
    ln_one<0><<<M, 256, 0, stream>>>(z2b, g2, be2, (float*)d_out);
}

// Round 17
// 387.696 us; speedup vs baseline: 1.1988x; 1.0263x over previous
//
#include <hip/hip_runtime.h>
#include <hip/hip_bf16.h>

// ---------- types ----------
typedef __attribute__((ext_vector_type(8)))  __bf16 bf16x8;
typedef __attribute__((ext_vector_type(4)))  float  f32x4;
typedef __attribute__((ext_vector_type(16))) float  f32x16;

static __device__ __forceinline__ unsigned short f2bf(float x) {
    unsigned int u = __float_as_uint(x);
    unsigned int r = (u + 0x7FFFu + ((u >> 16) & 1u)) >> 16;
    return (unsigned short)r;
}
static __device__ __forceinline__ float bf2f(unsigned short u) {
    return __uint_as_float(((unsigned int)u) << 16);
}

// 2^x via v_exp_f32 (CDNA VALU has HW interlocks; no nop needed)
static __device__ __forceinline__ float fast_exp2(float x) {
    float r;
    asm("v_exp_f32 %0, %1" : "=v"(r) : "v"(x));
    return r;
}
// packed f32x2 -> bf16x2 (u32); lo <- a, hi <- b
static __device__ __forceinline__ unsigned int cvt_pk_bf16(float a, float b) {
    unsigned int r;
    asm("v_cvt_pk_bf16_f32 %0, %1, %2" : "=v"(r) : "v"(a), "v"(b));
    return r;
}

// async global->LDS, 16B per lane; lds base wave-uniform (lane*16 auto-offset)
static __device__ __forceinline__ void gload_lds16(const ushort* g, ushort* l) {
    __builtin_amdgcn_global_load_lds((const __attribute__((address_space(1))) void*)g,
                                     (__attribute__((address_space(3))) void*)l, 16, 0, 0);
}

// raw barrier + scheduling/memory fence (no vmcnt drain, unlike __syncthreads)
static __device__ __forceinline__ void barrier_fence() {
    __builtin_amdgcn_s_barrier();
    __builtin_amdgcn_sched_barrier(0);
    asm volatile("" ::: "memory");
}

// T1: XCD-aware chunked remap (requires nwg % 8 == 0; all grids here comply)
static __device__ __forceinline__ int xcd_swz(int id, int nwg) {
    return (id & 7) * (nwg >> 3) + (id >> 3);
}

// ---------- elementwise cast f32 -> bf16 ----------
__global__ __launch_bounds__(256) void cast_bf16_kernel(const float* __restrict__ in,
                                                        ushort* __restrict__ out, int n4) {
    int i = blockIdx.x * 256 + threadIdx.x;
    if (i < n4) {
        float4 v = reinterpret_cast<const float4*>(in)[i];
        ushort4 o;
        o.x = f2bf(v.x); o.y = f2bf(v.y); o.z = f2bf(v.z); o.w = f2bf(v.w);
        reinterpret_cast<ushort4*>(out)[i] = o;
    }
}

// ---------- ALL weight transposes in one launch ----------
// flat block id ranges: [0,3072) Wq/Wk/Wv -> wqkvT; [3072,4096) Wo -> woT;
// [4096,8192) W1 (K=1024,N=4096) -> w1T; [8192,12288) W2 (K=4096,N=1024) -> w2T.
__global__ __launch_bounds__(256) void transpose_all_kernel(const float* __restrict__ Wq,
                                                            const float* __restrict__ Wk,
                                                            const float* __restrict__ Wv,
                                                            const float* __restrict__ Wo,
                                                            const float* __restrict__ W1,
                                                            const float* __restrict__ W2,
                                                            ushort* __restrict__ wqkvT,
                                                            ushort* __restrict__ woT,
                                                            ushort* __restrict__ w1T,
                                                            ushort* __restrict__ w2T) {
    __shared__ float tile[32][33];
    const int tx = threadIdx.x;        // 0..31
    const int ty = threadIdx.y;        // 0..7
    const int z  = blockIdx.x;

    const float* in;
    ushort* out;
    int K, N, idx;
    if (z < 3072) {
        const int s = z >> 10;                 // 0..2
        in  = (s == 0) ? Wq : (s == 1 ? Wk : Wv);
        out = wqkvT + (size_t)s * 1024 * 1024;
        K = 1024; N = 1024; idx = z & 1023;
    } else if (z < 4096) {
        in = Wo; out = woT; K = 1024; N = 1024; idx = z - 3072;
    } else if (z < 8192) {
        in = W1; out = w1T; K = 1024; N = 4096; idx = z - 4096;
    } else {
        in = W2; out = w2T; K = 4096; N = 1024; idx = z - 8192;
    }
    const int ntiles = N >> 5;
    const int n0 = (idx % ntiles) * 32;
    const int k0 = (idx / ntiles) * 32;

    for (int i = ty; i < 32; i += 8)
        tile[i][tx] = in[(size_t)(k0 + i) * N + n0 + tx];
    __syncthreads();
    for (int i = ty; i < 32; i += 8)
        out[(size_t)(n0 + i) * K + k0 + tx] = f2bf(tile[tx][i]);
}

// ============================================================================
// GEMM, 128x128 tile, BK=32, 256 threads (4 waves, 2x2 of 64x64).
// 3 LDS buffers, counted-vmcnt pipeline (round-8 structure, measured best):
//   iter t: s_waitcnt vmcnt(4) ; s_barrier ; issue tile t+2 ; compute tile t.
// T2 bank-conflict swizzle (round-11): chunk ^= (row>>1)&3, both sides.
// RES: 0 none, 1 add f32 residual, 2 add bf16 residual in epilogue.
// ============================================================================
template<int RELU, int OUTBF, int QKV, int RES>
__global__ __launch_bounds__(256) void gemm_p3(const ushort* __restrict__ A,
                                               const ushort* __restrict__ Bt,
                                               const float* __restrict__ b0,
                                               const float* __restrict__ b1_,
                                               const float* __restrict__ b2_,
                                               const void* __restrict__ xres,
                                               void* __restrict__ Cp,
                                               int M, int N, int K) {
    __shared__ ushort As[3][4096];
    __shared__ ushort Bs[3][4096];
    const int tid  = threadIdx.x;
    const int lane = tid & 63;
    const int w    = tid >> 6;
    const int wr   = w >> 1, wc = w & 1;
    const int nwg = gridDim.x * gridDim.y;
    int wid = xcd_swz(blockIdx.y * gridDim.x + blockIdx.x, nwg);
    const int bx = wid % gridDim.x;
    const int by = wid / gridDim.x;
    const int m0 = by * 128;
    const int n0 = bx * 128;
    const int lr = lane & 15;
    const int lg = lane >> 4;
    const int xc = (lg ^ ((lr >> 1) & 3)) * 8;

    const int r0 = w * 32 + (lane >> 2);
    const int c8 = ((lane & 3) ^ ((lane >> 3) & 3)) * 8;
    const ushort* gA0 = A  + (size_t)(m0 + r0)      * K + c8;
    const ushort* gA1 = A  + (size_t)(m0 + r0 + 16) * K + c8;
    const ushort* gB0 = Bt + (size_t)(n0 + r0)      * K + c8;
    const ushort* gB1 = Bt + (size_t)(n0 + r0 + 16) * K + c8;
    const int wb = w * 1024;

    f32x4 acc[4][4];
    const f32x4 z = {0.f, 0.f, 0.f, 0.f};
#pragma unroll
    for (int i = 0; i < 4; i++)
#pragma unroll
        for (int j = 0; j < 4; j++) acc[i][j] = z;

    const int nt = K >> 5;

#pragma unroll
    for (int t = 0; t < 2; ++t) {
        const int kn = t * 32;
        gload_lds16(gA0 + kn, &As[t][wb]);
        gload_lds16(gA1 + kn, &As[t][wb + 512]);
        gload_lds16(gB0 + kn, &Bs[t][wb]);
        gload_lds16(gB1 + kn, &Bs[t][wb + 512]);
    }

    int cur = 0;
    for (int t = 0; t < nt; ++t) {
        if (t + 1 < nt) asm volatile("s_waitcnt vmcnt(4)" ::: "memory");
        else            asm volatile("s_waitcnt vmcnt(0)" ::: "memory");
        barrier_fence();

        if (t + 2 < nt) {
            const int bi = (cur + 2 >= 3) ? cur - 1 : cur + 2;
            const int kn = (t + 2) * 32;
            gload_lds16(gA0 + kn, &As[bi][wb]);
            gload_lds16(gA1 + kn, &As[bi][wb + 512]);
            gload_lds16(gB0 + kn, &Bs[bi][wb]);
            gload_lds16(gB1 + kn, &Bs[bi][wb + 512]);
        }

        const ushort* Asb = As[cur];
        const ushort* Bsb = Bs[cur];
        bf16x8 af[4], bfr[4];
#pragma unroll
        for (int i = 0; i < 4; i++)
            af[i] = *reinterpret_cast<const bf16x8*>(&Asb[(wr * 64 + i * 16 + lr) * 32 + xc]);
#pragma unroll
        for (int j = 0; j < 4; j++)
            bfr[j] = *reinterpret_cast<const bf16x8*>(&Bsb[(wc * 64 + j * 16 + lr) * 32 + xc]);
#pragma unroll
        for (int i = 0; i < 4; i++)
#pragma unroll
            for (int j = 0; j < 4; j++)
                acc[i][j] = __builtin_amdgcn_mfma_f32_16x16x32_bf16(af[i], bfr[j], acc[i][j], 0, 0, 0);

        cur = (cur == 2) ? 0 : cur + 1;
    }

    const float* bias;
    float qscale = 1.0f;
    if (QKV) {
        bias = (n0 < 1024) ? b0 : (n0 < 2048 ? b1_ : b2_);
        if (n0 < 1024) qscale = 0.18033688f;   // 0.125*log2(e) folded into Q
    } else {
        bias = b0;
    }
    const int nb = QKV ? (n0 & 1023) : n0;
    const int rbase = (lane >> 4) * 4;
#pragma unroll
    for (int i = 0; i < 4; i++) {
#pragma unroll
        for (int j = 0; j < 4; j++) {
            const int cloc = wc * 64 + j * 16 + lr;
            const float bv = bias[nb + cloc];
#pragma unroll
            for (int r = 0; r < 4; r++) {
                const int row = m0 + wr * 64 + i * 16 + rbase + r;
                float v = acc[i][j][r] + bv;
                if (RES == 1) v += ((const float*)xres)[(size_t)row * N + n0 + cloc];
                if (RES == 2) v += bf2f(((const ushort*)xres)[(size_t)row * N + n0 + cloc]);
                if (RELU) v = v > 0.f ? v : 0.f;
                if (QKV)  v *= qscale;
                if (OUTBF) ((ushort*)Cp)[(size_t)row * N + n0 + cloc] = f2bf(v);
                else       ((float*)Cp)[(size_t)row * N + n0 + cloc] = v;
            }
        }
    }
}

// ---------- flash attention, 32x32 swapped-QK^T, in-register P (T12) ----------
// 8 waves x 32 q-rows = 256 q-rows per block (grid 512, 2 blocks/CU).
#define ASWZ(row, col) ((row) * 64 + ((col) ^ ((((row) ^ ((row) >> 3)) & 7) << 3)))

__global__ __launch_bounds__(512, 4) void attn_kernel(const ushort* __restrict__ QKV,
                                                      ushort* __restrict__ O) {
    __shared__ ushort Ks[2][4096];
    __shared__ ushort Vt[2][4096];
    const int tid  = threadIdx.x;          // 0..511
    const int lane = tid & 63;
    const int w    = tid >> 6;             // 0..7
    const int l31  = lane & 31;
    const int hi   = lane >> 5;

    int blk = xcd_swz(blockIdx.x, gridDim.x);   // 512 blocks
    const int qb = blk & 7;
    const int h  = (blk >> 3) & 15;
    const int b  = blk >> 7;
    const int s0 = qb * 256 + w * 32;
    const size_t rowb   = (size_t)b * 2048;
    const size_t base_q = rowb * 3072 + (size_t)h * 64;
    const size_t base_k = base_q + 1024;
    const size_t base_v = base_q + 2048;
    const size_t base_o = rowb * 1024 + (size_t)h * 64;

    bf16x8 qf[4];
#pragma unroll
    for (int ks = 0; ks < 4; ks++)
        qf[ks] = *reinterpret_cast<const bf16x8*>(
            &QKV[base_q + (size_t)(s0 + l31) * 3072 + ks * 16 + 8 * hi]);

    int off8[2][4];
#pragma unroll
    for (int sub = 0; sub < 2; sub++)
#pragma unroll
        for (int ks = 0; ks < 4; ks++)
            off8[sub][ks] = ASWZ(sub * 32 + l31, ks * 16 + 8 * hi);

    const int tS  = tid >> 3;              // row 0..63
    const int ccS = tid & 7;
    int voff[8];
#pragma unroll
    for (int jj = 0; jj < 8; jj++)
        voff[jj] = ASWZ(ccS * 8 + jj, tS);
    const int szK = (tS ^ (tS >> 3)) & 7;
    const ushort* pK = QKV + base_k + (size_t)tS * 3072 + (ccS ^ szK) * 8;
    const ushort* pV = QKV + base_v + (size_t)tS * 3072 + ccS * 8;
    const size_t step = (size_t)64 * 3072;

    gload_lds16(pK, &Ks[0][w * 512]);
    {
        int4 v0 = *reinterpret_cast<const int4*>(pV);
        const ushort* vs = reinterpret_cast<const ushort*>(&v0);
#pragma unroll
        for (int jj = 0; jj < 8; jj++) Vt[0][voff[jj]] = vs[jj];
    }
    pK += step; pV += step;
    __syncthreads();

    f32x16 oacc0, oacc1;
    for (int i = 0; i < 16; i++) { oacc0[i] = 0.f; oacc1[i] = 0.f; }
    float lacc = 0.f;
    int cur = 0;

    for (int it = 0; it < 32; ++it) {
        int4 nv;
        if (it < 31) {
            gload_lds16(pK, &Ks[cur ^ 1][w * 512]);
            nv = *reinterpret_cast<const int4*>(pV);
            pK += step; pV += step;
        }

        f32x16 sa0, sa1;
        for (int i = 0; i < 16; i++) { sa0[i] = 0.f; sa1[i] = 0.f; }
        __builtin_amdgcn_s_setprio(1);
#pragma unroll
        for (int ks = 0; ks < 4; ks++) {
            bf16x8 k0 = *reinterpret_cast<const bf16x8*>(&Ks[cur][off8[0][ks]]);
            sa0 = __builtin_amdgcn_mfma_f32_32x32x16_bf16(k0, qf[ks], sa0, 0, 0, 0);
        }
#pragma unroll
        for (int ks = 0; ks < 4; ks++) {
            bf16x8 k1 = *reinterpret_cast<const bf16x8*>(&Ks[cur][off8[1][ks]]);
            sa1 = __builtin_amdgcn_mfma_f32_32x32x16_bf16(k1, qf[ks], sa1, 0, 0, 0);
        }
        __builtin_amdgcn_s_setprio(0);

        unsigned pk0[8], pk1[8];
#pragma unroll
        for (int i = 0; i < 8; i++) {
            float plo = fast_exp2(sa0[2 * i]);
            float phi = fast_exp2(sa0[2 * i + 1]);
            lacc += plo + phi;
            pk0[i] = cvt_pk_bf16(plo, phi);
        }
#pragma unroll
        for (int i = 0; i < 8; i++) {
            float plo = fast_exp2(sa1[2 * i]);
            float phi = fast_exp2(sa1[2 * i + 1]);
            lacc += plo + phi;
            pk1[i] = cvt_pk_bf16(plo, phi);
        }

        __builtin_amdgcn_s_setprio(1);
#pragma unroll
        for (int ks = 0; ks < 4; ks++) {
            const int bi = 4 * (ks & 1);
            unsigned a, bb, c, d;
            if (ks < 2) { a = pk0[bi]; bb = pk0[bi + 1]; c = pk0[bi + 2]; d = pk0[bi + 3]; }
            else        { a = pk1[bi]; bb = pk1[bi + 1]; c = pk1[bi + 2]; d = pk1[bi + 3]; }
            asm("v_permlane32_swap_b32 %0, %1" : "+v"(a), "+v"(c));
            asm("v_permlane32_swap_b32 %0, %1" : "+v"(bb), "+v"(d));
            union { unsigned u[4]; bf16x8 v; } fr;
            fr.u[0] = a; fr.u[1] = bb; fr.u[2] = c; fr.u[3] = d;
            bf16x8 v0 = *reinterpret_cast<const bf16x8*>(&Vt[cur][off8[0][ks]]);
            oacc0 = __builtin_amdgcn_mfma_f32_32x32x16_bf16(fr.v, v0, oacc0, 0, 0, 0);
            bf16x8 v1 = *reinterpret_cast<const bf16x8*>(&Vt[cur][off8[1][ks]]);
            oacc1 = __builtin_amdgcn_mfma_f32_32x32x16_bf16(fr.v, v1, oacc1, 0, 0, 0);
        }
        __builtin_amdgcn_s_setprio(0);

        if (it < 31) {
            const ushort* vs = reinterpret_cast<const ushort*>(&nv);
#pragma unroll
            for (int jj = 0; jj < 8; jj++) Vt[cur ^ 1][voff[jj]] = vs[jj];
        }
        __syncthreads();
        cur ^= 1;
    }

    const float ltot = lacc + __shfl_xor(lacc, 32);
    const float inv  = 1.f / ltot;
#pragma unroll
    for (int r = 0; r < 16; r++) {
        const int qloc = (r & 3) + 8 * (r >> 2) + 4 * hi;
        const float invq = __shfl(inv, qloc);
        const size_t rowoff = base_o + (size_t)(s0 + qloc) * 1024 + l31;
        O[rowoff]      = f2bf(oacc0[r] * invq);
        O[rowoff + 32] = f2bf(oacc1[r] * invq);
    }
}

// ---------- single-input layernorm (residual already added in GEMM epilogue) ----------
template<int OUTBF>
__global__ __launch_bounds__(256) void ln_one(const ushort* __restrict__ zin,
                                              const float* __restrict__ g,
                                              const float* __restrict__ be,
                                              void* __restrict__ out) {
    const int row = blockIdx.x;
    const int tid = threadIdx.x;
    const ushort4 zv = reinterpret_cast<const ushort4*>(zin + (size_t)row * 1024)[tid];
    float v[4] = {bf2f(zv.x), bf2f(zv.y), bf2f(zv.z), bf2f(zv.w)};
    float s  = v[0] + v[1] + v[2] + v[3];
    float s2 = v[0]*v[0] + v[1]*v[1] + v[2]*v[2] + v[3]*v[3];
    for (int off = 32; off; off >>= 1) { s += __shfl_down(s, off); s2 += __shfl_down(s2, off); }
    __shared__ float red[8];
    const int w = tid >> 6, lane = tid & 63;
    if (lane == 0) { red[w] = s; red[4 + w] = s2; }
    __syncthreads();
    if (tid == 0) {
        const float ts  = red[0] + red[1] + red[2] + red[3];
        const float ts2 = red[4] + red[5] + red[6] + red[7];
        const float mu  = ts * (1.f / 1024.f);
        const float var = ts2 * (1.f / 1024.f) - mu * mu;
        red[0] = mu;
        red[1] = rsqrtf(var + 1e-5f);
    }
    __syncthreads();
    const float mu = red[0], rs = red[1];
    const float4 gv = reinterpret_cast<const float4*>(g)[tid];
    const float4 bv = reinterpret_cast<const float4*>(be)[tid];
    float o0 = (v[0] - mu) * rs * gv.x + bv.x;
    float o1 = (v[1] - mu) * rs * gv.y + bv.y;
    float o2 = (v[2] - mu) * rs * gv.z + bv.z;
    float o3 = (v[3] - mu) * rs * gv.w + bv.w;
    if (OUTBF) {
        ushort4 ob;
        ob.x = f2bf(o0); ob.y = f2bf(o1); ob.z = f2bf(o2); ob.w = f2bf(o3);
        reinterpret_cast<ushort4*>((ushort*)out + (size_t)row * 1024)[tid] = ob;
    } else {
        float4 of;
        of.x = o0; of.y = o1; of.z = o2; of.w = o3;
        reinterpret_cast<float4*>((float*)out + (size_t)row * 1024)[tid] = of;
    }
}

// ---------- launch ----------
extern "C" void kernel_launch(void* const* d_in, const int* in_sizes, int n_in,
                              void* d_out, int out_size, void* d_ws, size_t ws_size,
                              hipStream_t stream) {
    const float* x  = (const float*)d_in[0];
    const float* Wq = (const float*)d_in[1];  const float* bq = (const float*)d_in[2];
    const float* Wk = (const float*)d_in[3];  const float* bk = (const float*)d_in[4];
    const float* Wv = (const float*)d_in[5];  const float* bv = (const float*)d_in[6];
    const float* Wo = (const float*)d_in[7];  const float* bo = (const float*)d_in[8];
    const float* W1 = (const float*)d_in[9];  const float* b1 = (const float*)d_in[10];
    const float* W2 = (const float*)d_in[11]; const float* b2 = (const float*)d_in[12];
    const float* g1 = (const float*)d_in[13]; const float* be1 = (const float*)d_in[14];
    const float* g2 = (const float*)d_in[15]; const float* be2 = (const float*)d_in[16];

    char* ws = (char*)d_ws;
    const size_t MBy = (size_t)1 << 20;
    ushort* xb    = (ushort*)(ws + 0 * MBy);     // 16 MB  [8192][1024] bf16
    ushort* wqkvT = (ushort*)(ws + 16 * MBy);    // 6 MB   [3072][1024]
    ushort* woT   = (ushort*)(ws + 22 * MBy);    // 2 MB
    ushort* w1T   = (ushort*)(ws + 24 * MBy);    // 8 MB   [4096][1024]
    ushort* w2T   = (ushort*)(ws + 32 * MBy);    // 8 MB   [1024][4096]
    ushort* QKVb  = (ushort*)(ws + 40 * MBy);    // 48 MB  [8192][3072]
    ushort* AOb   = (ushort*)(ws + 88 * MBy);    // 16 MB
    ushort* h1    = (ushort*)(ws + 40 * MBy);    // 64 MB (aliases QKVb+AOb, both dead by FFN1)
    ushort* z1b   = (ushort*)(ws + 104 * MBy);   // 16 MB  x + attn_out (bf16)
    ushort* z2b   = (ushort*)(ws + 104 * MBy);   // aliases z1b (dead after LN1)
    ushort* x2b   = (ushort*)(ws + 120 * MBy);   // 16 MB
    (void)ws_size; (void)n_in; (void)in_sizes; (void)out_size;

    const int M = 8192;

    cast_bf16_kernel<<<(M * 1024 / 4 + 255) / 256, 256, 0, stream>>>(x, xb, M * 1024 / 4);
    // all weight transposes in one launch (12288 tile-blocks of 32x8)
    transpose_all_kernel<<<12288, dim3(32, 8), 0, stream>>>(Wq, Wk, Wv, Wo, W1, W2,
                                                            wqkvT, woT, w1T, w2T);

    // QKV projection (p3; 1536 blocks -> 3/CU)
    gemm_p3<0, 1, 1, 0><<<dim3(24, 64), 256, 0, stream>>>(xb, wqkvT, bq, bk, bv, nullptr,
                                                          QKVb, M, 3072, 1024);

    // attention: 512 blocks x 512 threads (256 q-rows per block)
    attn_kernel<<<512, 512, 0, stream>>>(QKVb, AOb);

    // Wo + fused residual (xb, bf16) -> z1 = x + attn_out (bf16)
    gemm_p3<0, 1, 0, 2><<<dim3(8, 64), 256, 0, stream>>>(AOb, woT, bo, nullptr, nullptr, xb,
                                                         z1b, M, 1024, 1024);

    // LN1 (single input)
    ln_one<1><<<M, 256, 0, stream>>>(z1b, g1, be1, x2b);

    // FFN1
    gemm_p3<1, 1, 0, 0><<<dim3(32, 64), 256, 0, stream>>>(x2b, w1T, b1, nullptr, nullptr,
                                                          nullptr, h1, M, 4096, 1024);
    // FFN2 + fused residual (x2b, bf16) -> z2 = x2 + ffn_out (bf16)
    gemm_p3<0, 1, 0, 2><<<dim3(8, 64), 256, 0, stream>>>(h1, w2T, b2, nullptr, nullptr, x2b,
                                                         z2b, M, 1024, 4096);

    // LN2 -> d_out (f32)
    ln_one<0><<<M, 256, 0, stream>>>(z2b, g2, be2, (float*)d_out);
}

// Round 18
// 385.912 us; speedup vs baseline: 1.2043x; 1.0046x over previous
//
#include <hip/hip_runtime.h>
#include <hip/hip_bf16.h>

// ---------- types ----------
typedef __attribute__((ext_vector_type(8)))  __bf16 bf16x8;
typedef __attribute__((ext_vector_type(4)))  float  f32x4;
typedef __attribute__((ext_vector_type(16))) float  f32x16;

static __device__ __forceinline__ unsigned short f2bf(float x) {
    unsigned int u = __float_as_uint(x);
    unsigned int r = (u + 0x7FFFu + ((u >> 16) & 1u)) >> 16;
    return (unsigned short)r;
}
static __device__ __forceinline__ float bf2f(unsigned short u) {
    return __uint_as_float(((unsigned int)u) << 16);
}

// 2^x via v_exp_f32 (CDNA VALU has HW interlocks; no nop needed)
static __device__ __forceinline__ float fast_exp2(float x) {
    float r;
    asm("v_exp_f32 %0, %1" : "=v"(r) : "v"(x));
    return r;
}
// packed f32x2 -> bf16x2 (u32); lo <- a, hi <- b
static __device__ __forceinline__ unsigned int cvt_pk_bf16(float a, float b) {
    unsigned int r;
    asm("v_cvt_pk_bf16_f32 %0, %1, %2" : "=v"(r) : "v"(a), "v"(b));
    return r;
}

// async global->LDS, 16B per lane; lds base wave-uniform (lane*16 auto-offset)
static __device__ __forceinline__ void gload_lds16(const ushort* g, ushort* l) {
    __builtin_amdgcn_global_load_lds((const __attribute__((address_space(1))) void*)g,
                                     (__attribute__((address_space(3))) void*)l, 16, 0, 0);
}

// raw barrier + scheduling/memory fence (no vmcnt drain, unlike __syncthreads)
static __device__ __forceinline__ void barrier_fence() {
    __builtin_amdgcn_s_barrier();
    __builtin_amdgcn_sched_barrier(0);
    asm volatile("" ::: "memory");
}

// T1: XCD-aware chunked remap (requires nwg % 8 == 0; all grids here comply)
static __device__ __forceinline__ int xcd_swz(int id, int nwg) {
    return (id & 7) * (nwg >> 3) + (id >> 3);
}

// ---------- fused prep: x cast (blocks 0..8191) + ALL weight transposes ----------
// blocks [0,8192): cast row b of x (1024 f32 -> bf16), 256 thr x 4 elems.
// blocks [8192,20480): 32x32 transpose tiles; sub-ranges per weight:
//   [0,3072) Wq/Wk/Wv -> wqkvT ; [3072,4096) Wo -> woT ;
//   [4096,8192) W1 (K=1024,N=4096) -> w1T ; [8192,12288) W2 (K=4096,N=1024) -> w2T.
__global__ __launch_bounds__(256) void prep_kernel(const float* __restrict__ x,
                                                   ushort* __restrict__ xb,
                                                   const float* __restrict__ Wq,
                                                   const float* __restrict__ Wk,
                                                   const float* __restrict__ Wv,
                                                   const float* __restrict__ Wo,
                                                   const float* __restrict__ W1,
                                                   const float* __restrict__ W2,
                                                   ushort* __restrict__ wqkvT,
                                                   ushort* __restrict__ woT,
                                                   ushort* __restrict__ w1T,
                                                   ushort* __restrict__ w2T) {
    const int bid = blockIdx.x;
    if (bid < 8192) {
        const int i = bid * 256 + threadIdx.x + threadIdx.y * 32;
        float4 v = reinterpret_cast<const float4*>(x)[i];
        ushort4 o;
        o.x = f2bf(v.x); o.y = f2bf(v.y); o.z = f2bf(v.z); o.w = f2bf(v.w);
        reinterpret_cast<ushort4*>(xb)[i] = o;
        return;
    }
    __shared__ float tile[32][33];
    const int tx = threadIdx.x;        // 0..31
    const int ty = threadIdx.y;        // 0..7
    const int z  = bid - 8192;

    const float* in;
    ushort* out;
    int K, N, idx;
    if (z < 3072) {
        const int s = z >> 10;
        in  = (s == 0) ? Wq : (s == 1 ? Wk : Wv);
        out = wqkvT + (size_t)s * 1024 * 1024;
        K = 1024; N = 1024; idx = z & 1023;
    } else if (z < 4096) {
        in = Wo; out = woT; K = 1024; N = 1024; idx = z - 3072;
    } else if (z < 8192) {
        in = W1; out = w1T; K = 1024; N = 4096; idx = z - 4096;
    } else {
        in = W2; out = w2T; K = 4096; N = 1024; idx = z - 8192;
    }
    const int ntiles = N >> 5;
    const int n0 = (idx % ntiles) * 32;
    const int k0 = (idx / ntiles) * 32;

    for (int i = ty; i < 32; i += 8)
        tile[i][tx] = in[(size_t)(k0 + i) * N + n0 + tx];
    __syncthreads();
    for (int i = ty; i < 32; i += 8)
        out[(size_t)(n0 + i) * K + k0 + tx] = f2bf(tile[tx][i]);
}

// ============================================================================
// GEMM, 128x128 tile, BK=32, 256 threads (4 waves, 2x2 of 64x64).
// 3 LDS buffers, counted-vmcnt pipeline (round-8 structure, measured best):
//   iter t: s_waitcnt vmcnt(4) ; s_barrier ; issue tile t+2 ; compute tile t.
// T2 bank-conflict swizzle (round-11): chunk ^= (row>>1)&3, both sides.
// RES: 0 none, 1 add f32 residual, 2 add bf16 residual in epilogue.
// ============================================================================
template<int RELU, int OUTBF, int QKV, int RES>
__global__ __launch_bounds__(256) void gemm_p3(const ushort* __restrict__ A,
                                               const ushort* __restrict__ Bt,
                                               const float* __restrict__ b0,
                                               const float* __restrict__ b1_,
                                               const float* __restrict__ b2_,
                                               const void* __restrict__ xres,
                                               void* __restrict__ Cp,
                                               int M, int N, int K) {
    __shared__ ushort As[3][4096];
    __shared__ ushort Bs[3][4096];
    const int tid  = threadIdx.x;
    const int lane = tid & 63;
    const int w    = tid >> 6;
    const int wr   = w >> 1, wc = w & 1;
    const int nwg = gridDim.x * gridDim.y;
    int wid = xcd_swz(blockIdx.y * gridDim.x + blockIdx.x, nwg);
    const int bx = wid % gridDim.x;
    const int by = wid / gridDim.x;
    const int m0 = by * 128;
    const int n0 = bx * 128;
    const int lr = lane & 15;
    const int lg = lane >> 4;
    const int xc = (lg ^ ((lr >> 1) & 3)) * 8;

    const int r0 = w * 32 + (lane >> 2);
    const int c8 = ((lane & 3) ^ ((lane >> 3) & 3)) * 8;
    const ushort* gA0 = A  + (size_t)(m0 + r0)      * K + c8;
    const ushort* gA1 = A  + (size_t)(m0 + r0 + 16) * K + c8;
    const ushort* gB0 = Bt + (size_t)(n0 + r0)      * K + c8;
    const ushort* gB1 = Bt + (size_t)(n0 + r0 + 16) * K + c8;
    const int wb = w * 1024;

    f32x4 acc[4][4];
    const f32x4 z = {0.f, 0.f, 0.f, 0.f};
#pragma unroll
    for (int i = 0; i < 4; i++)
#pragma unroll
        for (int j = 0; j < 4; j++) acc[i][j] = z;

    const int nt = K >> 5;

#pragma unroll
    for (int t = 0; t < 2; ++t) {
        const int kn = t * 32;
        gload_lds16(gA0 + kn, &As[t][wb]);
        gload_lds16(gA1 + kn, &As[t][wb + 512]);
        gload_lds16(gB0 + kn, &Bs[t][wb]);
        gload_lds16(gB1 + kn, &Bs[t][wb + 512]);
    }

    int cur = 0;
    for (int t = 0; t < nt; ++t) {
        if (t + 1 < nt) asm volatile("s_waitcnt vmcnt(4)" ::: "memory");
        else            asm volatile("s_waitcnt vmcnt(0)" ::: "memory");
        barrier_fence();

        if (t + 2 < nt) {
            const int bi = (cur + 2 >= 3) ? cur - 1 : cur + 2;
            const int kn = (t + 2) * 32;
            gload_lds16(gA0 + kn, &As[bi][wb]);
            gload_lds16(gA1 + kn, &As[bi][wb + 512]);
            gload_lds16(gB0 + kn, &Bs[bi][wb]);
            gload_lds16(gB1 + kn, &Bs[bi][wb + 512]);
        }

        const ushort* Asb = As[cur];
        const ushort* Bsb = Bs[cur];
        bf16x8 af[4], bfr[4];
#pragma unroll
        for (int i = 0; i < 4; i++)
            af[i] = *reinterpret_cast<const bf16x8*>(&Asb[(wr * 64 + i * 16 + lr) * 32 + xc]);
#pragma unroll
        for (int j = 0; j < 4; j++)
            bfr[j] = *reinterpret_cast<const bf16x8*>(&Bsb[(wc * 64 + j * 16 + lr) * 32 + xc]);
#pragma unroll
        for (int i = 0; i < 4; i++)
#pragma unroll
            for (int j = 0; j < 4; j++)
                acc[i][j] = __builtin_amdgcn_mfma_f32_16x16x32_bf16(af[i], bfr[j], acc[i][j], 0, 0, 0);

        cur = (cur == 2) ? 0 : cur + 1;
    }

    const float* bias;
    float qscale = 1.0f;
    if (QKV) {
        bias = (n0 < 1024) ? b0 : (n0 < 2048 ? b1_ : b2_);
        if (n0 < 1024) qscale = 0.18033688f;   // 0.125*log2(e) folded into Q
    } else {
        bias = b0;
    }
    const int nb = QKV ? (n0 & 1023) : n0;
    const int rbase = (lane >> 4) * 4;
#pragma unroll
    for (int i = 0; i < 4; i++) {
#pragma unroll
        for (int j = 0; j < 4; j++) {
            const int cloc = wc * 64 + j * 16 + lr;
            const float bv = bias[nb + cloc];
#pragma unroll
            for (int r = 0; r < 4; r++) {
                const int row = m0 + wr * 64 + i * 16 + rbase + r;
                float v = acc[i][j][r] + bv;
                if (RES == 1) v += ((const float*)xres)[(size_t)row * N + n0 + cloc];
                if (RES == 2) v += bf2f(((const ushort*)xres)[(size_t)row * N + n0 + cloc]);
                if (RELU) v = v > 0.f ? v : 0.f;
                if (QKV)  v *= qscale;
                if (OUTBF) ((ushort*)Cp)[(size_t)row * N + n0 + cloc] = f2bf(v);
                else       ((float*)Cp)[(size_t)row * N + n0 + cloc] = v;
            }
        }
    }
}

// ---------- flash attention, 32x32 swapped-QK^T, in-register P (T12) ----------
// 8 waves x 32 q-rows = 256 q-rows per block (grid 512, 2 blocks/CU).
#define ASWZ(row, col) ((row) * 64 + ((col) ^ ((((row) ^ ((row) >> 3)) & 7) << 3)))

__global__ __launch_bounds__(512, 4) void attn_kernel(const ushort* __restrict__ QKV,
                                                      ushort* __restrict__ O) {
    __shared__ ushort Ks[2][4096];
    __shared__ ushort Vt[2][4096];
    const int tid  = threadIdx.x;          // 0..511
    const int lane = tid & 63;
    const int w    = tid >> 6;             // 0..7
    const int l31  = lane & 31;
    const int hi   = lane >> 5;

    int blk = xcd_swz(blockIdx.x, gridDim.x);   // 512 blocks
    const int qb = blk & 7;
    const int h  = (blk >> 3) & 15;
    const int b  = blk >> 7;
    const int s0 = qb * 256 + w * 32;
    const size_t rowb   = (size_t)b * 2048;
    const size_t base_q = rowb * 3072 + (size_t)h * 64;
    const size_t base_k = base_q + 1024;
    const size_t base_v = base_q + 2048;
    const size_t base_o = rowb * 1024 + (size_t)h * 64;

    bf16x8 qf[4];
#pragma unroll
    for (int ks = 0; ks < 4; ks++)
        qf[ks] = *reinterpret_cast<const bf16x8*>(
            &QKV[base_q + (size_t)(s0 + l31) * 3072 + ks * 16 + 8 * hi]);

    int off8[2][4];
#pragma unroll
    for (int sub = 0; sub < 2; sub++)
#pragma unroll
        for (int ks = 0; ks < 4; ks++)
            off8[sub][ks] = ASWZ(sub * 32 + l31, ks * 16 + 8 * hi);

    const int tS  = tid >> 3;              // row 0..63
    const int ccS = tid & 7;
    int voff[8];
#pragma unroll
    for (int jj = 0; jj < 8; jj++)
        voff[jj] = ASWZ(ccS * 8 + jj, tS);
    const int szK = (tS ^ (tS >> 3)) & 7;
    const ushort* pK = QKV + base_k + (size_t)tS * 3072 + (ccS ^ szK) * 8;
    const ushort* pV = QKV + base_v + (size_t)tS * 3072 + ccS * 8;
    const size_t step = (size_t)64 * 3072;

    gload_lds16(pK, &Ks[0][w * 512]);
    {
        int4 v0 = *reinterpret_cast<const int4*>(pV);
        const ushort* vs = reinterpret_cast<const ushort*>(&v0);
#pragma unroll
        for (int jj = 0; jj < 8; jj++) Vt[0][voff[jj]] = vs[jj];
    }
    pK += step; pV += step;
    __syncthreads();

    f32x16 oacc0, oacc1;
    for (int i = 0; i < 16; i++) { oacc0[i] = 0.f; oacc1[i] = 0.f; }
    float lacc = 0.f;
    int cur = 0;

    for (int it = 0; it < 32; ++it) {
        int4 nv;
        if (it < 31) {
            gload_lds16(pK, &Ks[cur ^ 1][w * 512]);
            nv = *reinterpret_cast<const int4*>(pV);
            pK += step; pV += step;
        }

        f32x16 sa0, sa1;
        for (int i = 0; i < 16; i++) { sa0[i] = 0.f; sa1[i] = 0.f; }
        __builtin_amdgcn_s_setprio(1);
#pragma unroll
        for (int ks = 0; ks < 4; ks++) {
            bf16x8 k0 = *reinterpret_cast<const bf16x8*>(&Ks[cur][off8[0][ks]]);
            sa0 = __builtin_amdgcn_mfma_f32_32x32x16_bf16(k0, qf[ks], sa0, 0, 0, 0);
        }
#pragma unroll
        for (int ks = 0; ks < 4; ks++) {
            bf16x8 k1 = *reinterpret_cast<const bf16x8*>(&Ks[cur][off8[1][ks]]);
            sa1 = __builtin_amdgcn_mfma_f32_32x32x16_bf16(k1, qf[ks], sa1, 0, 0, 0);
        }
        __builtin_amdgcn_s_setprio(0);

        unsigned pk0[8], pk1[8];
#pragma unroll
        for (int i = 0; i < 8; i++) {
            float plo = fast_exp2(sa0[2 * i]);
            float phi = fast_exp2(sa0[2 * i + 1]);
            lacc += plo + phi;
            pk0[i] = cvt_pk_bf16(plo, phi);
        }
#pragma unroll
        for (int i = 0; i < 8; i++) {
            float plo = fast_exp2(sa1[2 * i]);
            float phi = fast_exp2(sa1[2 * i + 1]);
            lacc += plo + phi;
            pk1[i] = cvt_pk_bf16(plo, phi);
        }

        __builtin_amdgcn_s_setprio(1);
#pragma unroll
        for (int ks = 0; ks < 4; ks++) {
            const int bi = 4 * (ks & 1);
            unsigned a, bb, c, d;
            if (ks < 2) { a = pk0[bi]; bb = pk0[bi + 1]; c = pk0[bi + 2]; d = pk0[bi + 3]; }
            else        { a = pk1[bi]; bb = pk1[bi + 1]; c = pk1[bi + 2]; d = pk1[bi + 3]; }
            asm("v_permlane32_swap_b32 %0, %1" : "+v"(a), "+v"(c));
            asm("v_permlane32_swap_b32 %0, %1" : "+v"(bb), "+v"(d));
            union { unsigned u[4]; bf16x8 v; } fr;
            fr.u[0] = a; fr.u[1] = bb; fr.u[2] = c; fr.u[3] = d;
            bf16x8 v0 = *reinterpret_cast<const bf16x8*>(&Vt[cur][off8[0][ks]]);
            oacc0 = __builtin_amdgcn_mfma_f32_32x32x16_bf16(fr.v, v0, oacc0, 0, 0, 0);
            bf16x8 v1 = *reinterpret_cast<const bf16x8*>(&Vt[cur][off8[1][ks]]);
            oacc1 = __builtin_amdgcn_mfma_f32_32x32x16_bf16(fr.v, v1, oacc1, 0, 0, 0);
        }
        __builtin_amdgcn_s_setprio(0);

        if (it < 31) {
            const ushort* vs = reinterpret_cast<const ushort*>(&nv);
#pragma unroll
            for (int jj = 0; jj < 8; jj++) Vt[cur ^ 1][voff[jj]] = vs[jj];
        }
        __syncthreads();
        cur ^= 1;
    }

    const float ltot = lacc + __shfl_xor(lacc, 32);
    const float inv  = 1.f / ltot;
#pragma unroll
    for (int r = 0; r < 16; r++) {
        const int qloc = (r & 3) + 8 * (r >> 2) + 4 * hi;
        const float invq = __shfl(inv, qloc);
        const size_t rowoff = base_o + (size_t)(s0 + qloc) * 1024 + l31;
        O[rowoff]      = f2bf(oacc0[r] * invq);
        O[rowoff + 32] = f2bf(oacc1[r] * invq);
    }
}

// ---------- single-input layernorm (residual already added in GEMM epilogue) ----------
template<int OUTBF>
__global__ __launch_bounds__(256) void ln_one(const ushort* __restrict__ zin,
                                              const float* __restrict__ g,
                                              const float* __restrict__ be,
                                              void* __restrict__ out) {
    const int row = blockIdx.x;
    const int tid = threadIdx.x;
    const ushort4 zv = reinterpret_cast<const ushort4*>(zin + (size_t)row * 1024)[tid];
    float v[4] = {bf2f(zv.x), bf2f(zv.y), bf2f(zv.z), bf2f(zv.w)};
    float s  = v[0] + v[1] + v[2] + v[3];
    float s2 = v[0]*v[0] + v[1]*v[1] + v[2]*v[2] + v[3]*v[3];
    for (int off = 32; off; off >>= 1) { s += __shfl_down(s, off); s2 += __shfl_down(s2, off); }
    __shared__ float red[8];
    const int w = tid >> 6, lane = tid & 63;
    if (lane == 0) { red[w] = s; red[4 + w] = s2; }
    __syncthreads();
    if (tid == 0) {
        const float ts  = red[0] + red[1] + red[2] + red[3];
        const float ts2 = red[4] + red[5] + red[6] + red[7];
        const float mu  = ts * (1.f / 1024.f);
        const float var = ts2 * (1.f / 1024.f) - mu * mu;
        red[0] = mu;
        red[1] = rsqrtf(var + 1e-5f);
    }
    __syncthreads();
    const float mu = red[0], rs = red[1];
    const float4 gv = reinterpret_cast<const float4*>(g)[tid];
    const float4 bv = reinterpret_cast<const float4*>(be)[tid];
    float o0 = (v[0] - mu) * rs * gv.x + bv.x;
    float o1 = (v[1] - mu) * rs * gv.y + bv.y;
    float o2 = (v[2] - mu) * rs * gv.z + bv.z;
    float o3 = (v[3] - mu) * rs * gv.w + bv.w;
    if (OUTBF) {
        ushort4 ob;
        ob.x = f2bf(o0); ob.y = f2bf(o1); ob.z = f2bf(o2); ob.w = f2bf(o3);
        reinterpret_cast<ushort4*>((ushort*)out + (size_t)row * 1024)[tid] = ob;
    } else {
        float4 of;
        of.x = o0; of.y = o1; of.z = o2; of.w = o3;
        reinterpret_cast<float4*>((float*)out + (size_t)row * 1024)[tid] = of;
    }
}

// ---------- launch ----------
extern "C" void kernel_launch(void* const* d_in, const int* in_sizes, int n_in,
                              void* d_out, int out_size, void* d_ws, size_t ws_size,
                              hipStream_t stream) {
    const float* x  = (const float*)d_in[0];
    const float* Wq = (const float*)d_in[1];  const float* bq = (const float*)d_in[2];
    const float* Wk = (const float*)d_in[3];  const float* bk = (const float*)d_in[4];
    const float* Wv = (const float*)d_in[5];  const float* bv = (const float*)d_in[6];
    const float* Wo = (const float*)d_in[7];  const float* bo = (const float*)d_in[8];
    const float* W1 = (const float*)d_in[9];  const float* b1 = (const float*)d_in[10];
    const float* W2 = (const float*)d_in[11]; const float* b2 = (const float*)d_in[12];
    const float* g1 = (const float*)d_in[13]; const float* be1 = (const float*)d_in[14];
    const float* g2 = (const float*)d_in[15]; const float* be2 = (const float*)d_in[16];

    char* ws = (char*)d_ws;
    const size_t MBy = (size_t)1 << 20;
    ushort* xb    = (ushort*)(ws + 0 * MBy);     // 16 MB  [8192][1024] bf16
    ushort* wqkvT = (ushort*)(ws + 16 * MBy);    // 6 MB   [3072][1024]
    ushort* woT   = (ushort*)(ws + 22 * MBy);    // 2 MB
    ushort* w1T   = (ushort*)(ws + 24 * MBy);    // 8 MB   [4096][1024]
    ushort* w2T   = (ushort*)(ws + 32 * MBy);    // 8 MB   [1024][4096]
    ushort* QKVb  = (ushort*)(ws + 40 * MBy);    // 48 MB  [8192][3072]
    ushort* AOb   = (ushort*)(ws + 88 * MBy);    // 16 MB
    ushort* h1    = (ushort*)(ws + 40 * MBy);    // 64 MB (aliases QKVb+AOb, both dead by FFN1)
    ushort* z1b   = (ushort*)(ws + 104 * MBy);   // 16 MB  x + attn_out (bf16)
    ushort* z2b   = (ushort*)(ws + 104 * MBy);   // aliases z1b (dead after LN1)
    ushort* x2b   = (ushort*)(ws + 120 * MBy);   // 16 MB
    (void)ws_size; (void)n_in; (void)in_sizes; (void)out_size;

    const int M = 8192;

    // fused prep: x cast + all weight transposes (20480 blocks, one launch)
    prep_kernel<<<20480, dim3(32, 8), 0, stream>>>(x, xb, Wq, Wk, Wv, Wo, W1, W2,
                                                   wqkvT, woT, w1T, w2T);

    // QKV projection (p3; 1536 blocks -> 3/CU)
    gemm_p3<0, 1, 1, 0><<<dim3(24, 64), 256, 0, stream>>>(xb, wqkvT, bq, bk, bv, nullptr,
                                                          QKVb, M, 3072, 1024);

    // attention: 512 blocks x 512 threads (256 q-rows per block)
    attn_kernel<<<512, 512, 0, stream>>>(QKVb, AOb);

    // Wo + fused residual (xb, bf16) -> z1 = x + attn_out (bf16)
    gemm_p3<0, 1, 0, 2><<<dim3(8, 64), 256, 0, stream>>>(AOb, woT, bo, nullptr, nullptr, xb,
                                                         z1b, M, 1024, 1024);

    // LN1 (single input)
    ln_one<1><<<M, 256, 0, stream>>>(z1b, g1, be1, x2b);

    // FFN1
    gemm_p3<1, 1, 0, 0><<<dim3(32, 64), 256, 0, stream>>>(x2b, w1T, b1, nullptr, nullptr,
                                                          nullptr, h1, M, 4096, 1024);
    // FFN2 + fused residual (x2b, bf16) -> z2 = x2 + ffn_out (bf16)
    gemm_p3<0, 1, 0, 2><<<dim3(8, 64), 256, 0, stream>>>(h1, w2T, b2, nullptr, nullptr, x2b,
                                                         z2b, M, 1024, 4096);

    // LN2 -> d_out (f32)
    ln_one<0><<<M, 256, 0, stream>>>(z2b, g2, be2, (float*)d_out);
}

// Round 19
// 385.826 us; speedup vs baseline: 1.2046x; 1.0002x over previous
//
#include <hip/hip_runtime.h>
#include <hip/hip_bf16.h>

// ---------- types ----------
typedef __attribute__((ext_vector_type(8)))  __bf16 bf16x8;
typedef __attribute__((ext_vector_type(4)))  float  f32x4;
typedef __attribute__((ext_vector_type(16))) float  f32x16;

static __device__ __forceinline__ unsigned short f2bf(float x) {
    unsigned int u = __float_as_uint(x);
    unsigned int r = (u + 0x7FFFu + ((u >> 16) & 1u)) >> 16;
    return (unsigned short)r;
}
static __device__ __forceinline__ float bf2f(unsigned short u) {
    return __uint_as_float(((unsigned int)u) << 16);
}

// 2^x via v_exp_f32 (CDNA VALU has HW interlocks; no nop needed)
static __device__ __forceinline__ float fast_exp2(float x) {
    float r;
    asm("v_exp_f32 %0, %1" : "=v"(r) : "v"(x));
    return r;
}
// packed f32x2 -> bf16x2 (u32); lo <- a, hi <- b
static __device__ __forceinline__ unsigned int cvt_pk_bf16(float a, float b) {
    unsigned int r;
    asm("v_cvt_pk_bf16_f32 %0, %1, %2" : "=v"(r) : "v"(a), "v"(b));
    return r;
}

// async global->LDS, 16B per lane; lds base wave-uniform (lane*16 auto-offset)
static __device__ __forceinline__ void gload_lds16(const ushort* g, ushort* l) {
    __builtin_amdgcn_global_load_lds((const __attribute__((address_space(1))) void*)g,
                                     (__attribute__((address_space(3))) void*)l, 16, 0, 0);
}

// raw barrier + scheduling/memory fence (no vmcnt drain, unlike __syncthreads)
static __device__ __forceinline__ void barrier_fence() {
    __builtin_amdgcn_s_barrier();
    __builtin_amdgcn_sched_barrier(0);
    asm volatile("" ::: "memory");
}

// T1: XCD-aware chunked remap (requires nwg % 8 == 0; all grids here comply)
static __device__ __forceinline__ int xcd_swz(int id, int nwg) {
    return (id & 7) * (nwg >> 3) + (id >> 3);
}

// ---------- fused prep: x cast (blocks 0..8191) + ALL weight transposes ----------
__global__ __launch_bounds__(256) void prep_kernel(const float* __restrict__ x,
                                                   ushort* __restrict__ xb,
                                                   const float* __restrict__ Wq,
                                                   const float* __restrict__ Wk,
                                                   const float* __restrict__ Wv,
                                                   const float* __restrict__ Wo,
                                                   const float* __restrict__ W1,
                                                   const float* __restrict__ W2,
                                                   ushort* __restrict__ wqkvT,
                                                   ushort* __restrict__ woT,
                                                   ushort* __restrict__ w1T,
                                                   ushort* __restrict__ w2T) {
    const int bid = blockIdx.x;
    if (bid < 8192) {
        const int i = bid * 256 + threadIdx.x + threadIdx.y * 32;
        float4 v = reinterpret_cast<const float4*>(x)[i];
        ushort4 o;
        o.x = f2bf(v.x); o.y = f2bf(v.y); o.z = f2bf(v.z); o.w = f2bf(v.w);
        reinterpret_cast<ushort4*>(xb)[i] = o;
        return;
    }
    __shared__ float tile[32][33];
    const int tx = threadIdx.x;
    const int ty = threadIdx.y;
    const int z  = bid - 8192;

    const float* in;
    ushort* out;
    int K, N, idx;
    if (z < 3072) {
        const int s = z >> 10;
        in  = (s == 0) ? Wq : (s == 1 ? Wk : Wv);
        out = wqkvT + (size_t)s * 1024 * 1024;
        K = 1024; N = 1024; idx = z & 1023;
    } else if (z < 4096) {
        in = Wo; out = woT; K = 1024; N = 1024; idx = z - 3072;
    } else if (z < 8192) {
        in = W1; out = w1T; K = 1024; N = 4096; idx = z - 4096;
    } else {
        in = W2; out = w2T; K = 4096; N = 1024; idx = z - 8192;
    }
    const int ntiles = N >> 5;
    const int n0 = (idx % ntiles) * 32;
    const int k0 = (idx / ntiles) * 32;

    for (int i = ty; i < 32; i += 8)
        tile[i][tx] = in[(size_t)(k0 + i) * N + n0 + tx];
    __syncthreads();
    for (int i = ty; i < 32; i += 8)
        out[(size_t)(n0 + i) * K + k0 + tx] = f2bf(tile[tx][i]);
}

// ============================================================================
// GEMM, 128x128 tile, BK=32, 256 threads (4 waves, 2x2 of 64x64).
// 3 LDS buffers, counted-vmcnt pipeline; T2 chunk swizzle both sides.
// ============================================================================
template<int RELU, int OUTBF, int QKV, int RES>
__global__ __launch_bounds__(256) void gemm_p3(const ushort* __restrict__ A,
                                               const ushort* __restrict__ Bt,
                                               const float* __restrict__ b0,
                                               const float* __restrict__ b1_,
                                               const float* __restrict__ b2_,
                                               const void* __restrict__ xres,
                                               void* __restrict__ Cp,
                                               int M, int N, int K) {
    __shared__ ushort As[3][4096];
    __shared__ ushort Bs[3][4096];
    const int tid  = threadIdx.x;
    const int lane = tid & 63;
    const int w    = tid >> 6;
    const int wr   = w >> 1, wc = w & 1;
    const int nwg = gridDim.x * gridDim.y;
    int wid = xcd_swz(blockIdx.y * gridDim.x + blockIdx.x, nwg);
    const int bx = wid % gridDim.x;
    const int by = wid / gridDim.x;
    const int m0 = by * 128;
    const int n0 = bx * 128;
    const int lr = lane & 15;
    const int lg = lane >> 4;
    const int xc = (lg ^ ((lr >> 1) & 3)) * 8;

    const int r0 = w * 32 + (lane >> 2);
    const int c8 = ((lane & 3) ^ ((lane >> 3) & 3)) * 8;
    const ushort* gA0 = A  + (size_t)(m0 + r0)      * K + c8;
    const ushort* gA1 = A  + (size_t)(m0 + r0 + 16) * K + c8;
    const ushort* gB0 = Bt + (size_t)(n0 + r0)      * K + c8;
    const ushort* gB1 = Bt + (size_t)(n0 + r0 + 16) * K + c8;
    const int wb = w * 1024;

    f32x4 acc[4][4];
    const f32x4 z = {0.f, 0.f, 0.f, 0.f};
#pragma unroll
    for (int i = 0; i < 4; i++)
#pragma unroll
        for (int j = 0; j < 4; j++) acc[i][j] = z;

    const int nt = K >> 5;

#pragma unroll
    for (int t = 0; t < 2; ++t) {
        const int kn = t * 32;
        gload_lds16(gA0 + kn, &As[t][wb]);
        gload_lds16(gA1 + kn, &As[t][wb + 512]);
        gload_lds16(gB0 + kn, &Bs[t][wb]);
        gload_lds16(gB1 + kn, &Bs[t][wb + 512]);
    }

    int cur = 0;
    for (int t = 0; t < nt; ++t) {
        if (t + 1 < nt) asm volatile("s_waitcnt vmcnt(4)" ::: "memory");
        else            asm volatile("s_waitcnt vmcnt(0)" ::: "memory");
        barrier_fence();

        if (t + 2 < nt) {
            const int bi = (cur + 2 >= 3) ? cur - 1 : cur + 2;
            const int kn = (t + 2) * 32;
            gload_lds16(gA0 + kn, &As[bi][wb]);
            gload_lds16(gA1 + kn, &As[bi][wb + 512]);
            gload_lds16(gB0 + kn, &Bs[bi][wb]);
            gload_lds16(gB1 + kn, &Bs[bi][wb + 512]);
        }

        const ushort* Asb = As[cur];
        const ushort* Bsb = Bs[cur];
        bf16x8 af[4], bfr[4];
#pragma unroll
        for (int i = 0; i < 4; i++)
            af[i] = *reinterpret_cast<const bf16x8*>(&Asb[(wr * 64 + i * 16 + lr) * 32 + xc]);
#pragma unroll
        for (int j = 0; j < 4; j++)
            bfr[j] = *reinterpret_cast<const bf16x8*>(&Bsb[(wc * 64 + j * 16 + lr) * 32 + xc]);
#pragma unroll
        for (int i = 0; i < 4; i++)
#pragma unroll
            for (int j = 0; j < 4; j++)
                acc[i][j] = __builtin_amdgcn_mfma_f32_16x16x32_bf16(af[i], bfr[j], acc[i][j], 0, 0, 0);

        cur = (cur == 2) ? 0 : cur + 1;
    }

    const float* bias;
    float qscale = 1.0f;
    if (QKV) {
        bias = (n0 < 1024) ? b0 : (n0 < 2048 ? b1_ : b2_);
        if (n0 < 1024) qscale = 0.18033688f;   // 0.125*log2(e) folded into Q
    } else {
        bias = b0;
    }
    const int nb = QKV ? (n0 & 1023) : n0;
    const int rbase = (lane >> 4) * 4;
#pragma unroll
    for (int i = 0; i < 4; i++) {
#pragma unroll
        for (int j = 0; j < 4; j++) {
            const int cloc = wc * 64 + j * 16 + lr;
            const float bv = bias[nb + cloc];
#pragma unroll
            for (int r = 0; r < 4; r++) {
                const int row = m0 + wr * 64 + i * 16 + rbase + r;
                float v = acc[i][j][r] + bv;
                if (RES == 1) v += ((const float*)xres)[(size_t)row * N + n0 + cloc];
                if (RES == 2) v += bf2f(((const ushort*)xres)[(size_t)row * N + n0 + cloc]);
                if (RELU) v = v > 0.f ? v : 0.f;
                if (QKV)  v *= qscale;
                if (OUTBF) ((ushort*)Cp)[(size_t)row * N + n0 + cloc] = f2bf(v);
                else       ((float*)Cp)[(size_t)row * N + n0 + cloc] = v;
            }
        }
    }
}

// ---------- flash attention, 32x32 swapped-QK^T, in-register P (T12) ----------
// 8 waves x 32 q-rows = 256 q-rows/block (grid 512). Counted-vmcnt pipeline:
// 3 K-buffers; per iter issue V(t+1) THEN K(t+2) (FIFO: consuming V at the
// Vt-write implies vmcnt(1), certifying K(t+1) while K(t+2) stays in flight
// ACROSS the barrier). Explicit vmcnt(1)+lgkmcnt(0)+raw barrier replace the
// old __syncthreads (which drained vmcnt to 0 every tile).
#define ASWZ(row, col) ((row) * 64 + ((col) ^ ((((row) ^ ((row) >> 3)) & 7) << 3)))

__global__ __launch_bounds__(512, 4) void attn_kernel(const ushort* __restrict__ QKV,
                                                      ushort* __restrict__ O) {
    __shared__ ushort Ks[3][4096];
    __shared__ ushort Vt[2][4096];
    const int tid  = threadIdx.x;          // 0..511
    const int lane = tid & 63;
    const int w    = tid >> 6;             // 0..7
    const int l31  = lane & 31;
    const int hi   = lane >> 5;

    int blk = xcd_swz(blockIdx.x, gridDim.x);   // 512 blocks
    const int qb = blk & 7;
    const int h  = (blk >> 3) & 15;
    const int b  = blk >> 7;
    const int s0 = qb * 256 + w * 32;
    const size_t rowb   = (size_t)b * 2048;
    const size_t base_q = rowb * 3072 + (size_t)h * 64;
    const size_t base_k = base_q + 1024;
    const size_t base_v = base_q + 2048;
    const size_t base_o = rowb * 1024 + (size_t)h * 64;

    bf16x8 qf[4];
#pragma unroll
    for (int ks = 0; ks < 4; ks++)
        qf[ks] = *reinterpret_cast<const bf16x8*>(
            &QKV[base_q + (size_t)(s0 + l31) * 3072 + ks * 16 + 8 * hi]);

    int off8[2][4];
#pragma unroll
    for (int sub = 0; sub < 2; sub++)
#pragma unroll
        for (int ks = 0; ks < 4; ks++)
            off8[sub][ks] = ASWZ(sub * 32 + l31, ks * 16 + 8 * hi);

    const int tS  = tid >> 3;              // row 0..63
    const int ccS = tid & 7;
    int voff[8];
#pragma unroll
    for (int jj = 0; jj < 8; jj++)
        voff[jj] = ASWZ(ccS * 8 + jj, tS);
    const int szK = (tS ^ (tS >> 3)) & 7;
    const ushort* pK = QKV + base_k + (size_t)tS * 3072 + (ccS ^ szK) * 8;
    const ushort* pV = QKV + base_v + (size_t)tS * 3072 + ccS * 8;
    const size_t step = (size_t)64 * 3072;

    // prologue: V(0) first (oldest), then K(0), K(1); consume V -> implicit
    // vmcnt(2); explicit vmcnt(1) certifies K(0), leaves K(1) in flight.
    {
        int4 v0 = *reinterpret_cast<const int4*>(pV);
        gload_lds16(pK,        &Ks[0][w * 512]);
        gload_lds16(pK + step, &Ks[1][w * 512]);
        const ushort* vs = reinterpret_cast<const ushort*>(&v0);
#pragma unroll
        for (int jj = 0; jj < 8; jj++) Vt[0][voff[jj]] = vs[jj];
    }
    asm volatile("s_waitcnt vmcnt(1)" ::: "memory");
    asm volatile("s_waitcnt lgkmcnt(0)" ::: "memory");
    barrier_fence();
    pK += 2 * step; pV += step;

    f32x16 oacc0, oacc1;
    for (int i = 0; i < 16; i++) { oacc0[i] = 0.f; oacc1[i] = 0.f; }
    float lacc = 0.f;
    int kc = 0;                            // t % 3

    for (int it = 0; it < 32; ++it) {
        const int vc = it & 1;
        int4 nv;
        if (it < 31) {
            nv = *reinterpret_cast<const int4*>(pV);   // V(t+1), issued BEFORE K(t+2)
            pV += step;
        }
        if (it < 30) {
            const int bi = (kc + 2 >= 3) ? kc - 1 : kc + 2;   // (t+2)%3
            gload_lds16(pK, &Ks[bi][w * 512]);
            pK += step;
        }

        f32x16 sa0, sa1;
        for (int i = 0; i < 16; i++) { sa0[i] = 0.f; sa1[i] = 0.f; }
        __builtin_amdgcn_s_setprio(1);
#pragma unroll
        for (int ks = 0; ks < 4; ks++) {
            bf16x8 k0 = *reinterpret_cast<const bf16x8*>(&Ks[kc][off8[0][ks]]);
            sa0 = __builtin_amdgcn_mfma_f32_32x32x16_bf16(k0, qf[ks], sa0, 0, 0, 0);
        }
#pragma unroll
        for (int ks = 0; ks < 4; ks++) {
            bf16x8 k1 = *reinterpret_cast<const bf16x8*>(&Ks[kc][off8[1][ks]]);
            sa1 = __builtin_amdgcn_mfma_f32_32x32x16_bf16(k1, qf[ks], sa1, 0, 0, 0);
        }
        __builtin_amdgcn_s_setprio(0);

        unsigned pk0[8], pk1[8];
#pragma unroll
        for (int i = 0; i < 8; i++) {
            float plo = fast_exp2(sa0[2 * i]);
            float phi = fast_exp2(sa0[2 * i + 1]);
            lacc += plo + phi;
            pk0[i] = cvt_pk_bf16(plo, phi);
        }
#pragma unroll
        for (int i = 0; i < 8; i++) {
            float plo = fast_exp2(sa1[2 * i]);
            float phi = fast_exp2(sa1[2 * i + 1]);
            lacc += plo + phi;
            pk1[i] = cvt_pk_bf16(plo, phi);
        }

        __builtin_amdgcn_s_setprio(1);
#pragma unroll
        for (int ks = 0; ks < 4; ks++) {
            const int bi = 4 * (ks & 1);
            unsigned a, bb, c, d;
            if (ks < 2) { a = pk0[bi]; bb = pk0[bi + 1]; c = pk0[bi + 2]; d = pk0[bi + 3]; }
            else        { a = pk1[bi]; bb = pk1[bi + 1]; c = pk1[bi + 2]; d = pk1[bi + 3]; }
            asm("v_permlane32_swap_b32 %0, %1" : "+v"(a), "+v"(c));
            asm("v_permlane32_swap_b32 %0, %1" : "+v"(bb), "+v"(d));
            union { unsigned u[4]; bf16x8 v; } fr;
            fr.u[0] = a; fr.u[1] = bb; fr.u[2] = c; fr.u[3] = d;
            bf16x8 v0 = *reinterpret_cast<const bf16x8*>(&Vt[vc][off8[0][ks]]);
            oacc0 = __builtin_amdgcn_mfma_f32_32x32x16_bf16(fr.v, v0, oacc0, 0, 0, 0);
            bf16x8 v1 = *reinterpret_cast<const bf16x8*>(&Vt[vc][off8[1][ks]]);
            oacc1 = __builtin_amdgcn_mfma_f32_32x32x16_bf16(fr.v, v1, oacc1, 0, 0, 0);
        }
        __builtin_amdgcn_s_setprio(0);

        if (it < 31) {
            const ushort* vs = reinterpret_cast<const ushort*>(&nv);
#pragma unroll
            for (int jj = 0; jj < 8; jj++) Vt[vc ^ 1][voff[jj]] = vs[jj];
        }
        // K(t+1) certified (implicit via nv consumption; explicit for safety),
        // K(t+2) stays in flight across the barrier.
        asm volatile("s_waitcnt vmcnt(1)" ::: "memory");
        asm volatile("s_waitcnt lgkmcnt(0)" ::: "memory");
        barrier_fence();
        kc = (kc == 2) ? 0 : kc + 1;
    }

    const float ltot = lacc + __shfl_xor(lacc, 32);
    const float inv  = 1.f / ltot;
#pragma unroll
    for (int r = 0; r < 16; r++) {
        const int qloc = (r & 3) + 8 * (r >> 2) + 4 * hi;
        const float invq = __shfl(inv, qloc);
        const size_t rowoff = base_o + (size_t)(s0 + qloc) * 1024 + l31;
        O[rowoff]      = f2bf(oacc0[r] * invq);
        O[rowoff + 32] = f2bf(oacc1[r] * invq);
    }
}

// ---------- single-input layernorm (residual already added in GEMM epilogue) ----------
template<int OUTBF>
__global__ __launch_bounds__(256) void ln_one(const ushort* __restrict__ zin,
                                              const float* __restrict__ g,
                                              const float* __restrict__ be,
                                              void* __restrict__ out) {
    const int row = blockIdx.x;
    const int tid = threadIdx.x;
    const ushort4 zv = reinterpret_cast<const ushort4*>(zin + (size_t)row * 1024)[tid];
    float v[4] = {bf2f(zv.x), bf2f(zv.y), bf2f(zv.z), bf2f(zv.w)};
    float s  = v[0] + v[1] + v[2] + v[3];
    float s2 = v[0]*v[0] + v[1]*v[1] + v[2]*v[2] + v[3]*v[3];
    for (int off = 32; off; off >>= 1) { s += __shfl_down(s, off); s2 += __shfl_down(s2, off); }
    __shared__ float red[8];
    const int w = tid >> 6, lane = tid & 63;
    if (lane == 0) { red[w] = s; red[4 + w] = s2; }
    __syncthreads();
    if (tid == 0) {
        const float ts  = red[0] + red[1] + red[2] + red[3];
        const float ts2 = red[4] + red[5] + red[6] + red[7];
        const float mu  = ts * (1.f / 1024.f);
        const float var = ts2 * (1.f / 1024.f) - mu * mu;
        red[0] = mu;
        red[1] = rsqrtf(var + 1e-5f);
    }
    __syncthreads();
    const float mu = red[0], rs = red[1];
    const float4 gv = reinterpret_cast<const float4*>(g)[tid];
    const float4 bv = reinterpret_cast<const float4*>(be)[tid];
    float o0 = (v[0] - mu) * rs * gv.x + bv.x;
    float o1 = (v[1] - mu) * rs * gv.y + bv.y;
    float o2 = (v[2] - mu) * rs * gv.z + bv.z;
    float o3 = (v[3] - mu) * rs * gv.w + bv.w;
    if (OUTBF) {
        ushort4 ob;
        ob.x = f2bf(o0); ob.y = f2bf(o1); ob.z = f2bf(o2); ob.w = f2bf(o3);
        reinterpret_cast<ushort4*>((ushort*)out + (size_t)row * 1024)[tid] = ob;
    } else {
        float4 of;
        of.x = o0; of.y = o1; of.z = o2; of.w = o3;
        reinterpret_cast<float4*>((float*)out + (size_t)row * 1024)[tid] = of;
    }
}

// ---------- launch ----------
extern "C" void kernel_launch(void* const* d_in, const int* in_sizes, int n_in,
                              void* d_out, int out_size, void* d_ws, size_t ws_size,
                              hipStream_t stream) {
    const float* x  = (const float*)d_in[0];
    const float* Wq = (const float*)d_in[1];  const float* bq = (const float*)d_in[2];
    const float* Wk = (const float*)d_in[3];  const float* bk = (const float*)d_in[4];
    const float* Wv = (const float*)d_in[5];  const float* bv = (const float*)d_in[6];
    const float* Wo = (const float*)d_in[7];  const float* bo = (const float*)d_in[8];
    const float* W1 = (const float*)d_in[9];  const float* b1 = (const float*)d_in[10];
    const float* W2 = (const float*)d_in[11]; const float* b2 = (const float*)d_in[12];
    const float* g1 = (const float*)d_in[13]; const float* be1 = (const float*)d_in[14];
    const float* g2 = (const float*)d_in[15]; const float* be2 = (const float*)d_in[16];

    char* ws = (char*)d_ws;
    const size_t MBy = (size_t)1 << 20;
    ushort* xb    = (ushort*)(ws + 0 * MBy);     // 16 MB  [8192][1024] bf16
    ushort* wqkvT = (ushort*)(ws + 16 * MBy);    // 6 MB   [3072][1024]
    ushort* woT   = (ushort*)(ws + 22 * MBy);    // 2 MB
    ushort* w1T   = (ushort*)(ws + 24 * MBy);    // 8 MB   [4096][1024]
    ushort* w2T   = (ushort*)(ws + 32 * MBy);    // 8 MB   [1024][4096]
    ushort* QKVb  = (ushort*)(ws + 40 * MBy);    // 48 MB  [8192][3072]
    ushort* AOb   = (ushort*)(ws + 88 * MBy);    // 16 MB
    ushort* h1    = (ushort*)(ws + 40 * MBy);    // 64 MB (aliases QKVb+AOb, both dead by FFN1)
    ushort* z1b   = (ushort*)(ws + 104 * MBy);   // 16 MB  x + attn_out (bf16)
    ushort* z2b   = (ushort*)(ws + 104 * MBy);   // aliases z1b (dead after LN1)
    ushort* x2b   = (ushort*)(ws + 120 * MBy);   // 16 MB
    (void)ws_size; (void)n_in; (void)in_sizes; (void)out_size;

    const int M = 8192;

    // fused prep: x cast + all weight transposes (20480 blocks, one launch)
    prep_kernel<<<20480, dim3(32, 8), 0, stream>>>(x, xb, Wq, Wk, Wv, Wo, W1, W2,
                                                   wqkvT, woT, w1T, w2T);

    // QKV projection (p3; 1536 blocks -> 3/CU)
    gemm_p3<0, 1, 1, 0><<<dim3(24, 64), 256, 0, stream>>>(xb, wqkvT, bq, bk, bv, nullptr,
                                                          QKVb, M, 3072, 1024);

    // attention: 512 blocks x 512 threads (256 q-rows per block)
    attn_kernel<<<512, 512, 0, stream>>>(QKVb, AOb);

    // Wo + fused residual (xb, bf16) -> z1 = x + attn_out (bf16)
    gemm_p3<0, 1, 0, 2><<<dim3(8, 64), 256, 0, stream>>>(AOb, woT, bo, nullptr, nullptr, xb,
                                                         z1b, M, 1024, 1024);

    // LN1 (single input)
    ln_one<1><<<M, 256, 0, stream>>>(z1b, g1, be1, x2b);

    // FFN1
    gemm_p3<1, 1, 0, 0><<<dim3(32, 64), 256, 0, stream>>>(x2b, w1T, b1, nullptr, nullptr,
                                                          nullptr, h1, M, 4096, 1024);
    // FFN2 + fused residual (x2b, bf16) -> z2 = x2 + ffn_out (bf16)
    gemm_p3<0, 1, 0, 2><<<dim3(8, 64), 256, 0, stream>>>(h1, w2T, b2, nullptr, nullptr, x2b,
                                                         z2b, M, 1024, 4096);

    // LN2 -> d_out (f32)
    ln_one<0><<<M, 256, 0, stream>>>(z2b, g2, be2, (float*)d_out);
}